// Round 11
// baseline (310.523 us; speedup 1.0000x reference)
//
#include <hip/hip_runtime.h>
#include <math.h>

#define N_NODES 100000
#define N_EDGES 800000
#define E_TOT (N_EDGES + N_NODES)
#define NEG_SLOPE 0.2f
#define SCAN_NB ((N_NODES + 1023) / 1024)
#define EB ((E_TOT + 255) / 256)
#define GBM ((N_NODES + 127) / 128)
#define HB 512   // grid-strided histogram blocks (placed first in merged grid)

typedef unsigned short ushort_t;
typedef unsigned long long ull_t;
typedef __attribute__((ext_vector_type(8))) short short8v;   // 8 bf16
typedef __attribute__((ext_vector_type(4))) float f32x4;

static __device__ __forceinline__ float leaky(float e) {
  return e > 0.f ? e : NEG_SLOPE * e;
}

static __device__ __forceinline__ float b2f(ushort_t u) {
  union { unsigned int i; float f; } x;
  x.i = ((unsigned int)u) << 16;
  return x.f;
}

static __device__ __forceinline__ ushort_t f2b(float f) {
  union { float f; unsigned int i; } x;
  x.f = f;
  unsigned int r = x.i + 0x7FFFu + ((x.i >> 16) & 1u);  // RNE (finite inputs)
  return (ushort_t)(r >> 16);
}

// ---------------- prep: zero buffers + weight transposes (absorbs memset) ----------------

__global__ void prep_kernel(int* __restrict__ deg, float* __restrict__ asrc1,
                            float* __restrict__ adst1, ull_t* __restrict__ state,
                            const float* __restrict__ W1, ushort_t* __restrict__ W1t,
                            const float* __restrict__ W2, ushort_t* __restrict__ W2t) {
  int g = blockIdx.x * 256 + threadIdx.x;
  const int GT = gridDim.x * 256;
  for (int i = g; i < N_NODES; i += GT) { deg[i] = 0; asrc1[i] = 0.f; adst1[i] = 0.f; }
  for (int i = g; i < 256 * 128; i += GT) {       // W1t[n][k] = W1[k][n]
    int n = i >> 7, k = i & 127;
    W1t[i] = f2b(W1[(size_t)k * 256 + n]);
  }
  for (int i = g; i < 64 * 256; i += GT) {        // W2t[n][k] = W2[k][n]
    int n = i >> 8, k = i & 255;
    W2t[i] = f2b(W2[(size_t)k * 64 + n]);
  }
  for (int i = g; i < SCAN_NB; i += GT) state[i] = 0;
}

// ---------------- GEMM body (device fn; callable from merged dispatch) ----------------
// ALPHA_MODE 1: per-row partial alpha dots; LDS-reduce, 2 global atomicAdds/row
// (exactly 2 contributions per address -> deterministic).
// ALPHA_MODE 2: block covers ALL cols: direct store, no atomics.

template <int WAVES_M, int WAVES_N, int KTOT, bool A_FP32, int ALPHA_MODE>
static __device__ void gemm_body(
    int bx, int by,
    const void* __restrict__ Aptr, const ushort_t* __restrict__ Bt,
    ushort_t* __restrict__ Out, int M, int NTOT,
    const float* __restrict__ av_s, const float* __restrict__ av_d,
    float* __restrict__ os, float* __restrict__ od) {
  constexpr int BM = 128;
  constexpr int WN = 64;
  constexpr int WM = BM / WAVES_M;
  constexpr int M_REP = WM / 16;
  constexpr int N_REP = WN / 16;
  constexpr int KC = 128;
  __shared__ ushort_t As[BM * KC];
  __shared__ float als_s[BM], als_d[BM];

  const int tid = threadIdx.x;
  const int lane = tid & 63;
  const int wid = tid >> 6;
  const int wm = wid % WAVES_M;
  const int wn = wid / WAVES_M;
  const int rowBase = bx * BM;
  const int colBase = by * (WAVES_N * WN) + wn * WN;
  const int l15 = lane & 15;
  const int l4 = lane >> 4;

  if (ALPHA_MODE == 1) {
    for (int rr = tid; rr < BM; rr += 256) { als_s[rr] = 0.f; als_d[rr] = 0.f; }
  }

  f32x4 acc[M_REP][N_REP] = {};

  for (int kc = 0; kc < KTOT; kc += KC) {
    if (kc) __syncthreads();
    for (int c = tid; c < BM * KC / 8; c += 256) {
      int r = c >> 4;
      int k8 = (c & 15) << 3;
      int gr = rowBase + r;
      short8v u = {};
      if (gr < M) {
        if (A_FP32) {
          const float* A = (const float*)Aptr;
          float4 f0 = *(const float4*)&A[(size_t)gr * KTOT + kc + k8];
          float4 f1 = *(const float4*)&A[(size_t)gr * KTOT + kc + k8 + 4];
          u[0] = (short)f2b(f0.x); u[1] = (short)f2b(f0.y);
          u[2] = (short)f2b(f0.z); u[3] = (short)f2b(f0.w);
          u[4] = (short)f2b(f1.x); u[5] = (short)f2b(f1.y);
          u[6] = (short)f2b(f1.z); u[7] = (short)f2b(f1.w);
        } else {
          const ushort_t* A = (const ushort_t*)Aptr;
          u = *(const short8v*)&A[(size_t)gr * KTOT + kc + k8];
        }
      }
      int byte = (r * KC + k8) * 2;
      byte ^= (r & 7) << 4;  // G4 swizzle
      *(short8v*)((char*)As + byte) = u;
    }
    short8v bfr[KC / 32][N_REP];
#pragma unroll
    for (int kk = 0; kk < KC / 32; ++kk)
#pragma unroll
      for (int n = 0; n < N_REP; ++n) {
        int bcol = colBase + n * 16 + l15;
        int k0 = kc + kk * 32 + l4 * 8;
        bfr[kk][n] = *(const short8v*)&Bt[(size_t)bcol * KTOT + k0];
      }
    __syncthreads();
#pragma unroll
    for (int kk = 0; kk < KC / 32; ++kk) {
      short8v afr[M_REP];
#pragma unroll
      for (int m = 0; m < M_REP; ++m) {
        int r = wm * WM + m * 16 + l15;
        int k0 = kk * 32 + l4 * 8;
        int byte = ((r * KC + k0) * 2) ^ ((r & 7) << 4);
        afr[m] = *(const short8v*)((const char*)As + byte);
      }
#pragma unroll
      for (int m = 0; m < M_REP; ++m)
#pragma unroll
        for (int n = 0; n < N_REP; ++n)
          acc[m][n] = __builtin_amdgcn_mfma_f32_16x16x32_bf16(
              afr[m], bfr[kk][n], acc[m][n], 0, 0, 0);
    }
  }
  // C write: col=lane&15, row=(lane>>4)*4+reg
#pragma unroll
  for (int m = 0; m < M_REP; ++m) {
    int r0 = rowBase + wm * WM + m * 16 + l4 * 4;
#pragma unroll
    for (int n = 0; n < N_REP; ++n) {
      int gc = colBase + n * 16 + l15;
#pragma unroll
      for (int j = 0; j < 4; ++j) {
        int gr = r0 + j;
        if (gr < M) Out[(size_t)gr * NTOT + gc] = f2b(acc[m][n][j]);
      }
    }
  }
  // fused alpha epilogue
  if (ALPHA_MODE) {
    float as_v[N_REP], ad_v[N_REP];
#pragma unroll
    for (int n = 0; n < N_REP; ++n) {
      as_v[n] = av_s[colBase + n * 16 + l15];
      ad_v[n] = av_d[colBase + n * 16 + l15];
    }
#pragma unroll
    for (int m = 0; m < M_REP; ++m)
#pragma unroll
      for (int j = 0; j < 4; ++j) {
        float ss = 0.f, dd = 0.f;
#pragma unroll
        for (int n = 0; n < N_REP; ++n) {
          ss += acc[m][n][j] * as_v[n];
          dd += acc[m][n][j] * ad_v[n];
        }
#pragma unroll
        for (int o = 1; o < 16; o <<= 1) {
          ss += __shfl_xor(ss, o);
          dd += __shfl_xor(dd, o);
        }
        if (l15 == 0) {
          int rloc = wm * WM + m * 16 + l4 * 4 + j;
          if (ALPHA_MODE == 1) {
            atomicAdd(&als_s[rloc], ss);
            atomicAdd(&als_d[rloc], dd);
          } else {
            int gr = rowBase + rloc;
            if (gr < M) { os[gr] = ss; od[gr] = dd; }
          }
        }
      }
    if (ALPHA_MODE == 1) {
      __syncthreads();
      for (int rr = tid; rr < BM; rr += 256) {
        int gr = rowBase + rr;
        if (gr < M) {
          atomicAdd(&os[gr], als_s[rr]);
          atomicAdd(&od[gr], als_d[rr]);
        }
      }
    }
  }
}

// ---------------- merged dispatch: histogram (grid-strided, FIRST) + GEMM1 ----------------

__global__ __launch_bounds__(256) void hist_gemm1(
    const float* __restrict__ x, const ushort_t* __restrict__ W1t,
    ushort_t* __restrict__ h1,
    const float* __restrict__ a1s, const float* __restrict__ a1d,
    float* __restrict__ asrc1, float* __restrict__ adst1,
    const int* __restrict__ ei, int* __restrict__ deg) {
  int gb = blockIdx.x;
  if (gb < HB) {
    // grid-strided histogram: starts immediately, finishes in ~8us, hides
    // under the GEMM blocks that own the machine afterwards
    for (int e = gb * 256 + threadIdx.x; e < E_TOT; e += HB * 256) {
      int d = (e < N_EDGES) ? ei[N_EDGES + e] : (e - N_EDGES);
      atomicAdd(&deg[d], 1);
    }
  } else {
    gb -= HB;
    gemm_body<2, 2, 128, true, 1>(gb % GBM, gb / GBM, x, W1t, h1, N_NODES, 256,
                                  a1s, a1d, asrc1, adst1);
  }
}

__global__ __launch_bounds__(256) void gemm2_kernel(
    const ushort_t* __restrict__ a1b, const ushort_t* __restrict__ W2t,
    ushort_t* __restrict__ h2,
    const float* __restrict__ a2s, const float* __restrict__ a2d,
    float* __restrict__ asrc2, float* __restrict__ adst2) {
  gemm_body<4, 1, 256, false, 2>(blockIdx.x, 0, a1b, W2t, h2, N_NODES, 64,
                                 a2s, a2d, asrc2, adst2);
}

// ---------------- single-pass decoupled-lookback scan ----------------

__global__ __launch_bounds__(1024) void scan_lookback(
    const int* __restrict__ deg, ull_t* __restrict__ state,
    int* __restrict__ rowptr, int* __restrict__ fillpos) {
  __shared__ int sh[1024];
  __shared__ int boff_sh;
  const int tid = threadIdx.x;
  const int bid = blockIdx.x;
  int i = bid * 1024 + tid;
  int v = (i < N_NODES) ? deg[i] : 0;
  sh[tid] = v;
  __syncthreads();
  for (int off = 1; off < 1024; off <<= 1) {
    int t = (tid >= off) ? sh[tid - off] : 0;
    __syncthreads();
    sh[tid] += t;
    __syncthreads();
  }
  if (tid == 0) {
    int total = sh[1023];
    atomicExch(&state[bid], (1ULL << 32) | (unsigned int)total);
    long long excl = 0;
    int p = bid - 1;
    while (p >= 0) {
      ull_t st;
      do { st = atomicAdd(&state[p], 0ULL); } while (st == 0);
      excl += (int)(st & 0xffffffffULL);
      if ((st >> 32) == 2) break;
      --p;
    }
    atomicExch(&state[bid], (2ULL << 32) | (unsigned int)(excl + total));
    boff_sh = (int)excl;
  }
  __syncthreads();
  if (i < N_NODES) {
    int excl = sh[tid] - v + boff_sh;
    rowptr[i] = excl;
    fillpos[i] = excl;
    if (i == N_NODES - 1) rowptr[N_NODES] = excl + v;
  }
}

__global__ void fill_kernel(const int* __restrict__ ei, int* __restrict__ fillpos,
                            int* __restrict__ col) {
  int e = blockIdx.x * 256 + threadIdx.x;
  if (e >= E_TOT) return;
  int s, d;
  if (e < N_EDGES) { s = ei[e]; d = ei[N_EDGES + e]; }
  else { s = d = e - N_EDGES; }
  int p = atomicAdd(&fillpos[d], 1);
  col[p] = s;
}

// ---------------- fused softmax + aggregation ----------------

// layer 1: lane = 4 channels (C=256, 512B rows); fused relu(acc+b1) -> bf16
__global__ __launch_bounds__(256) void fused_agg1(
    const ushort_t* __restrict__ h, const int* __restrict__ rowptr,
    const int* __restrict__ col, const float* __restrict__ asrc,
    const float* __restrict__ adst, const float* __restrict__ bias,
    ushort_t* __restrict__ out) {
  __shared__ float wlds[4][64];
  __shared__ int clds[4][64];
  int wid = threadIdx.x >> 6;
  int n = blockIdx.x * 4 + wid;
  if (n >= N_NODES) return;
  int lane = threadIdx.x & 63;
  int beg = rowptr[n], end = rowptr[n + 1];
  int deg = end - beg;
  float ad = adst[n];
  float we = 0.f;
  int s = 0;
  if (lane < deg) { s = col[beg + lane]; we = __expf(leaky(asrc[s] + ad)); }
  float ssum = we;
  for (int jj = beg + 64 + lane; jj < end; jj += 64)   // essentially never
    ssum += __expf(leaky(asrc[col[jj]] + ad));
#pragma unroll
  for (int off = 32; off; off >>= 1) ssum += __shfl_xor(ssum, off);
  float inv = 1.0f / ssum;
  wlds[wid][lane] = we * inv;
  clds[wid][lane] = s << 9;   // byte offset of 512B row
  float a0 = 0.f, a1 = 0.f, a2 = 0.f, a3 = 0.f;
  const char* hb = (const char*)h + lane * 8;
  if (deg <= 64) {
    int t = 0;
    for (; t + 8 <= deg; t += 8) {
      int4 cA = *reinterpret_cast<const int4*>(&clds[wid][t]);
      int4 cB = *reinterpret_cast<const int4*>(&clds[wid][t + 4]);
      float4 wA = *reinterpret_cast<const float4*>(&wlds[wid][t]);
      float4 wB = *reinterpret_cast<const float4*>(&wlds[wid][t + 4]);
      ushort4 u0 = *reinterpret_cast<const ushort4*>(hb + cA.x);
      ushort4 u1 = *reinterpret_cast<const ushort4*>(hb + cA.y);
      ushort4 u2 = *reinterpret_cast<const ushort4*>(hb + cA.z);
      ushort4 u3 = *reinterpret_cast<const ushort4*>(hb + cA.w);
      ushort4 u4 = *reinterpret_cast<const ushort4*>(hb + cB.x);
      ushort4 u5 = *reinterpret_cast<const ushort4*>(hb + cB.y);
      ushort4 u6 = *reinterpret_cast<const ushort4*>(hb + cB.z);
      ushort4 u7 = *reinterpret_cast<const ushort4*>(hb + cB.w);
      a0 += wA.x * b2f(u0.x) + wA.y * b2f(u1.x) + wA.z * b2f(u2.x) + wA.w * b2f(u3.x)
          + wB.x * b2f(u4.x) + wB.y * b2f(u5.x) + wB.z * b2f(u6.x) + wB.w * b2f(u7.x);
      a1 += wA.x * b2f(u0.y) + wA.y * b2f(u1.y) + wA.z * b2f(u2.y) + wA.w * b2f(u3.y)
          + wB.x * b2f(u4.y) + wB.y * b2f(u5.y) + wB.z * b2f(u6.y) + wB.w * b2f(u7.y);
      a2 += wA.x * b2f(u0.z) + wA.y * b2f(u1.z) + wA.z * b2f(u2.z) + wA.w * b2f(u3.z)
          + wB.x * b2f(u4.z) + wB.y * b2f(u5.z) + wB.z * b2f(u6.z) + wB.w * b2f(u7.z);
      a3 += wA.x * b2f(u0.w) + wA.y * b2f(u1.w) + wA.z * b2f(u2.w) + wA.w * b2f(u3.w)
          + wB.x * b2f(u4.w) + wB.y * b2f(u5.w) + wB.z * b2f(u6.w) + wB.w * b2f(u7.w);
    }
    for (; t < deg; ++t) {
      int c = clds[wid][t];
      float w = wlds[wid][t];
      ushort4 u = *reinterpret_cast<const ushort4*>(hb + c);
      a0 += w * b2f(u.x); a1 += w * b2f(u.y);
      a2 += w * b2f(u.z); a3 += w * b2f(u.w);
    }
  } else {  // deg > 64: recompute weights (astronomically rare)
    for (int j = beg; j < end; ++j) {
      int sj = col[j];
      float w = __expf(leaky(asrc[sj] + ad)) * inv;
      ushort4 u = *reinterpret_cast<const ushort4*>(&h[(size_t)sj * 256 + lane * 4]);
      a0 += w * b2f(u.x); a1 += w * b2f(u.y);
      a2 += w * b2f(u.z); a3 += w * b2f(u.w);
    }
  }
  float4 bv = *reinterpret_cast<const float4*>(&bias[lane * 4]);
  ushort4 o;
  o.x = f2b(fmaxf(a0 + bv.x, 0.f));
  o.y = f2b(fmaxf(a1 + bv.y, 0.f));
  o.z = f2b(fmaxf(a2 + bv.z, 0.f));
  o.w = f2b(fmaxf(a3 + bv.w, 0.f));
  *reinterpret_cast<ushort4*>(&out[(size_t)n * 256 + lane * 4]) = o;
}

// layer 2: lane = 1 channel (C=64, 128B rows); fused +bias, final fp32 out
__global__ __launch_bounds__(256) void fused_agg2(
    const ushort_t* __restrict__ h, const int* __restrict__ rowptr,
    const int* __restrict__ col, const float* __restrict__ asrc,
    const float* __restrict__ adst, const float* __restrict__ bias,
    float* __restrict__ out) {
  __shared__ float wlds[4][64];
  __shared__ int clds[4][64];
  int wid = threadIdx.x >> 6;
  int n = blockIdx.x * 4 + wid;
  if (n >= N_NODES) return;
  int lane = threadIdx.x & 63;
  int beg = rowptr[n], end = rowptr[n + 1];
  int deg = end - beg;
  float ad = adst[n];
  float we = 0.f;
  int s = 0;
  if (lane < deg) { s = col[beg + lane]; we = __expf(leaky(asrc[s] + ad)); }
  float ssum = we;
  for (int jj = beg + 64 + lane; jj < end; jj += 64)
    ssum += __expf(leaky(asrc[col[jj]] + ad));
#pragma unroll
  for (int off = 32; off; off >>= 1) ssum += __shfl_xor(ssum, off);
  float inv = 1.0f / ssum;
  wlds[wid][lane] = we * inv;
  clds[wid][lane] = s << 7;   // byte offset of 128B row
  float acc = 0.f;
  const char* hb = (const char*)h + lane * 2;
  if (deg <= 64) {
    int t = 0;
    for (; t + 8 <= deg; t += 8) {
      int4 cA = *reinterpret_cast<const int4*>(&clds[wid][t]);
      int4 cB = *reinterpret_cast<const int4*>(&clds[wid][t + 4]);
      float4 wA = *reinterpret_cast<const float4*>(&wlds[wid][t]);
      float4 wB = *reinterpret_cast<const float4*>(&wlds[wid][t + 4]);
      ushort_t u0 = *reinterpret_cast<const ushort_t*>(hb + cA.x);
      ushort_t u1 = *reinterpret_cast<const ushort_t*>(hb + cA.y);
      ushort_t u2 = *reinterpret_cast<const ushort_t*>(hb + cA.z);
      ushort_t u3 = *reinterpret_cast<const ushort_t*>(hb + cA.w);
      ushort_t u4 = *reinterpret_cast<const ushort_t*>(hb + cB.x);
      ushort_t u5 = *reinterpret_cast<const ushort_t*>(hb + cB.y);
      ushort_t u6 = *reinterpret_cast<const ushort_t*>(hb + cB.z);
      ushort_t u7 = *reinterpret_cast<const ushort_t*>(hb + cB.w);
      acc += wA.x * b2f(u0) + wA.y * b2f(u1) + wA.z * b2f(u2) + wA.w * b2f(u3)
           + wB.x * b2f(u4) + wB.y * b2f(u5) + wB.z * b2f(u6) + wB.w * b2f(u7);
    }
    for (; t < deg; ++t)
      acc += wlds[wid][t] * b2f(*reinterpret_cast<const ushort_t*>(hb + clds[wid][t]));
  } else {
    for (int j = beg; j < end; ++j) {
      int sj = col[j];
      float w = __expf(leaky(asrc[sj] + ad)) * inv;
      acc += w * b2f(h[(size_t)sj * 64 + lane]);
    }
  }
  out[(size_t)n * 64 + lane] = acc + bias[lane];
}

// ---------------- launch ----------------

extern "C" void kernel_launch(void* const* d_in, const int* in_sizes, int n_in,
                              void* d_out, int out_size, void* d_ws, size_t ws_size,
                              hipStream_t stream) {
  const float* x    = (const float*)d_in[0];
  const int*   ei   = (const int*)d_in[1];
  const float* W1   = (const float*)d_in[2];
  const float* a1s  = (const float*)d_in[3];
  const float* a1d  = (const float*)d_in[4];
  const float* b1   = (const float*)d_in[5];
  const float* W2   = (const float*)d_in[6];
  const float* a2s  = (const float*)d_in[7];
  const float* a2d  = (const float*)d_in[8];
  const float* b2   = (const float*)d_in[9];
  float* out = (float*)d_out;

  char* ws = (char*)d_ws;
  size_t off = 0;
  auto alloc = [&](size_t bytes) {
    void* p = ws + off;
    off += bytes;
    off = (off + 255) & ~(size_t)255;
    return p;
  };

  ushort_t* h1   = (ushort_t*)alloc((size_t)N_NODES * 256 * 2);  // bf16
  ushort_t* a1b  = (ushort_t*)alloc((size_t)N_NODES * 256 * 2);  // bf16 relu(agg1+b1)
  ushort_t* h2   = (ushort_t*)alloc((size_t)N_NODES * 64 * 2);   // bf16
  ushort_t* W1t  = (ushort_t*)alloc((size_t)256 * 128 * 2);
  ushort_t* W2t  = (ushort_t*)alloc((size_t)64 * 256 * 2);
  float* asrc1   = (float*)alloc((size_t)N_NODES * 4);
  float* adst1   = (float*)alloc((size_t)N_NODES * 4);
  int*   deg     = (int*)alloc((size_t)N_NODES * 4);
  float* asrc2   = (float*)alloc((size_t)N_NODES * 4);
  float* adst2   = (float*)alloc((size_t)N_NODES * 4);
  int*   rowptr  = (int*)alloc((size_t)(N_NODES + 1) * 4);
  int*   fillp   = (int*)alloc((size_t)N_NODES * 4);
  int*   col     = (int*)alloc((size_t)E_TOT * 4);
  ull_t* state   = (ull_t*)alloc((size_t)SCAN_NB * 8);

  const int nodeBlocks4 = (N_NODES + 3) / 4;

  // 1. prep: zeros + weight transposes
  prep_kernel<<<1024, 256, 0, stream>>>(deg, asrc1, adst1, state, W1, W1t, W2, W2t);
  // 2. histogram (grid-strided, first) + GEMM1 (+ fused alpha)
  hist_gemm1<<<HB + GBM * 2, 256, 0, stream>>>(x, W1t, h1, a1s, a1d, asrc1, adst1, ei, deg);
  // 3. single-pass scan
  scan_lookback<<<SCAN_NB, 1024, 0, stream>>>(deg, state, rowptr, fillp);
  // 4. edge fill
  fill_kernel<<<EB, 256, 0, stream>>>(ei, fillp, col);
  // 5. layer-1 softmax+aggregate (+relu+bias -> bf16)
  fused_agg1<<<nodeBlocks4, 256, 0, stream>>>(h1, rowptr, col, asrc1, adst1, b1, a1b);
  // 6. GEMM2 (+ direct alpha)
  gemm2_kernel<<<GBM, 256, 0, stream>>>(a1b, W2t, h2, a2s, a2d, asrc2, adst2);
  // 7. layer-2 softmax+aggregate (+bias) -> out
  fused_agg2<<<nodeBlocks4, 256, 0, stream>>>(h2, rowptr, col, asrc2, adst2, b2, out);
}

// Round 12
// 306.887 us; speedup vs baseline: 1.0118x; 1.0118x over previous
//
#include <hip/hip_runtime.h>
#include <math.h>

#define N_NODES 100000
#define N_EDGES 800000
#define E_TOT (N_EDGES + N_NODES)
#define NEG_SLOPE 0.2f
#define SCAN_NB ((N_NODES + 1023) / 1024)
#define EB ((E_TOT + 255) / 256)
#define GBM1 ((N_NODES + 63) / 64)    // gemm1: BM=64, grid.y=2 folded in
#define GBM2 ((N_NODES + 127) / 128)  // gemm2: BM=128
#define HB 512   // grid-strided histogram blocks (first in merged grid)

typedef unsigned short ushort_t;
typedef unsigned long long ull_t;
typedef __attribute__((ext_vector_type(8))) short short8v;   // 8 bf16
typedef __attribute__((ext_vector_type(4))) float f32x4;

static __device__ __forceinline__ float leaky(float e) {
  return e > 0.f ? e : NEG_SLOPE * e;
}

static __device__ __forceinline__ float b2f(ushort_t u) {
  union { unsigned int i; float f; } x;
  x.i = ((unsigned int)u) << 16;
  return x.f;
}

static __device__ __forceinline__ ushort_t f2b(float f) {
  union { float f; unsigned int i; } x;
  x.f = f;
  unsigned int r = x.i + 0x7FFFu + ((x.i >> 16) & 1u);  // RNE (finite inputs)
  return (ushort_t)(r >> 16);
}

// ---------------- prep: zero buffers + weight transposes (absorbs memset) ----------------

__global__ void prep_kernel(int* __restrict__ deg, float* __restrict__ asrc1,
                            float* __restrict__ adst1, ull_t* __restrict__ state,
                            const float* __restrict__ W1, ushort_t* __restrict__ W1t,
                            const float* __restrict__ W2, ushort_t* __restrict__ W2t) {
  int g = blockIdx.x * 256 + threadIdx.x;
  const int GT = gridDim.x * 256;
  for (int i = g; i < N_NODES; i += GT) { deg[i] = 0; asrc1[i] = 0.f; adst1[i] = 0.f; }
  for (int i = g; i < 256 * 128; i += GT) {       // W1t[n][k] = W1[k][n]
    int n = i >> 7, k = i & 127;
    W1t[i] = f2b(W1[(size_t)k * 256 + n]);
  }
  for (int i = g; i < 64 * 256; i += GT) {        // W2t[n][k] = W2[k][n]
    int n = i >> 8, k = i & 255;
    W2t[i] = f2b(W2[(size_t)k * 64 + n]);
  }
  for (int i = g; i < SCAN_NB; i += GT) state[i] = 0;
}

// ---------------- barrier-free direct-MFMA GEMM body ----------------
// No LDS staging: A fragments loaded straight from global (row l&15, 32B/lane-quad
// contiguous -> 128B segments; L3 absorbs re-reads), B fragments re-read per kk
// from L2-hot transposed weights. Per-wave tile 32x64 (acc = 8 x f32x4 = 32 AGPR).
// ALPHA_MODE 1: per-row alpha partials, LDS-reduce + 2 global atomicAdds/row
// (exactly 2 contributions per address -> deterministic).
// ALPHA_MODE 2: single column-block covers all cols: direct store.

template <int WAVES_M, int WAVES_N, int KTOT, bool A_FP32, int ALPHA_MODE>
static __device__ void gemm_direct(
    int bx, int by,
    const void* __restrict__ Aptr, const ushort_t* __restrict__ Bt,
    ushort_t* __restrict__ Out, int M, int NTOT,
    const float* __restrict__ av_s, const float* __restrict__ av_d,
    float* __restrict__ os, float* __restrict__ od) {
  constexpr int M_REP = 2;
  constexpr int N_REP = 4;
  constexpr int WM = M_REP * 16;   // 32
  constexpr int WN = N_REP * 16;   // 64
  constexpr int BM = WAVES_M * WM;
  __shared__ float als_s[BM], als_d[BM];

  const int tid = threadIdx.x;
  const int lane = tid & 63;
  const int wid = tid >> 6;
  const int wm = wid % WAVES_M;
  const int wn = wid / WAVES_M;
  const int rowBase = bx * BM;
  const int colBase = by * (WAVES_N * WN) + wn * WN;
  const int l15 = lane & 15;
  const int l4 = lane >> 4;

  if (ALPHA_MODE == 1) {
    for (int rr = tid; rr < BM; rr += 256) { als_s[rr] = 0.f; als_d[rr] = 0.f; }
  }

  // clamped row addresses (garbage rows only feed never-stored acc entries)
  int grow[M_REP];
#pragma unroll
  for (int m = 0; m < M_REP; ++m) {
    int gr = rowBase + wm * WM + m * 16 + l15;
    grow[m] = gr < M ? gr : M - 1;
  }

  f32x4 acc[M_REP][N_REP] = {};

#pragma unroll
  for (int kk = 0; kk < KTOT / 32; ++kk) {
    const int k0 = kk * 32 + l4 * 8;
    short8v afr[M_REP];
#pragma unroll
    for (int m = 0; m < M_REP; ++m) {
      if (A_FP32) {
        const float* A = (const float*)Aptr;
        float4 f0 = *(const float4*)&A[(size_t)grow[m] * KTOT + k0];
        float4 f1 = *(const float4*)&A[(size_t)grow[m] * KTOT + k0 + 4];
        short8v u;
        u[0] = (short)f2b(f0.x); u[1] = (short)f2b(f0.y);
        u[2] = (short)f2b(f0.z); u[3] = (short)f2b(f0.w);
        u[4] = (short)f2b(f1.x); u[5] = (short)f2b(f1.y);
        u[6] = (short)f2b(f1.z); u[7] = (short)f2b(f1.w);
        afr[m] = u;
      } else {
        const ushort_t* A = (const ushort_t*)Aptr;
        afr[m] = *(const short8v*)&A[(size_t)grow[m] * KTOT + k0];
      }
    }
    short8v bfr[N_REP];
#pragma unroll
    for (int n = 0; n < N_REP; ++n)
      bfr[n] = *(const short8v*)&Bt[(size_t)(colBase + n * 16 + l15) * KTOT + k0];
#pragma unroll
    for (int m = 0; m < M_REP; ++m)
#pragma unroll
      for (int n = 0; n < N_REP; ++n)
        acc[m][n] = __builtin_amdgcn_mfma_f32_16x16x32_bf16(
            afr[m], bfr[n], acc[m][n], 0, 0, 0);
  }

  // C write: col=lane&15, row=(lane>>4)*4+reg
#pragma unroll
  for (int m = 0; m < M_REP; ++m) {
    int r0 = rowBase + wm * WM + m * 16 + l4 * 4;
#pragma unroll
    for (int n = 0; n < N_REP; ++n) {
      int gc = colBase + n * 16 + l15;
#pragma unroll
      for (int j = 0; j < 4; ++j) {
        int gr = r0 + j;
        if (gr < M) Out[(size_t)gr * NTOT + gc] = f2b(acc[m][n][j]);
      }
    }
  }
  // fused alpha epilogue
  if (ALPHA_MODE) {
    float as_v[N_REP], ad_v[N_REP];
#pragma unroll
    for (int n = 0; n < N_REP; ++n) {
      as_v[n] = av_s[colBase + n * 16 + l15];
      ad_v[n] = av_d[colBase + n * 16 + l15];
    }
#pragma unroll
    for (int m = 0; m < M_REP; ++m)
#pragma unroll
      for (int j = 0; j < 4; ++j) {
        float ss = 0.f, dd = 0.f;
#pragma unroll
        for (int n = 0; n < N_REP; ++n) {
          ss += acc[m][n][j] * as_v[n];
          dd += acc[m][n][j] * ad_v[n];
        }
#pragma unroll
        for (int o = 1; o < 16; o <<= 1) {
          ss += __shfl_xor(ss, o);
          dd += __shfl_xor(dd, o);
        }
        if (l15 == 0) {
          int rloc = wm * WM + m * 16 + l4 * 4 + j;
          if (ALPHA_MODE == 1) {
            atomicAdd(&als_s[rloc], ss);
            atomicAdd(&als_d[rloc], dd);
          } else {
            int gr = rowBase + rloc;
            if (gr < M) { os[gr] = ss; od[gr] = dd; }
          }
        }
      }
    if (ALPHA_MODE == 1) {
      __syncthreads();
      for (int rr = tid; rr < BM; rr += 256) {
        int gr = rowBase + rr;
        if (gr < M) {
          atomicAdd(&os[gr], als_s[rr]);
          atomicAdd(&od[gr], als_d[rr]);
        }
      }
    }
  }
}

// ---------------- merged dispatch: histogram (grid-strided, first) + GEMM1 ----------------

__global__ __launch_bounds__(256) void hist_gemm1(
    const float* __restrict__ x, const ushort_t* __restrict__ W1t,
    ushort_t* __restrict__ h1,
    const float* __restrict__ a1s, const float* __restrict__ a1d,
    float* __restrict__ asrc1, float* __restrict__ adst1,
    const int* __restrict__ ei, int* __restrict__ deg) {
  int gb = blockIdx.x;
  if (gb < HB) {
    for (int e = gb * 256 + threadIdx.x; e < E_TOT; e += HB * 256) {
      int d = (e < N_EDGES) ? ei[N_EDGES + e] : (e - N_EDGES);
      atomicAdd(&deg[d], 1);
    }
  } else {
    gb -= HB;
    gemm_direct<2, 2, 128, true, 1>(gb % GBM1, gb / GBM1, x, W1t, h1, N_NODES, 256,
                                    a1s, a1d, asrc1, adst1);
  }
}

__global__ __launch_bounds__(256) void gemm2_kernel(
    const ushort_t* __restrict__ a1b, const ushort_t* __restrict__ W2t,
    ushort_t* __restrict__ h2,
    const float* __restrict__ a2s, const float* __restrict__ a2d,
    float* __restrict__ asrc2, float* __restrict__ adst2) {
  gemm_direct<4, 1, 256, false, 2>(blockIdx.x, 0, a1b, W2t, h2, N_NODES, 64,
                                   a2s, a2d, asrc2, adst2);
}

// ---------------- single-pass decoupled-lookback scan ----------------

__global__ __launch_bounds__(1024) void scan_lookback(
    const int* __restrict__ deg, ull_t* __restrict__ state,
    int* __restrict__ rowptr, int* __restrict__ fillpos) {
  __shared__ int sh[1024];
  __shared__ int boff_sh;
  const int tid = threadIdx.x;
  const int bid = blockIdx.x;
  int i = bid * 1024 + tid;
  int v = (i < N_NODES) ? deg[i] : 0;
  sh[tid] = v;
  __syncthreads();
  for (int off = 1; off < 1024; off <<= 1) {
    int t = (tid >= off) ? sh[tid - off] : 0;
    __syncthreads();
    sh[tid] += t;
    __syncthreads();
  }
  if (tid == 0) {
    int total = sh[1023];
    atomicExch(&state[bid], (1ULL << 32) | (unsigned int)total);
    long long excl = 0;
    int p = bid - 1;
    while (p >= 0) {
      ull_t st;
      do { st = atomicAdd(&state[p], 0ULL); } while (st == 0);
      excl += (int)(st & 0xffffffffULL);
      if ((st >> 32) == 2) break;
      --p;
    }
    atomicExch(&state[bid], (2ULL << 32) | (unsigned int)(excl + total));
    boff_sh = (int)excl;
  }
  __syncthreads();
  if (i < N_NODES) {
    int excl = sh[tid] - v + boff_sh;
    rowptr[i] = excl;
    fillpos[i] = excl;
    if (i == N_NODES - 1) rowptr[N_NODES] = excl + v;
  }
}

__global__ void fill_kernel(const int* __restrict__ ei, int* __restrict__ fillpos,
                            int* __restrict__ col) {
  int e = blockIdx.x * 256 + threadIdx.x;
  if (e >= E_TOT) return;
  int s, d;
  if (e < N_EDGES) { s = ei[e]; d = ei[N_EDGES + e]; }
  else { s = d = e - N_EDGES; }
  int p = atomicAdd(&fillpos[d], 1);
  col[p] = s;
}

// ---------------- fused softmax + aggregation ----------------

// layer 1: lane = 4 channels (C=256, 512B rows); fused relu(acc+b1) -> bf16
__global__ __launch_bounds__(256) void fused_agg1(
    const ushort_t* __restrict__ h, const int* __restrict__ rowptr,
    const int* __restrict__ col, const float* __restrict__ asrc,
    const float* __restrict__ adst, const float* __restrict__ bias,
    ushort_t* __restrict__ out) {
  __shared__ float wlds[4][64];
  __shared__ int clds[4][64];
  int wid = threadIdx.x >> 6;
  int n = blockIdx.x * 4 + wid;
  if (n >= N_NODES) return;
  int lane = threadIdx.x & 63;
  int beg = rowptr[n], end = rowptr[n + 1];
  int deg = end - beg;
  float ad = adst[n];
  float we = 0.f;
  int s = 0;
  if (lane < deg) { s = col[beg + lane]; we = __expf(leaky(asrc[s] + ad)); }
  float ssum = we;
  for (int jj = beg + 64 + lane; jj < end; jj += 64)   // essentially never
    ssum += __expf(leaky(asrc[col[jj]] + ad));
#pragma unroll
  for (int off = 32; off; off >>= 1) ssum += __shfl_xor(ssum, off);
  float inv = 1.0f / ssum;
  wlds[wid][lane] = we * inv;
  clds[wid][lane] = s << 9;   // byte offset of 512B row
  float a0 = 0.f, a1 = 0.f, a2 = 0.f, a3 = 0.f;
  const char* hb = (const char*)h + lane * 8;
  if (deg <= 64) {
    int t = 0;
    for (; t + 8 <= deg; t += 8) {
      int4 cA = *reinterpret_cast<const int4*>(&clds[wid][t]);
      int4 cB = *reinterpret_cast<const int4*>(&clds[wid][t + 4]);
      float4 wA = *reinterpret_cast<const float4*>(&wlds[wid][t]);
      float4 wB = *reinterpret_cast<const float4*>(&wlds[wid][t + 4]);
      ushort4 u0 = *reinterpret_cast<const ushort4*>(hb + cA.x);
      ushort4 u1 = *reinterpret_cast<const ushort4*>(hb + cA.y);
      ushort4 u2 = *reinterpret_cast<const ushort4*>(hb + cA.z);
      ushort4 u3 = *reinterpret_cast<const ushort4*>(hb + cA.w);
      ushort4 u4 = *reinterpret_cast<const ushort4*>(hb + cB.x);
      ushort4 u5 = *reinterpret_cast<const ushort4*>(hb + cB.y);
      ushort4 u6 = *reinterpret_cast<const ushort4*>(hb + cB.z);
      ushort4 u7 = *reinterpret_cast<const ushort4*>(hb + cB.w);
      a0 += wA.x * b2f(u0.x) + wA.y * b2f(u1.x) + wA.z * b2f(u2.x) + wA.w * b2f(u3.x)
          + wB.x * b2f(u4.x) + wB.y * b2f(u5.x) + wB.z * b2f(u6.x) + wB.w * b2f(u7.x);
      a1 += wA.x * b2f(u0.y) + wA.y * b2f(u1.y) + wA.z * b2f(u2.y) + wA.w * b2f(u3.y)
          + wB.x * b2f(u4.y) + wB.y * b2f(u5.y) + wB.z * b2f(u6.y) + wB.w * b2f(u7.y);
      a2 += wA.x * b2f(u0.z) + wA.y * b2f(u1.z) + wA.z * b2f(u2.z) + wA.w * b2f(u3.z)
          + wB.x * b2f(u4.z) + wB.y * b2f(u5.z) + wB.z * b2f(u6.z) + wB.w * b2f(u7.z);
      a3 += wA.x * b2f(u0.w) + wA.y * b2f(u1.w) + wA.z * b2f(u2.w) + wA.w * b2f(u3.w)
          + wB.x * b2f(u4.w) + wB.y * b2f(u5.w) + wB.z * b2f(u6.w) + wB.w * b2f(u7.w);
    }
    for (; t < deg; ++t) {
      int c = clds[wid][t];
      float w = wlds[wid][t];
      ushort4 u = *reinterpret_cast<const ushort4*>(hb + c);
      a0 += w * b2f(u.x); a1 += w * b2f(u.y);
      a2 += w * b2f(u.z); a3 += w * b2f(u.w);
    }
  } else {  // deg > 64: recompute weights (astronomically rare)
    for (int j = beg; j < end; ++j) {
      int sj = col[j];
      float w = __expf(leaky(asrc[sj] + ad)) * inv;
      ushort4 u = *reinterpret_cast<const ushort4*>(&h[(size_t)sj * 256 + lane * 4]);
      a0 += w * b2f(u.x); a1 += w * b2f(u.y);
      a2 += w * b2f(u.z); a3 += w * b2f(u.w);
    }
  }
  float4 bv = *reinterpret_cast<const float4*>(&bias[lane * 4]);
  ushort4 o;
  o.x = f2b(fmaxf(a0 + bv.x, 0.f));
  o.y = f2b(fmaxf(a1 + bv.y, 0.f));
  o.z = f2b(fmaxf(a2 + bv.z, 0.f));
  o.w = f2b(fmaxf(a3 + bv.w, 0.f));
  *reinterpret_cast<ushort4*>(&out[(size_t)n * 256 + lane * 4]) = o;
}

// layer 2: lane = 1 channel (C=64, 128B rows); fused +bias, final fp32 out
__global__ __launch_bounds__(256) void fused_agg2(
    const ushort_t* __restrict__ h, const int* __restrict__ rowptr,
    const int* __restrict__ col, const float* __restrict__ asrc,
    const float* __restrict__ adst, const float* __restrict__ bias,
    float* __restrict__ out) {
  __shared__ float wlds[4][64];
  __shared__ int clds[4][64];
  int wid = threadIdx.x >> 6;
  int n = blockIdx.x * 4 + wid;
  if (n >= N_NODES) return;
  int lane = threadIdx.x & 63;
  int beg = rowptr[n], end = rowptr[n + 1];
  int deg = end - beg;
  float ad = adst[n];
  float we = 0.f;
  int s = 0;
  if (lane < deg) { s = col[beg + lane]; we = __expf(leaky(asrc[s] + ad)); }
  float ssum = we;
  for (int jj = beg + 64 + lane; jj < end; jj += 64)
    ssum += __expf(leaky(asrc[col[jj]] + ad));
#pragma unroll
  for (int off = 32; off; off >>= 1) ssum += __shfl_xor(ssum, off);
  float inv = 1.0f / ssum;
  wlds[wid][lane] = we * inv;
  clds[wid][lane] = s << 7;   // byte offset of 128B row
  float acc = 0.f;
  const char* hb = (const char*)h + lane * 2;
  if (deg <= 64) {
    int t = 0;
    for (; t + 8 <= deg; t += 8) {
      int4 cA = *reinterpret_cast<const int4*>(&clds[wid][t]);
      int4 cB = *reinterpret_cast<const int4*>(&clds[wid][t + 4]);
      float4 wA = *reinterpret_cast<const float4*>(&wlds[wid][t]);
      float4 wB = *reinterpret_cast<const float4*>(&wlds[wid][t + 4]);
      ushort_t u0 = *reinterpret_cast<const ushort_t*>(hb + cA.x);
      ushort_t u1 = *reinterpret_cast<const ushort_t*>(hb + cA.y);
      ushort_t u2 = *reinterpret_cast<const ushort_t*>(hb + cA.z);
      ushort_t u3 = *reinterpret_cast<const ushort_t*>(hb + cA.w);
      ushort_t u4 = *reinterpret_cast<const ushort_t*>(hb + cB.x);
      ushort_t u5 = *reinterpret_cast<const ushort_t*>(hb + cB.y);
      ushort_t u6 = *reinterpret_cast<const ushort_t*>(hb + cB.z);
      ushort_t u7 = *reinterpret_cast<const ushort_t*>(hb + cB.w);
      acc += wA.x * b2f(u0) + wA.y * b2f(u1) + wA.z * b2f(u2) + wA.w * b2f(u3)
           + wB.x * b2f(u4) + wB.y * b2f(u5) + wB.z * b2f(u6) + wB.w * b2f(u7);
    }
    for (; t < deg; ++t)
      acc += wlds[wid][t] * b2f(*reinterpret_cast<const ushort_t*>(hb + clds[wid][t]));
  } else {
    for (int j = beg; j < end; ++j) {
      int sj = col[j];
      float w = __expf(leaky(asrc[sj] + ad)) * inv;
      acc += w * b2f(h[(size_t)sj * 64 + lane]);
    }
  }
  out[(size_t)n * 64 + lane] = acc + bias[lane];
}

// ---------------- launch ----------------

extern "C" void kernel_launch(void* const* d_in, const int* in_sizes, int n_in,
                              void* d_out, int out_size, void* d_ws, size_t ws_size,
                              hipStream_t stream) {
  const float* x    = (const float*)d_in[0];
  const int*   ei   = (const int*)d_in[1];
  const float* W1   = (const float*)d_in[2];
  const float* a1s  = (const float*)d_in[3];
  const float* a1d  = (const float*)d_in[4];
  const float* b1   = (const float*)d_in[5];
  const float* W2   = (const float*)d_in[6];
  const float* a2s  = (const float*)d_in[7];
  const float* a2d  = (const float*)d_in[8];
  const float* b2   = (const float*)d_in[9];
  float* out = (float*)d_out;

  char* ws = (char*)d_ws;
  size_t off = 0;
  auto alloc = [&](size_t bytes) {
    void* p = ws + off;
    off += bytes;
    off = (off + 255) & ~(size_t)255;
    return p;
  };

  ushort_t* h1   = (ushort_t*)alloc((size_t)N_NODES * 256 * 2);  // bf16
  ushort_t* a1b  = (ushort_t*)alloc((size_t)N_NODES * 256 * 2);  // bf16 relu(agg1+b1)
  ushort_t* h2   = (ushort_t*)alloc((size_t)N_NODES * 64 * 2);   // bf16
  ushort_t* W1t  = (ushort_t*)alloc((size_t)256 * 128 * 2);
  ushort_t* W2t  = (ushort_t*)alloc((size_t)64 * 256 * 2);
  float* asrc1   = (float*)alloc((size_t)N_NODES * 4);
  float* adst1   = (float*)alloc((size_t)N_NODES * 4);
  int*   deg     = (int*)alloc((size_t)N_NODES * 4);
  float* asrc2   = (float*)alloc((size_t)N_NODES * 4);
  float* adst2   = (float*)alloc((size_t)N_NODES * 4);
  int*   rowptr  = (int*)alloc((size_t)(N_NODES + 1) * 4);
  int*   fillp   = (int*)alloc((size_t)N_NODES * 4);
  int*   col     = (int*)alloc((size_t)E_TOT * 4);
  ull_t* state   = (ull_t*)alloc((size_t)SCAN_NB * 8);

  const int nodeBlocks4 = (N_NODES + 3) / 4;

  // 1. prep: zeros + weight transposes
  prep_kernel<<<1024, 256, 0, stream>>>(deg, asrc1, adst1, state, W1, W1t, W2, W2t);
  // 2. histogram (grid-strided, first) + barrier-free GEMM1 (+ fused alpha)
  hist_gemm1<<<HB + GBM1 * 2, 256, 0, stream>>>(x, W1t, h1, a1s, a1d, asrc1, adst1, ei, deg);
  // 3. single-pass scan
  scan_lookback<<<SCAN_NB, 1024, 0, stream>>>(deg, state, rowptr, fillp);
  // 4. edge fill
  fill_kernel<<<EB, 256, 0, stream>>>(ei, fillp, col);
  // 5. layer-1 softmax+aggregate (+relu+bias -> bf16)
  fused_agg1<<<nodeBlocks4, 256, 0, stream>>>(h1, rowptr, col, asrc1, adst1, b1, a1b);
  // 6. barrier-free GEMM2 (+ direct alpha)
  gemm2_kernel<<<GBM2, 256, 0, stream>>>(a1b, W2t, h2, a2s, a2d, asrc2, adst2);
  // 7. layer-2 softmax+aggregate (+bias) -> out
  fused_agg2<<<nodeBlocks4, 256, 0, stream>>>(h2, rowptr, col, asrc2, adst2, b2, out);
}

// Round 13
// 302.174 us; speedup vs baseline: 1.0276x; 1.0156x over previous
//
#include <hip/hip_runtime.h>
#include <math.h>

#define N_NODES 100000
#define N_EDGES 800000
#define E_TOT (N_EDGES + N_NODES)
#define NEG_SLOPE 0.2f
#define SCAN_NB ((N_NODES + 1023) / 1024)
#define EB ((E_TOT + 255) / 256)
#define GBM ((N_NODES + 127) / 128)
#define HB 512    // histogram blocks (merged into cast_alpha dispatch)
#define CB 2048   // cast/alpha blocks

typedef unsigned short ushort_t;
typedef unsigned long long ull_t;
typedef __attribute__((ext_vector_type(8))) short short8v;   // 8 bf16
typedef __attribute__((ext_vector_type(4))) float f32x4;

static __device__ __forceinline__ float leaky(float e) {
  return e > 0.f ? e : NEG_SLOPE * e;
}

static __device__ __forceinline__ float b2f(ushort_t u) {
  union { unsigned int i; float f; } x;
  x.i = ((unsigned int)u) << 16;
  return x.f;
}

static __device__ __forceinline__ ushort_t f2b(float f) {
  union { float f; unsigned int i; } x;
  x.f = f;
  unsigned int r = x.i + 0x7FFFu + ((x.i >> 16) & 1u);  // RNE (finite inputs)
  return (ushort_t)(r >> 16);
}

// ---------------- prep: zeros + weight transposes + w1as/w1ad = W1 @ a1{s,d} ----------------

__global__ void prep_kernel(int* __restrict__ deg, ull_t* __restrict__ state,
                            const float* __restrict__ W1, ushort_t* __restrict__ W1t,
                            const float* __restrict__ W2, ushort_t* __restrict__ W2t,
                            const float* __restrict__ a1s, const float* __restrict__ a1d,
                            float* __restrict__ w1as, float* __restrict__ w1ad) {
  int g = blockIdx.x * 256 + threadIdx.x;
  const int GT = gridDim.x * 256;
  for (int i = g; i < N_NODES; i += GT) deg[i] = 0;
  for (int i = g; i < 256 * 128; i += GT) {       // W1t[n][k] = W1[k][n]
    int n = i >> 7, k = i & 127;
    W1t[i] = f2b(W1[(size_t)k * 256 + n]);
  }
  for (int i = g; i < 64 * 256; i += GT) {        // W2t[n][k] = W2[k][n]
    int n = i >> 8, k = i & 255;
    W2t[i] = f2b(W2[(size_t)k * 64 + n]);
  }
  for (int i = g; i < SCAN_NB; i += GT) state[i] = 0;
  if (g < 128) {                                  // w1as[k] = sum_n W1[k][n]*a1s[n]
    float ss = 0.f, dd = 0.f;
    for (int n = 0; n < 256; ++n) {
      float w = W1[(size_t)g * 256 + n];
      ss += w * a1s[n];
      dd += w * a1d[n];
    }
    w1as[g] = ss;
    w1ad[g] = dd;
  }
}

// ---------------- merged: x->bf16 cast + per-row alpha dots + degree histogram ----------------
// alpha1 via linearity: asrc1[n] = x[n]Β·(W1@a1s). Wave per row: lane covers
// cols {2l, 2l+1}; shfl-reduce; direct (non-atomic) writes.

__global__ __launch_bounds__(256) void cast_alpha_hist(
    const float* __restrict__ x, ushort_t* __restrict__ x_bf,
    const float* __restrict__ w1as, const float* __restrict__ w1ad,
    float* __restrict__ asrc1, float* __restrict__ adst1,
    const int* __restrict__ ei, int* __restrict__ deg) {
  int gb = blockIdx.x;
  if (gb < HB) {
    for (int e = gb * 256 + threadIdx.x; e < E_TOT; e += HB * 256) {
      int d = (e < N_EDGES) ? ei[N_EDGES + e] : (e - N_EDGES);
      atomicAdd(&deg[d], 1);
    }
    return;
  }
  gb -= HB;
  int lane = threadIdx.x & 63;
  int gwave = gb * 4 + (threadIdx.x >> 6);
  float ws0 = w1as[lane * 2], ws1 = w1as[lane * 2 + 1];
  float wd0 = w1ad[lane * 2], wd1 = w1ad[lane * 2 + 1];
  for (int n = gwave; n < N_NODES; n += CB * 4) {
    float2 v = *reinterpret_cast<const float2*>(&x[(size_t)n * 128 + lane * 2]);
    ushort2 o;
    o.x = f2b(v.x); o.y = f2b(v.y);
    *reinterpret_cast<ushort2*>(&x_bf[(size_t)n * 128 + lane * 2]) = o;
    float ps = v.x * ws0 + v.y * ws1;
    float pd = v.x * wd0 + v.y * wd1;
#pragma unroll
    for (int off = 32; off; off >>= 1) {
      ps += __shfl_xor(ps, off);
      pd += __shfl_xor(pd, off);
    }
    if (lane == 0) { asrc1[n] = ps; adst1[n] = pd; }
  }
}

// ---------------- single-pass decoupled-lookback scan ----------------

__global__ __launch_bounds__(1024) void scan_lookback(
    const int* __restrict__ deg, ull_t* __restrict__ state,
    int* __restrict__ rowptr, int* __restrict__ fillpos) {
  __shared__ int sh[1024];
  __shared__ int boff_sh;
  const int tid = threadIdx.x;
  const int bid = blockIdx.x;
  int i = bid * 1024 + tid;
  int v = (i < N_NODES) ? deg[i] : 0;
  sh[tid] = v;
  __syncthreads();
  for (int off = 1; off < 1024; off <<= 1) {
    int t = (tid >= off) ? sh[tid - off] : 0;
    __syncthreads();
    sh[tid] += t;
    __syncthreads();
  }
  if (tid == 0) {
    int total = sh[1023];
    atomicExch(&state[bid], (1ULL << 32) | (unsigned int)total);
    long long excl = 0;
    int p = bid - 1;
    while (p >= 0) {
      ull_t st;
      do { st = atomicAdd(&state[p], 0ULL); } while (st == 0);
      excl += (int)(st & 0xffffffffULL);
      if ((st >> 32) == 2) break;
      --p;
    }
    atomicExch(&state[bid], (2ULL << 32) | (unsigned int)(excl + total));
    boff_sh = (int)excl;
  }
  __syncthreads();
  if (i < N_NODES) {
    int excl = sh[tid] - v + boff_sh;
    rowptr[i] = excl;
    fillpos[i] = excl;
    if (i == N_NODES - 1) rowptr[N_NODES] = excl + v;
  }
}

__global__ void fill_kernel(const int* __restrict__ ei, int* __restrict__ fillpos,
                            int* __restrict__ col) {
  int e = blockIdx.x * 256 + threadIdx.x;
  if (e >= E_TOT) return;
  int s, d;
  if (e < N_EDGES) { s = ei[e]; d = ei[N_EDGES + e]; }
  else { s = d = e - N_EDGES; }
  int p = atomicAdd(&fillpos[d], 1);
  col[p] = s;
}

// ---------------- layer-1 aggregation over x_bf (256B rows) ----------------
// aggX[n] = sum_j alpha_j * x_bf[col_j]; lane covers 2 channels (ushort2).

__global__ __launch_bounds__(256) void fused_aggx(
    const ushort_t* __restrict__ xb, const int* __restrict__ rowptr,
    const int* __restrict__ col, const float* __restrict__ asrc,
    const float* __restrict__ adst, ushort_t* __restrict__ out) {
  __shared__ float wlds[4][64];
  __shared__ int clds[4][64];
  int wid = threadIdx.x >> 6;
  int n = blockIdx.x * 4 + wid;
  if (n >= N_NODES) return;
  int lane = threadIdx.x & 63;
  int beg = rowptr[n], end = rowptr[n + 1];
  int deg = end - beg;
  float ad = adst[n];
  float we = 0.f;
  int s = 0;
  if (lane < deg) { s = col[beg + lane]; we = __expf(leaky(asrc[s] + ad)); }
  float ssum = we;
  for (int jj = beg + 64 + lane; jj < end; jj += 64)   // essentially never
    ssum += __expf(leaky(asrc[col[jj]] + ad));
#pragma unroll
  for (int off = 32; off; off >>= 1) ssum += __shfl_xor(ssum, off);
  float inv = 1.0f / ssum;
  wlds[wid][lane] = we * inv;
  clds[wid][lane] = s << 8;   // byte offset of 256B row
  float a0 = 0.f, a1 = 0.f;
  const char* hb = (const char*)xb + lane * 4;
  if (deg <= 64) {
    int t = 0;
    for (; t + 8 <= deg; t += 8) {
      int4 cA = *reinterpret_cast<const int4*>(&clds[wid][t]);
      int4 cB = *reinterpret_cast<const int4*>(&clds[wid][t + 4]);
      float4 wA = *reinterpret_cast<const float4*>(&wlds[wid][t]);
      float4 wB = *reinterpret_cast<const float4*>(&wlds[wid][t + 4]);
      ushort2 u0 = *reinterpret_cast<const ushort2*>(hb + cA.x);
      ushort2 u1 = *reinterpret_cast<const ushort2*>(hb + cA.y);
      ushort2 u2 = *reinterpret_cast<const ushort2*>(hb + cA.z);
      ushort2 u3 = *reinterpret_cast<const ushort2*>(hb + cA.w);
      ushort2 u4 = *reinterpret_cast<const ushort2*>(hb + cB.x);
      ushort2 u5 = *reinterpret_cast<const ushort2*>(hb + cB.y);
      ushort2 u6 = *reinterpret_cast<const ushort2*>(hb + cB.z);
      ushort2 u7 = *reinterpret_cast<const ushort2*>(hb + cB.w);
      a0 += wA.x * b2f(u0.x) + wA.y * b2f(u1.x) + wA.z * b2f(u2.x) + wA.w * b2f(u3.x)
          + wB.x * b2f(u4.x) + wB.y * b2f(u5.x) + wB.z * b2f(u6.x) + wB.w * b2f(u7.x);
      a1 += wA.x * b2f(u0.y) + wA.y * b2f(u1.y) + wA.z * b2f(u2.y) + wA.w * b2f(u3.y)
          + wB.x * b2f(u4.y) + wB.y * b2f(u5.y) + wB.z * b2f(u6.y) + wB.w * b2f(u7.y);
    }
    for (; t < deg; ++t) {
      int c = clds[wid][t];
      float w = wlds[wid][t];
      ushort2 u = *reinterpret_cast<const ushort2*>(hb + c);
      a0 += w * b2f(u.x);
      a1 += w * b2f(u.y);
    }
  } else {  // deg > 64: recompute weights (astronomically rare)
    for (int j = beg; j < end; ++j) {
      int sj = col[j];
      float w = __expf(leaky(asrc[sj] + ad)) * inv;
      ushort2 u = *reinterpret_cast<const ushort2*>(&xb[(size_t)sj * 128 + lane * 2]);
      a0 += w * b2f(u.x);
      a1 += w * b2f(u.y);
    }
  }
  ushort2 o;
  o.x = f2b(a0);
  o.y = f2b(a1);
  *reinterpret_cast<ushort2*>(&out[(size_t)n * 128 + lane * 2]) = o;
}

// ---------------- staged MFMA GEMM (bf16 A) ----------------
// RELU_BIAS: out = relu(acc + bias). ALPHA_MODE 2: direct alpha store (NTOT<=64).

template <int WAVES_M, int WAVES_N, int KTOT, bool RELU_BIAS, int ALPHA_MODE>
__global__ __launch_bounds__(256) void mfma_gemm(
    const ushort_t* __restrict__ A, const ushort_t* __restrict__ Bt,
    const float* __restrict__ bias, ushort_t* __restrict__ Out, int M, int NTOT,
    const float* __restrict__ av_s, const float* __restrict__ av_d,
    float* __restrict__ os, float* __restrict__ od) {
  constexpr int BM = 128;
  constexpr int WN = 64;
  constexpr int WM = BM / WAVES_M;
  constexpr int M_REP = WM / 16;
  constexpr int N_REP = WN / 16;
  constexpr int KC = 128;
  __shared__ ushort_t As[BM * KC];

  const int tid = threadIdx.x;
  const int lane = tid & 63;
  const int wid = tid >> 6;
  const int wm = wid % WAVES_M;
  const int wn = wid / WAVES_M;
  const int rowBase = blockIdx.x * BM;
  const int colBase = blockIdx.y * (WAVES_N * WN) + wn * WN;
  const int l15 = lane & 15;
  const int l4 = lane >> 4;

  f32x4 acc[M_REP][N_REP] = {};

  for (int kc = 0; kc < KTOT; kc += KC) {
    if (kc) __syncthreads();
    for (int c = tid; c < BM * KC / 8; c += 256) {
      int r = c >> 4;
      int k8 = (c & 15) << 3;
      int gr = rowBase + r;
      short8v u = {};
      if (gr < M) u = *(const short8v*)&A[(size_t)gr * KTOT + kc + k8];
      int byte = (r * KC + k8) * 2;
      byte ^= (r & 7) << 4;  // G4 swizzle
      *(short8v*)((char*)As + byte) = u;
    }
    short8v bfr[KC / 32][N_REP];
#pragma unroll
    for (int kk = 0; kk < KC / 32; ++kk)
#pragma unroll
      for (int n = 0; n < N_REP; ++n) {
        int bcol = colBase + n * 16 + l15;
        int k0 = kc + kk * 32 + l4 * 8;
        bfr[kk][n] = *(const short8v*)&Bt[(size_t)bcol * KTOT + k0];
      }
    __syncthreads();
#pragma unroll
    for (int kk = 0; kk < KC / 32; ++kk) {
      short8v afr[M_REP];
#pragma unroll
      for (int m = 0; m < M_REP; ++m) {
        int r = wm * WM + m * 16 + l15;
        int k0 = kk * 32 + l4 * 8;
        int byte = ((r * KC + k0) * 2) ^ ((r & 7) << 4);
        afr[m] = *(const short8v*)((const char*)As + byte);
      }
#pragma unroll
      for (int m = 0; m < M_REP; ++m)
#pragma unroll
        for (int n = 0; n < N_REP; ++n)
          acc[m][n] = __builtin_amdgcn_mfma_f32_16x16x32_bf16(
              afr[m], bfr[kk][n], acc[m][n], 0, 0, 0);
    }
  }
  // epilogue: C/D layout col=lane&15, row=(lane>>4)*4+reg
#pragma unroll
  for (int m = 0; m < M_REP; ++m) {
    int r0 = rowBase + wm * WM + m * 16 + l4 * 4;
#pragma unroll
    for (int n = 0; n < N_REP; ++n) {
      int gc = colBase + n * 16 + l15;
      float bv = RELU_BIAS ? bias[gc] : 0.f;
#pragma unroll
      for (int j = 0; j < 4; ++j) {
        int gr = r0 + j;
        float v = acc[m][n][j];
        if (RELU_BIAS) v = fmaxf(v + bv, 0.f);
        if (gr < M) Out[(size_t)gr * NTOT + gc] = f2b(v);
        acc[m][n][j] = v;   // alpha epilogue uses post-activation value
      }
    }
  }
  if (ALPHA_MODE == 2) {
    float as_v[N_REP], ad_v[N_REP];
#pragma unroll
    for (int n = 0; n < N_REP; ++n) {
      as_v[n] = av_s[colBase + n * 16 + l15];
      ad_v[n] = av_d[colBase + n * 16 + l15];
    }
#pragma unroll
    for (int m = 0; m < M_REP; ++m)
#pragma unroll
      for (int j = 0; j < 4; ++j) {
        float ss = 0.f, dd = 0.f;
#pragma unroll
        for (int n = 0; n < N_REP; ++n) {
          ss += acc[m][n][j] * as_v[n];
          dd += acc[m][n][j] * ad_v[n];
        }
#pragma unroll
        for (int o = 1; o < 16; o <<= 1) {
          ss += __shfl_xor(ss, o);
          dd += __shfl_xor(dd, o);
        }
        if (l15 == 0) {
          int gr = rowBase + wm * WM + m * 16 + l4 * 4 + j;
          if (gr < M) { os[gr] = ss; od[gr] = dd; }
        }
      }
  }
}

// ---------------- layer-2 aggregation (h2 rows, 128B) ----------------

__global__ __launch_bounds__(256) void fused_agg2(
    const ushort_t* __restrict__ h, const int* __restrict__ rowptr,
    const int* __restrict__ col, const float* __restrict__ asrc,
    const float* __restrict__ adst, const float* __restrict__ bias,
    float* __restrict__ out) {
  __shared__ float wlds[4][64];
  __shared__ int clds[4][64];
  int wid = threadIdx.x >> 6;
  int n = blockIdx.x * 4 + wid;
  if (n >= N_NODES) return;
  int lane = threadIdx.x & 63;
  int beg = rowptr[n], end = rowptr[n + 1];
  int deg = end - beg;
  float ad = adst[n];
  float we = 0.f;
  int s = 0;
  if (lane < deg) { s = col[beg + lane]; we = __expf(leaky(asrc[s] + ad)); }
  float ssum = we;
  for (int jj = beg + 64 + lane; jj < end; jj += 64)
    ssum += __expf(leaky(asrc[col[jj]] + ad));
#pragma unroll
  for (int off = 32; off; off >>= 1) ssum += __shfl_xor(ssum, off);
  float inv = 1.0f / ssum;
  wlds[wid][lane] = we * inv;
  clds[wid][lane] = s << 7;   // byte offset of 128B row
  float acc = 0.f;
  const char* hb = (const char*)h + lane * 2;
  if (deg <= 64) {
    int t = 0;
    for (; t + 8 <= deg; t += 8) {
      int4 cA = *reinterpret_cast<const int4*>(&clds[wid][t]);
      int4 cB = *reinterpret_cast<const int4*>(&clds[wid][t + 4]);
      float4 wA = *reinterpret_cast<const float4*>(&wlds[wid][t]);
      float4 wB = *reinterpret_cast<const float4*>(&wlds[wid][t + 4]);
      ushort_t u0 = *reinterpret_cast<const ushort_t*>(hb + cA.x);
      ushort_t u1 = *reinterpret_cast<const ushort_t*>(hb + cA.y);
      ushort_t u2 = *reinterpret_cast<const ushort_t*>(hb + cA.z);
      ushort_t u3 = *reinterpret_cast<const ushort_t*>(hb + cA.w);
      ushort_t u4 = *reinterpret_cast<const ushort_t*>(hb + cB.x);
      ushort_t u5 = *reinterpret_cast<const ushort_t*>(hb + cB.y);
      ushort_t u6 = *reinterpret_cast<const ushort_t*>(hb + cB.z);
      ushort_t u7 = *reinterpret_cast<const ushort_t*>(hb + cB.w);
      acc += wA.x * b2f(u0) + wA.y * b2f(u1) + wA.z * b2f(u2) + wA.w * b2f(u3)
           + wB.x * b2f(u4) + wB.y * b2f(u5) + wB.z * b2f(u6) + wB.w * b2f(u7);
    }
    for (; t < deg; ++t)
      acc += wlds[wid][t] * b2f(*reinterpret_cast<const ushort_t*>(hb + clds[wid][t]));
  } else {
    for (int j = beg; j < end; ++j) {
      int sj = col[j];
      float w = __expf(leaky(asrc[sj] + ad)) * inv;
      acc += w * b2f(h[(size_t)sj * 64 + lane]);
    }
  }
  out[(size_t)n * 64 + lane] = acc + bias[lane];
}

// ---------------- launch ----------------

extern "C" void kernel_launch(void* const* d_in, const int* in_sizes, int n_in,
                              void* d_out, int out_size, void* d_ws, size_t ws_size,
                              hipStream_t stream) {
  const float* x    = (const float*)d_in[0];
  const int*   ei   = (const int*)d_in[1];
  const float* W1   = (const float*)d_in[2];
  const float* a1s  = (const float*)d_in[3];
  const float* a1d  = (const float*)d_in[4];
  const float* b1   = (const float*)d_in[5];
  const float* W2   = (const float*)d_in[6];
  const float* a2s  = (const float*)d_in[7];
  const float* a2d  = (const float*)d_in[8];
  const float* b2   = (const float*)d_in[9];
  float* out = (float*)d_out;

  char* ws = (char*)d_ws;
  size_t off = 0;
  auto alloc = [&](size_t bytes) {
    void* p = ws + off;
    off += bytes;
    off = (off + 255) & ~(size_t)255;
    return p;
  };

  ushort_t* x_bf = (ushort_t*)alloc((size_t)N_NODES * 128 * 2);  // bf16 x
  ushort_t* aggX = (ushort_t*)alloc((size_t)N_NODES * 128 * 2);  // bf16 sum(alpha*x)
  ushort_t* a1b  = (ushort_t*)alloc((size_t)N_NODES * 256 * 2);  // bf16 relu(aggX@W1+b1)
  ushort_t* h2   = (ushort_t*)alloc((size_t)N_NODES * 64 * 2);   // bf16
  ushort_t* W1t  = (ushort_t*)alloc((size_t)256 * 128 * 2);
  ushort_t* W2t  = (ushort_t*)alloc((size_t)64 * 256 * 2);
  float* w1as    = (float*)alloc((size_t)128 * 4);
  float* w1ad    = (float*)alloc((size_t)128 * 4);
  float* asrc1   = (float*)alloc((size_t)N_NODES * 4);
  float* adst1   = (float*)alloc((size_t)N_NODES * 4);
  float* asrc2   = (float*)alloc((size_t)N_NODES * 4);
  float* adst2   = (float*)alloc((size_t)N_NODES * 4);
  int*   deg     = (int*)alloc((size_t)N_NODES * 4);
  int*   rowptr  = (int*)alloc((size_t)(N_NODES + 1) * 4);
  int*   fillp   = (int*)alloc((size_t)N_NODES * 4);
  int*   col     = (int*)alloc((size_t)E_TOT * 4);
  ull_t* state   = (ull_t*)alloc((size_t)SCAN_NB * 8);

  const int nodeBlocks4 = (N_NODES + 3) / 4;

  // 1. prep: zeros + W transposes + w1as/w1ad
  prep_kernel<<<1024, 256, 0, stream>>>(deg, state, W1, W1t, W2, W2t,
                                        a1s, a1d, w1as, w1ad);
  // 2. x->bf16 + alpha1 row-dots + degree histogram (merged)
  cast_alpha_hist<<<HB + CB, 256, 0, stream>>>(x, x_bf, w1as, w1ad,
                                               asrc1, adst1, ei, deg);
  // 3. single-pass scan
  scan_lookback<<<SCAN_NB, 1024, 0, stream>>>(deg, state, rowptr, fillp);
  // 4. edge fill
  fill_kernel<<<EB, 256, 0, stream>>>(ei, fillp, col);
  // 5. layer-1 aggregation over x_bf (linearity: GEMM deferred)
  fused_aggx<<<nodeBlocks4, 256, 0, stream>>>(x_bf, rowptr, col, asrc1, adst1, aggX);
  // 6. a1b = relu(aggX @ W1 + b1)
  mfma_gemm<2, 2, 128, true, 0><<<dim3(GBM, 2), 256, 0, stream>>>(
      aggX, W1t, b1, a1b, N_NODES, 256, nullptr, nullptr, nullptr, nullptr);
  // 7. h2 = a1b @ W2, + alpha2 epilogue (direct store)
  mfma_gemm<4, 1, 256, false, 2><<<dim3(GBM, 1), 256, 0, stream>>>(
      a1b, W2t, nullptr, h2, N_NODES, 64, a2s, a2d, asrc2, adst2);
  // 8. layer-2 softmax+aggregate (+bias) -> out
  fused_agg2<<<nodeBlocks4, 256, 0, stream>>>(h2, rowptr, col, asrc2, adst2, b2, out);
}

// Round 14
// 288.742 us; speedup vs baseline: 1.0754x; 1.0465x over previous
//
#include <hip/hip_runtime.h>
#include <math.h>

#define N_NODES 100000
#define N_EDGES 800000
#define E_TOT (N_EDGES + N_NODES)
#define NEG_SLOPE 0.2f
#define SCAN_NB ((N_NODES + 1023) / 1024)
#define GBM ((N_NODES + 127) / 128)
#define HB 512    // histogram blocks (merged into cast_alpha dispatch)
#define CB 2048   // cast/alpha blocks
#define FB 2048   // fill blocks: 8 partitions x 256 blocks

typedef unsigned short ushort_t;
typedef unsigned long long ull_t;
typedef __attribute__((ext_vector_type(8))) short short8v;   // 8 bf16
typedef __attribute__((ext_vector_type(4))) float f32x4;

static __device__ __forceinline__ float leaky(float e) {
  return e > 0.f ? e : NEG_SLOPE * e;
}

static __device__ __forceinline__ float b2f(ushort_t u) {
  union { unsigned int i; float f; } x;
  x.i = ((unsigned int)u) << 16;
  return x.f;
}

static __device__ __forceinline__ ushort_t f2b(float f) {
  union { float f; unsigned int i; } x;
  x.f = f;
  unsigned int r = x.i + 0x7FFFu + ((x.i >> 16) & 1u);  // RNE (finite inputs)
  return (ushort_t)(r >> 16);
}

// ---------------- prep: zeros + weight transposes + w1as/w1ad = W1 @ a1{s,d} ----------------

__global__ void prep_kernel(int* __restrict__ deg, ull_t* __restrict__ state,
                            const float* __restrict__ W1, ushort_t* __restrict__ W1t,
                            const float* __restrict__ W2, ushort_t* __restrict__ W2t,
                            const float* __restrict__ a1s, const float* __restrict__ a1d,
                            float* __restrict__ w1as, float* __restrict__ w1ad) {
  int g = blockIdx.x * 256 + threadIdx.x;
  const int GT = gridDim.x * 256;
  for (int i = g; i < N_NODES; i += GT) deg[i] = 0;
  for (int i = g; i < 256 * 128; i += GT) {       // W1t[n][k] = W1[k][n]
    int n = i >> 7, k = i & 127;
    W1t[i] = f2b(W1[(size_t)k * 256 + n]);
  }
  for (int i = g; i < 64 * 256; i += GT) {        // W2t[n][k] = W2[k][n]
    int n = i >> 8, k = i & 255;
    W2t[i] = f2b(W2[(size_t)k * 64 + n]);
  }
  for (int i = g; i < SCAN_NB; i += GT) state[i] = 0;
  if (g < 128) {                                  // w1as[k] = sum_n W1[k][n]*a1s[n]
    float ss = 0.f, dd = 0.f;
    for (int n = 0; n < 256; ++n) {
      float w = W1[(size_t)g * 256 + n];
      ss += w * a1s[n];
      dd += w * a1d[n];
    }
    w1as[g] = ss;
    w1ad[g] = dd;
  }
}

// ---------------- merged: x->bf16 cast + per-row alpha dots + degree histogram ----------------

__global__ __launch_bounds__(256) void cast_alpha_hist(
    const float* __restrict__ x, ushort_t* __restrict__ x_bf,
    const float* __restrict__ w1as, const float* __restrict__ w1ad,
    float* __restrict__ asrc1, float* __restrict__ adst1,
    const int* __restrict__ ei, int* __restrict__ deg) {
  int gb = blockIdx.x;
  if (gb < HB) {
    for (int e = gb * 256 + threadIdx.x; e < E_TOT; e += HB * 256) {
      int d = (e < N_EDGES) ? ei[N_EDGES + e] : (e - N_EDGES);
      atomicAdd(&deg[d], 1);
    }
    return;
  }
  gb -= HB;
  int lane = threadIdx.x & 63;
  int gwave = gb * 4 + (threadIdx.x >> 6);
  float ws0 = w1as[lane * 2], ws1 = w1as[lane * 2 + 1];
  float wd0 = w1ad[lane * 2], wd1 = w1ad[lane * 2 + 1];
  for (int n = gwave; n < N_NODES; n += CB * 4) {
    float2 v = *reinterpret_cast<const float2*>(&x[(size_t)n * 128 + lane * 2]);
    ushort2 o;
    o.x = f2b(v.x); o.y = f2b(v.y);
    *reinterpret_cast<ushort2*>(&x_bf[(size_t)n * 128 + lane * 2]) = o;
    float ps = v.x * ws0 + v.y * ws1;
    float pd = v.x * wd0 + v.y * wd1;
#pragma unroll
    for (int off = 32; off; off >>= 1) {
      ps += __shfl_xor(ps, off);
      pd += __shfl_xor(pd, off);
    }
    if (lane == 0) { asrc1[n] = ps; adst1[n] = pd; }
  }
}

// ---------------- single-pass decoupled-lookback scan ----------------

__global__ __launch_bounds__(1024) void scan_lookback(
    const int* __restrict__ deg, ull_t* __restrict__ state,
    int* __restrict__ rowptr, int* __restrict__ fillpos) {
  __shared__ int sh[1024];
  __shared__ int boff_sh;
  const int tid = threadIdx.x;
  const int bid = blockIdx.x;
  int i = bid * 1024 + tid;
  int v = (i < N_NODES) ? deg[i] : 0;
  sh[tid] = v;
  __syncthreads();
  for (int off = 1; off < 1024; off <<= 1) {
    int t = (tid >= off) ? sh[tid - off] : 0;
    __syncthreads();
    sh[tid] += t;
    __syncthreads();
  }
  if (tid == 0) {
    int total = sh[1023];
    atomicExch(&state[bid], (1ULL << 32) | (unsigned int)total);
    long long excl = 0;
    int p = bid - 1;
    while (p >= 0) {
      ull_t st;
      do { st = atomicAdd(&state[p], 0ULL); } while (st == 0);
      excl += (int)(st & 0xffffffffULL);
      if ((st >> 32) == 2) break;
      --p;
    }
    atomicExch(&state[bid], (2ULL << 32) | (unsigned int)(excl + total));
    boff_sh = (int)excl;
  }
  __syncthreads();
  if (i < N_NODES) {
    int excl = sh[tid] - v + boff_sh;
    rowptr[i] = excl;
    fillpos[i] = excl;
    if (i == N_NODES - 1) rowptr[N_NODES] = excl + v;
  }
}

// ---------------- dst-partitioned edge fill ----------------
// 8 dst-partitions; blocks with (bid&7)==j handle only dst in partition j.
// With round-robin block->XCD dispatch, each ~450KB col slice is written by
// ONE XCD's L2 -> full-line writebacks once (kills the 16x cross-XCD
// partial-line amplification). ei dst array (3.6MB) is L2-resident per XCD.

__global__ __launch_bounds__(256) void fill_kernel(
    const int* __restrict__ ei, int* __restrict__ fillpos, int* __restrict__ col) {
  const int part = blockIdx.x & 7;
  const int gb = blockIdx.x >> 3;
  const int PB = FB >> 3;                      // blocks per partition
  const int lo = part * (N_NODES >> 3);
  const int hi = (part == 7) ? N_NODES : lo + (N_NODES >> 3);
  for (int e = gb * 256 + threadIdx.x; e < E_TOT; e += PB * 256) {
    int d = (e < N_EDGES) ? ei[N_EDGES + e] : (e - N_EDGES);
    if (d >= lo && d < hi) {
      int s = (e < N_EDGES) ? ei[e] : d;
      int p = atomicAdd(&fillpos[d], 1);
      col[p] = s;
    }
  }
}

// ---------------- layer-1 aggregation over x_bf (256B rows) ----------------

__global__ __launch_bounds__(256) void fused_aggx(
    const ushort_t* __restrict__ xb, const int* __restrict__ rowptr,
    const int* __restrict__ col, const float* __restrict__ asrc,
    const float* __restrict__ adst, ushort_t* __restrict__ out) {
  __shared__ float wlds[4][64];
  __shared__ int clds[4][64];
  int wid = threadIdx.x >> 6;
  int n = blockIdx.x * 4 + wid;
  if (n >= N_NODES) return;
  int lane = threadIdx.x & 63;
  int beg = rowptr[n], end = rowptr[n + 1];
  int deg = end - beg;
  float ad = adst[n];
  float we = 0.f;
  int s = 0;
  if (lane < deg) { s = col[beg + lane]; we = __expf(leaky(asrc[s] + ad)); }
  float ssum = we;
  for (int jj = beg + 64 + lane; jj < end; jj += 64)   // essentially never
    ssum += __expf(leaky(asrc[col[jj]] + ad));
#pragma unroll
  for (int off = 32; off; off >>= 1) ssum += __shfl_xor(ssum, off);
  float inv = 1.0f / ssum;
  wlds[wid][lane] = we * inv;
  clds[wid][lane] = s << 8;   // byte offset of 256B row
  float a0 = 0.f, a1 = 0.f;
  const char* hb = (const char*)xb + lane * 4;
  if (deg <= 64) {
    int t = 0;
    for (; t + 8 <= deg; t += 8) {
      int4 cA = *reinterpret_cast<const int4*>(&clds[wid][t]);
      int4 cB = *reinterpret_cast<const int4*>(&clds[wid][t + 4]);
      float4 wA = *reinterpret_cast<const float4*>(&wlds[wid][t]);
      float4 wB = *reinterpret_cast<const float4*>(&wlds[wid][t + 4]);
      ushort2 u0 = *reinterpret_cast<const ushort2*>(hb + cA.x);
      ushort2 u1 = *reinterpret_cast<const ushort2*>(hb + cA.y);
      ushort2 u2 = *reinterpret_cast<const ushort2*>(hb + cA.z);
      ushort2 u3 = *reinterpret_cast<const ushort2*>(hb + cA.w);
      ushort2 u4 = *reinterpret_cast<const ushort2*>(hb + cB.x);
      ushort2 u5 = *reinterpret_cast<const ushort2*>(hb + cB.y);
      ushort2 u6 = *reinterpret_cast<const ushort2*>(hb + cB.z);
      ushort2 u7 = *reinterpret_cast<const ushort2*>(hb + cB.w);
      a0 += wA.x * b2f(u0.x) + wA.y * b2f(u1.x) + wA.z * b2f(u2.x) + wA.w * b2f(u3.x)
          + wB.x * b2f(u4.x) + wB.y * b2f(u5.x) + wB.z * b2f(u6.x) + wB.w * b2f(u7.x);
      a1 += wA.x * b2f(u0.y) + wA.y * b2f(u1.y) + wA.z * b2f(u2.y) + wA.w * b2f(u3.y)
          + wB.x * b2f(u4.y) + wB.y * b2f(u5.y) + wB.z * b2f(u6.y) + wB.w * b2f(u7.y);
    }
    for (; t < deg; ++t) {
      int c = clds[wid][t];
      float w = wlds[wid][t];
      ushort2 u = *reinterpret_cast<const ushort2*>(hb + c);
      a0 += w * b2f(u.x);
      a1 += w * b2f(u.y);
    }
  } else {  // deg > 64: recompute weights (astronomically rare)
    for (int j = beg; j < end; ++j) {
      int sj = col[j];
      float w = __expf(leaky(asrc[sj] + ad)) * inv;
      ushort2 u = *reinterpret_cast<const ushort2*>(&xb[(size_t)sj * 128 + lane * 2]);
      a0 += w * b2f(u.x);
      a1 += w * b2f(u.y);
    }
  }
  ushort2 o;
  o.x = f2b(a0);
  o.y = f2b(a1);
  *reinterpret_cast<ushort2*>(&out[(size_t)n * 128 + lane * 2]) = o;
}

// ---------------- staged MFMA GEMM (bf16 A) ----------------

template <int WAVES_M, int WAVES_N, int KTOT, bool RELU_BIAS, int ALPHA_MODE>
__global__ __launch_bounds__(256) void mfma_gemm(
    const ushort_t* __restrict__ A, const ushort_t* __restrict__ Bt,
    const float* __restrict__ bias, ushort_t* __restrict__ Out, int M, int NTOT,
    const float* __restrict__ av_s, const float* __restrict__ av_d,
    float* __restrict__ os, float* __restrict__ od) {
  constexpr int BM = 128;
  constexpr int WN = 64;
  constexpr int WM = BM / WAVES_M;
  constexpr int M_REP = WM / 16;
  constexpr int N_REP = WN / 16;
  constexpr int KC = 128;
  __shared__ ushort_t As[BM * KC];

  const int tid = threadIdx.x;
  const int lane = tid & 63;
  const int wid = tid >> 6;
  const int wm = wid % WAVES_M;
  const int wn = wid / WAVES_M;
  const int rowBase = blockIdx.x * BM;
  const int colBase = blockIdx.y * (WAVES_N * WN) + wn * WN;
  const int l15 = lane & 15;
  const int l4 = lane >> 4;

  f32x4 acc[M_REP][N_REP] = {};

  for (int kc = 0; kc < KTOT; kc += KC) {
    if (kc) __syncthreads();
    for (int c = tid; c < BM * KC / 8; c += 256) {
      int r = c >> 4;
      int k8 = (c & 15) << 3;
      int gr = rowBase + r;
      short8v u = {};
      if (gr < M) u = *(const short8v*)&A[(size_t)gr * KTOT + kc + k8];
      int byte = (r * KC + k8) * 2;
      byte ^= (r & 7) << 4;  // G4 swizzle
      *(short8v*)((char*)As + byte) = u;
    }
    short8v bfr[KC / 32][N_REP];
#pragma unroll
    for (int kk = 0; kk < KC / 32; ++kk)
#pragma unroll
      for (int n = 0; n < N_REP; ++n) {
        int bcol = colBase + n * 16 + l15;
        int k0 = kc + kk * 32 + l4 * 8;
        bfr[kk][n] = *(const short8v*)&Bt[(size_t)bcol * KTOT + k0];
      }
    __syncthreads();
#pragma unroll
    for (int kk = 0; kk < KC / 32; ++kk) {
      short8v afr[M_REP];
#pragma unroll
      for (int m = 0; m < M_REP; ++m) {
        int r = wm * WM + m * 16 + l15;
        int k0 = kk * 32 + l4 * 8;
        int byte = ((r * KC + k0) * 2) ^ ((r & 7) << 4);
        afr[m] = *(const short8v*)((const char*)As + byte);
      }
#pragma unroll
      for (int m = 0; m < M_REP; ++m)
#pragma unroll
        for (int n = 0; n < N_REP; ++n)
          acc[m][n] = __builtin_amdgcn_mfma_f32_16x16x32_bf16(
              afr[m], bfr[kk][n], acc[m][n], 0, 0, 0);
    }
  }
  // epilogue: C/D layout col=lane&15, row=(lane>>4)*4+reg
#pragma unroll
  for (int m = 0; m < M_REP; ++m) {
    int r0 = rowBase + wm * WM + m * 16 + l4 * 4;
#pragma unroll
    for (int n = 0; n < N_REP; ++n) {
      int gc = colBase + n * 16 + l15;
      float bv = RELU_BIAS ? bias[gc] : 0.f;
#pragma unroll
      for (int j = 0; j < 4; ++j) {
        int gr = r0 + j;
        float v = acc[m][n][j];
        if (RELU_BIAS) v = fmaxf(v + bv, 0.f);
        if (gr < M) Out[(size_t)gr * NTOT + gc] = f2b(v);
        acc[m][n][j] = v;   // alpha epilogue uses post-activation value
      }
    }
  }
  if (ALPHA_MODE == 2) {
    float as_v[N_REP], ad_v[N_REP];
#pragma unroll
    for (int n = 0; n < N_REP; ++n) {
      as_v[n] = av_s[colBase + n * 16 + l15];
      ad_v[n] = av_d[colBase + n * 16 + l15];
    }
#pragma unroll
    for (int m = 0; m < M_REP; ++m)
#pragma unroll
      for (int j = 0; j < 4; ++j) {
        float ss = 0.f, dd = 0.f;
#pragma unroll
        for (int n = 0; n < N_REP; ++n) {
          ss += acc[m][n][j] * as_v[n];
          dd += acc[m][n][j] * ad_v[n];
        }
#pragma unroll
        for (int o = 1; o < 16; o <<= 1) {
          ss += __shfl_xor(ss, o);
          dd += __shfl_xor(dd, o);
        }
        if (l15 == 0) {
          int gr = rowBase + wm * WM + m * 16 + l4 * 4 + j;
          if (gr < M) { os[gr] = ss; od[gr] = dd; }
        }
      }
  }
}

// ---------------- layer-2 aggregation (h2 rows, 128B) ----------------

__global__ __launch_bounds__(256) void fused_agg2(
    const ushort_t* __restrict__ h, const int* __restrict__ rowptr,
    const int* __restrict__ col, const float* __restrict__ asrc,
    const float* __restrict__ adst, const float* __restrict__ bias,
    float* __restrict__ out) {
  __shared__ float wlds[4][64];
  __shared__ int clds[4][64];
  int wid = threadIdx.x >> 6;
  int n = blockIdx.x * 4 + wid;
  if (n >= N_NODES) return;
  int lane = threadIdx.x & 63;
  int beg = rowptr[n], end = rowptr[n + 1];
  int deg = end - beg;
  float ad = adst[n];
  float we = 0.f;
  int s = 0;
  if (lane < deg) { s = col[beg + lane]; we = __expf(leaky(asrc[s] + ad)); }
  float ssum = we;
  for (int jj = beg + 64 + lane; jj < end; jj += 64)
    ssum += __expf(leaky(asrc[col[jj]] + ad));
#pragma unroll
  for (int off = 32; off; off >>= 1) ssum += __shfl_xor(ssum, off);
  float inv = 1.0f / ssum;
  wlds[wid][lane] = we * inv;
  clds[wid][lane] = s << 7;   // byte offset of 128B row
  float acc = 0.f;
  const char* hb = (const char*)h + lane * 2;
  if (deg <= 64) {
    int t = 0;
    for (; t + 8 <= deg; t += 8) {
      int4 cA = *reinterpret_cast<const int4*>(&clds[wid][t]);
      int4 cB = *reinterpret_cast<const int4*>(&clds[wid][t + 4]);
      float4 wA = *reinterpret_cast<const float4*>(&wlds[wid][t]);
      float4 wB = *reinterpret_cast<const float4*>(&wlds[wid][t + 4]);
      ushort_t u0 = *reinterpret_cast<const ushort_t*>(hb + cA.x);
      ushort_t u1 = *reinterpret_cast<const ushort_t*>(hb + cA.y);
      ushort_t u2 = *reinterpret_cast<const ushort_t*>(hb + cA.z);
      ushort_t u3 = *reinterpret_cast<const ushort_t*>(hb + cA.w);
      ushort_t u4 = *reinterpret_cast<const ushort_t*>(hb + cB.x);
      ushort_t u5 = *reinterpret_cast<const ushort_t*>(hb + cB.y);
      ushort_t u6 = *reinterpret_cast<const ushort_t*>(hb + cB.z);
      ushort_t u7 = *reinterpret_cast<const ushort_t*>(hb + cB.w);
      acc += wA.x * b2f(u0) + wA.y * b2f(u1) + wA.z * b2f(u2) + wA.w * b2f(u3)
           + wB.x * b2f(u4) + wB.y * b2f(u5) + wB.z * b2f(u6) + wB.w * b2f(u7);
    }
    for (; t < deg; ++t)
      acc += wlds[wid][t] * b2f(*reinterpret_cast<const ushort_t*>(hb + clds[wid][t]));
  } else {
    for (int j = beg; j < end; ++j) {
      int sj = col[j];
      float w = __expf(leaky(asrc[sj] + ad)) * inv;
      acc += w * b2f(h[(size_t)sj * 64 + lane]);
    }
  }
  out[(size_t)n * 64 + lane] = acc + bias[lane];
}

// ---------------- launch ----------------

extern "C" void kernel_launch(void* const* d_in, const int* in_sizes, int n_in,
                              void* d_out, int out_size, void* d_ws, size_t ws_size,
                              hipStream_t stream) {
  const float* x    = (const float*)d_in[0];
  const int*   ei   = (const int*)d_in[1];
  const float* W1   = (const float*)d_in[2];
  const float* a1s  = (const float*)d_in[3];
  const float* a1d  = (const float*)d_in[4];
  const float* b1   = (const float*)d_in[5];
  const float* W2   = (const float*)d_in[6];
  const float* a2s  = (const float*)d_in[7];
  const float* a2d  = (const float*)d_in[8];
  const float* b2   = (const float*)d_in[9];
  float* out = (float*)d_out;

  char* ws = (char*)d_ws;
  size_t off = 0;
  auto alloc = [&](size_t bytes) {
    void* p = ws + off;
    off += bytes;
    off = (off + 255) & ~(size_t)255;
    return p;
  };

  ushort_t* x_bf = (ushort_t*)alloc((size_t)N_NODES * 128 * 2);  // bf16 x
  ushort_t* aggX = (ushort_t*)alloc((size_t)N_NODES * 128 * 2);  // bf16 sum(alpha*x)
  ushort_t* a1b  = (ushort_t*)alloc((size_t)N_NODES * 256 * 2);  // bf16 relu(aggX@W1+b1)
  ushort_t* h2   = (ushort_t*)alloc((size_t)N_NODES * 64 * 2);   // bf16
  ushort_t* W1t  = (ushort_t*)alloc((size_t)256 * 128 * 2);
  ushort_t* W2t  = (ushort_t*)alloc((size_t)64 * 256 * 2);
  float* w1as    = (float*)alloc((size_t)128 * 4);
  float* w1ad    = (float*)alloc((size_t)128 * 4);
  float* asrc1   = (float*)alloc((size_t)N_NODES * 4);
  float* adst1   = (float*)alloc((size_t)N_NODES * 4);
  float* asrc2   = (float*)alloc((size_t)N_NODES * 4);
  float* adst2   = (float*)alloc((size_t)N_NODES * 4);
  int*   deg     = (int*)alloc((size_t)N_NODES * 4);
  int*   rowptr  = (int*)alloc((size_t)(N_NODES + 1) * 4);
  int*   fillp   = (int*)alloc((size_t)N_NODES * 4);
  int*   col     = (int*)alloc((size_t)E_TOT * 4);
  ull_t* state   = (ull_t*)alloc((size_t)SCAN_NB * 8);

  const int nodeBlocks4 = (N_NODES + 3) / 4;

  // 1. prep: zeros + W transposes + w1as/w1ad
  prep_kernel<<<1024, 256, 0, stream>>>(deg, state, W1, W1t, W2, W2t,
                                        a1s, a1d, w1as, w1ad);
  // 2. x->bf16 + alpha1 row-dots + degree histogram (merged)
  cast_alpha_hist<<<HB + CB, 256, 0, stream>>>(x, x_bf, w1as, w1ad,
                                               asrc1, adst1, ei, deg);
  // 3. single-pass scan
  scan_lookback<<<SCAN_NB, 1024, 0, stream>>>(deg, state, rowptr, fillp);
  // 4. dst-partitioned edge fill (XCD-local col writes)
  fill_kernel<<<FB, 256, 0, stream>>>(ei, fillp, col);
  // 5. layer-1 aggregation over x_bf (linearity: GEMM deferred)
  fused_aggx<<<nodeBlocks4, 256, 0, stream>>>(x_bf, rowptr, col, asrc1, adst1, aggX);
  // 6. a1b = relu(aggX @ W1 + b1)
  mfma_gemm<2, 2, 128, true, 0><<<dim3(GBM, 2), 256, 0, stream>>>(
      aggX, W1t, b1, a1b, N_NODES, 256, nullptr, nullptr, nullptr, nullptr);
  // 7. h2 = a1b @ W2, + alpha2 epilogue (direct store)
  mfma_gemm<4, 1, 256, false, 2><<<dim3(GBM, 1), 256, 0, stream>>>(
      a1b, W2t, nullptr, h2, N_NODES, 64, a2s, a2d, asrc2, adst2);
  // 8. layer-2 softmax+aggregate (+bias) -> out
  fused_agg2<<<nodeBlocks4, 256, 0, stream>>>(h2, rowptr, col, asrc2, adst2, b2, out);
}

// Round 15
// 276.648 us; speedup vs baseline: 1.1224x; 1.0437x over previous
//
#include <hip/hip_runtime.h>
#include <math.h>

#define N_NODES 100000
#define N_EDGES 800000
#define E_TOT (N_EDGES + N_NODES)
#define NEG_SLOPE 0.2f
#define SCAN_NB ((N_NODES + 1023) / 1024)
#define GBM ((N_NODES + 127) / 128)
#define HB 1024   // histogram blocks: 8 dst-partitions x 128
#define CB 2048   // cast/alpha blocks
#define FB 2048   // fill blocks: 8 partitions x 256

typedef unsigned short ushort_t;
typedef unsigned long long ull_t;
typedef __attribute__((ext_vector_type(8))) short short8v;   // 8 bf16
typedef __attribute__((ext_vector_type(4))) float f32x4;

static __device__ __forceinline__ float leaky(float e) {
  return e > 0.f ? e : NEG_SLOPE * e;
}

static __device__ __forceinline__ float b2f(ushort_t u) {
  union { unsigned int i; float f; } x;
  x.i = ((unsigned int)u) << 16;
  return x.f;
}

static __device__ __forceinline__ ushort_t f2b(float f) {
  union { float f; unsigned int i; } x;
  x.f = f;
  unsigned int r = x.i + 0x7FFFu + ((x.i >> 16) & 1u);  // RNE (finite inputs)
  return (ushort_t)(r >> 16);
}

// ---------------- prep: zeros + weight transposes + w1as/w1ad = W1 @ a1{s,d} ----------------

__global__ void prep_kernel(int* __restrict__ deg, ull_t* __restrict__ state,
                            const float* __restrict__ W1, ushort_t* __restrict__ W1t,
                            const float* __restrict__ W2, ushort_t* __restrict__ W2t,
                            const float* __restrict__ a1s, const float* __restrict__ a1d,
                            float* __restrict__ w1as, float* __restrict__ w1ad) {
  int g = blockIdx.x * 256 + threadIdx.x;
  const int GT = gridDim.x * 256;
  for (int i = g; i < N_NODES; i += GT) deg[i] = 0;
  for (int i = g; i < 256 * 128; i += GT) {       // W1t[n][k] = W1[k][n]
    int n = i >> 7, k = i & 127;
    W1t[i] = f2b(W1[(size_t)k * 256 + n]);
  }
  for (int i = g; i < 64 * 256; i += GT) {        // W2t[n][k] = W2[k][n]
    int n = i >> 8, k = i & 255;
    W2t[i] = f2b(W2[(size_t)k * 64 + n]);
  }
  for (int i = g; i < SCAN_NB; i += GT) state[i] = 0;
  if (g < 128) {                                  // w1as[k] = sum_n W1[k][n]*a1s[n]
    float ss = 0.f, dd = 0.f;
    for (int n = 0; n < 256; ++n) {
      float w = W1[(size_t)g * 256 + n];
      ss += w * a1s[n];
      dd += w * a1d[n];
    }
    w1as[g] = ss;
    w1ad[g] = dd;
  }
}

// ---------------- merged: dst-partitioned histogram + x->bf16 cast + alpha dots ----------------
// Histogram: blocks with (bid&7)==j only touch deg in partition j -> all of
// partition j's atomics land on one XCD's L2 (same mechanism as fill fix).
// Cast: float4 loads (16B/lane), 2 rows per wave, contiguous row chunk/wave.

__global__ __launch_bounds__(256) void cast_alpha_hist(
    const float* __restrict__ x, ushort_t* __restrict__ x_bf,
    const float* __restrict__ w1as, const float* __restrict__ w1ad,
    float* __restrict__ asrc1, float* __restrict__ adst1,
    const int* __restrict__ ei, int* __restrict__ deg) {
  int gb = blockIdx.x;
  if (gb < HB) {
    const int part = gb & 7;
    const int pb = gb >> 3;
    const int PB = HB >> 3;                  // 128 blocks per partition
    const int lo = part * (N_NODES >> 3);
    const int hi = (part == 7) ? N_NODES : lo + (N_NODES >> 3);
    for (int e = pb * 256 + threadIdx.x; e < E_TOT; e += PB * 256) {
      int d = (e < N_EDGES) ? ei[N_EDGES + e] : (e - N_EDGES);
      if (d >= lo && d < hi) atomicAdd(&deg[d], 1);
    }
    return;
  }
  gb -= HB;
  const int lane = threadIdx.x & 63;
  const int half = lane >> 5;
  const int l31 = lane & 31;
  const int wv = gb * 4 + (threadIdx.x >> 6);
  const int R = (N_NODES + CB * 4 - 1) / (CB * 4);
  int base = wv * R;
  int limit = base + R;
  if (limit > N_NODES) limit = N_NODES;
  float4 ws = *reinterpret_cast<const float4*>(&w1as[l31 * 4]);
  float4 wd = *reinterpret_cast<const float4*>(&w1ad[l31 * 4]);
  for (int n0 = base; n0 < limit; n0 += 2) {
    int n = n0 + half;
    bool valid = n < limit;
    float4 v = make_float4(0.f, 0.f, 0.f, 0.f);
    if (valid) v = *reinterpret_cast<const float4*>(&x[(size_t)n * 128 + l31 * 4]);
    if (valid) {
      ushort4 o;
      o.x = f2b(v.x); o.y = f2b(v.y); o.z = f2b(v.z); o.w = f2b(v.w);
      *reinterpret_cast<ushort4*>(&x_bf[(size_t)n * 128 + l31 * 4]) = o;
    }
    float ps = v.x * ws.x + v.y * ws.y + v.z * ws.z + v.w * ws.w;
    float pd = v.x * wd.x + v.y * wd.y + v.z * wd.z + v.w * wd.w;
#pragma unroll
    for (int off = 16; off; off >>= 1) {    // reduce within 32-lane halves
      ps += __shfl_xor(ps, off);
      pd += __shfl_xor(pd, off);
    }
    if (l31 == 0 && valid) { asrc1[n] = ps; adst1[n] = pd; }
  }
}

// ---------------- single-pass decoupled-lookback scan ----------------

__global__ __launch_bounds__(1024) void scan_lookback(
    const int* __restrict__ deg, ull_t* __restrict__ state,
    int* __restrict__ rowptr, int* __restrict__ fillpos) {
  __shared__ int sh[1024];
  __shared__ int boff_sh;
  const int tid = threadIdx.x;
  const int bid = blockIdx.x;
  int i = bid * 1024 + tid;
  int v = (i < N_NODES) ? deg[i] : 0;
  sh[tid] = v;
  __syncthreads();
  for (int off = 1; off < 1024; off <<= 1) {
    int t = (tid >= off) ? sh[tid - off] : 0;
    __syncthreads();
    sh[tid] += t;
    __syncthreads();
  }
  if (tid == 0) {
    int total = sh[1023];
    atomicExch(&state[bid], (1ULL << 32) | (unsigned int)total);
    long long excl = 0;
    int p = bid - 1;
    while (p >= 0) {
      ull_t st;
      do { st = atomicAdd(&state[p], 0ULL); } while (st == 0);
      excl += (int)(st & 0xffffffffULL);
      if ((st >> 32) == 2) break;
      --p;
    }
    atomicExch(&state[bid], (2ULL << 32) | (unsigned int)(excl + total));
    boff_sh = (int)excl;
  }
  __syncthreads();
  if (i < N_NODES) {
    int excl = sh[tid] - v + boff_sh;
    rowptr[i] = excl;
    fillpos[i] = excl;
    if (i == N_NODES - 1) rowptr[N_NODES] = excl + v;
  }
}

// ---------------- dst-partitioned edge fill ----------------

__global__ __launch_bounds__(256) void fill_kernel(
    const int* __restrict__ ei, int* __restrict__ fillpos, int* __restrict__ col) {
  const int part = blockIdx.x & 7;
  const int gb = blockIdx.x >> 3;
  const int PB = FB >> 3;
  const int lo = part * (N_NODES >> 3);
  const int hi = (part == 7) ? N_NODES : lo + (N_NODES >> 3);
  for (int e = gb * 256 + threadIdx.x; e < E_TOT; e += PB * 256) {
    int d = (e < N_EDGES) ? ei[N_EDGES + e] : (e - N_EDGES);
    if (d >= lo && d < hi) {
      int s = (e < N_EDGES) ? ei[e] : d;
      int p = atomicAdd(&fillpos[d], 1);
      col[p] = s;
    }
  }
}

// ---------------- layer-1 aggregation over x_bf (256B rows) ----------------

__global__ __launch_bounds__(256) void fused_aggx(
    const ushort_t* __restrict__ xb, const int* __restrict__ rowptr,
    const int* __restrict__ col, const float* __restrict__ asrc,
    const float* __restrict__ adst, ushort_t* __restrict__ out) {
  __shared__ float wlds[4][64];
  __shared__ int clds[4][64];
  int wid = threadIdx.x >> 6;
  int n = blockIdx.x * 4 + wid;
  if (n >= N_NODES) return;
  int lane = threadIdx.x & 63;
  int beg = rowptr[n], end = rowptr[n + 1];
  int deg = end - beg;
  float ad = adst[n];
  float we = 0.f;
  int s = 0;
  if (lane < deg) { s = col[beg + lane]; we = __expf(leaky(asrc[s] + ad)); }
  float ssum = we;
  for (int jj = beg + 64 + lane; jj < end; jj += 64)   // essentially never
    ssum += __expf(leaky(asrc[col[jj]] + ad));
#pragma unroll
  for (int off = 32; off; off >>= 1) ssum += __shfl_xor(ssum, off);
  float inv = 1.0f / ssum;
  wlds[wid][lane] = we * inv;
  clds[wid][lane] = s << 8;   // byte offset of 256B row
  float a0 = 0.f, a1 = 0.f;
  const char* hb = (const char*)xb + lane * 4;
  if (deg <= 64) {
    int t = 0;
    for (; t + 8 <= deg; t += 8) {
      int4 cA = *reinterpret_cast<const int4*>(&clds[wid][t]);
      int4 cB = *reinterpret_cast<const int4*>(&clds[wid][t + 4]);
      float4 wA = *reinterpret_cast<const float4*>(&wlds[wid][t]);
      float4 wB = *reinterpret_cast<const float4*>(&wlds[wid][t + 4]);
      ushort2 u0 = *reinterpret_cast<const ushort2*>(hb + cA.x);
      ushort2 u1 = *reinterpret_cast<const ushort2*>(hb + cA.y);
      ushort2 u2 = *reinterpret_cast<const ushort2*>(hb + cA.z);
      ushort2 u3 = *reinterpret_cast<const ushort2*>(hb + cA.w);
      ushort2 u4 = *reinterpret_cast<const ushort2*>(hb + cB.x);
      ushort2 u5 = *reinterpret_cast<const ushort2*>(hb + cB.y);
      ushort2 u6 = *reinterpret_cast<const ushort2*>(hb + cB.z);
      ushort2 u7 = *reinterpret_cast<const ushort2*>(hb + cB.w);
      a0 += wA.x * b2f(u0.x) + wA.y * b2f(u1.x) + wA.z * b2f(u2.x) + wA.w * b2f(u3.x)
          + wB.x * b2f(u4.x) + wB.y * b2f(u5.x) + wB.z * b2f(u6.x) + wB.w * b2f(u7.x);
      a1 += wA.x * b2f(u0.y) + wA.y * b2f(u1.y) + wA.z * b2f(u2.y) + wA.w * b2f(u3.y)
          + wB.x * b2f(u4.y) + wB.y * b2f(u5.y) + wB.z * b2f(u6.y) + wB.w * b2f(u7.y);
    }
    for (; t < deg; ++t) {
      int c = clds[wid][t];
      float w = wlds[wid][t];
      ushort2 u = *reinterpret_cast<const ushort2*>(hb + c);
      a0 += w * b2f(u.x);
      a1 += w * b2f(u.y);
    }
  } else {  // deg > 64: recompute weights (astronomically rare)
    for (int j = beg; j < end; ++j) {
      int sj = col[j];
      float w = __expf(leaky(asrc[sj] + ad)) * inv;
      ushort2 u = *reinterpret_cast<const ushort2*>(&xb[(size_t)sj * 128 + lane * 2]);
      a0 += w * b2f(u.x);
      a1 += w * b2f(u.y);
    }
  }
  ushort2 o;
  o.x = f2b(a0);
  o.y = f2b(a1);
  *reinterpret_cast<ushort2*>(&out[(size_t)n * 128 + lane * 2]) = o;
}

// ---------------- staged MFMA GEMM (bf16 A) ----------------

template <int WAVES_M, int WAVES_N, int KTOT, bool RELU_BIAS, int ALPHA_MODE>
__global__ __launch_bounds__(256) void mfma_gemm(
    const ushort_t* __restrict__ A, const ushort_t* __restrict__ Bt,
    const float* __restrict__ bias, ushort_t* __restrict__ Out, int M, int NTOT,
    const float* __restrict__ av_s, const float* __restrict__ av_d,
    float* __restrict__ os, float* __restrict__ od) {
  constexpr int BM = 128;
  constexpr int WN = 64;
  constexpr int WM = BM / WAVES_M;
  constexpr int M_REP = WM / 16;
  constexpr int N_REP = WN / 16;
  constexpr int KC = 128;
  __shared__ ushort_t As[BM * KC];

  const int tid = threadIdx.x;
  const int lane = tid & 63;
  const int wid = tid >> 6;
  const int wm = wid % WAVES_M;
  const int wn = wid / WAVES_M;
  const int rowBase = blockIdx.x * BM;
  const int colBase = blockIdx.y * (WAVES_N * WN) + wn * WN;
  const int l15 = lane & 15;
  const int l4 = lane >> 4;

  f32x4 acc[M_REP][N_REP] = {};

  for (int kc = 0; kc < KTOT; kc += KC) {
    if (kc) __syncthreads();
    for (int c = tid; c < BM * KC / 8; c += 256) {
      int r = c >> 4;
      int k8 = (c & 15) << 3;
      int gr = rowBase + r;
      short8v u = {};
      if (gr < M) u = *(const short8v*)&A[(size_t)gr * KTOT + kc + k8];
      int byte = (r * KC + k8) * 2;
      byte ^= (r & 7) << 4;  // G4 swizzle
      *(short8v*)((char*)As + byte) = u;
    }
    short8v bfr[KC / 32][N_REP];
#pragma unroll
    for (int kk = 0; kk < KC / 32; ++kk)
#pragma unroll
      for (int n = 0; n < N_REP; ++n) {
        int bcol = colBase + n * 16 + l15;
        int k0 = kc + kk * 32 + l4 * 8;
        bfr[kk][n] = *(const short8v*)&Bt[(size_t)bcol * KTOT + k0];
      }
    __syncthreads();
#pragma unroll
    for (int kk = 0; kk < KC / 32; ++kk) {
      short8v afr[M_REP];
#pragma unroll
      for (int m = 0; m < M_REP; ++m) {
        int r = wm * WM + m * 16 + l15;
        int k0 = kk * 32 + l4 * 8;
        int byte = ((r * KC + k0) * 2) ^ ((r & 7) << 4);
        afr[m] = *(const short8v*)((const char*)As + byte);
      }
#pragma unroll
      for (int m = 0; m < M_REP; ++m)
#pragma unroll
        for (int n = 0; n < N_REP; ++n)
          acc[m][n] = __builtin_amdgcn_mfma_f32_16x16x32_bf16(
              afr[m], bfr[kk][n], acc[m][n], 0, 0, 0);
    }
  }
  // epilogue: C/D layout col=lane&15, row=(lane>>4)*4+reg
#pragma unroll
  for (int m = 0; m < M_REP; ++m) {
    int r0 = rowBase + wm * WM + m * 16 + l4 * 4;
#pragma unroll
    for (int n = 0; n < N_REP; ++n) {
      int gc = colBase + n * 16 + l15;
      float bv = RELU_BIAS ? bias[gc] : 0.f;
#pragma unroll
      for (int j = 0; j < 4; ++j) {
        int gr = r0 + j;
        float v = acc[m][n][j];
        if (RELU_BIAS) v = fmaxf(v + bv, 0.f);
        if (gr < M) Out[(size_t)gr * NTOT + gc] = f2b(v);
        acc[m][n][j] = v;   // alpha epilogue uses post-activation value
      }
    }
  }
  if (ALPHA_MODE == 2) {
    float as_v[N_REP], ad_v[N_REP];
#pragma unroll
    for (int n = 0; n < N_REP; ++n) {
      as_v[n] = av_s[colBase + n * 16 + l15];
      ad_v[n] = av_d[colBase + n * 16 + l15];
    }
#pragma unroll
    for (int m = 0; m < M_REP; ++m)
#pragma unroll
      for (int j = 0; j < 4; ++j) {
        float ss = 0.f, dd = 0.f;
#pragma unroll
        for (int n = 0; n < N_REP; ++n) {
          ss += acc[m][n][j] * as_v[n];
          dd += acc[m][n][j] * ad_v[n];
        }
#pragma unroll
        for (int o = 1; o < 16; o <<= 1) {
          ss += __shfl_xor(ss, o);
          dd += __shfl_xor(dd, o);
        }
        if (l15 == 0) {
          int gr = rowBase + wm * WM + m * 16 + l4 * 4 + j;
          if (gr < M) { os[gr] = ss; od[gr] = dd; }
        }
      }
  }
}

// ---------------- layer-2 aggregation (h2 rows, 128B) ----------------

__global__ __launch_bounds__(256) void fused_agg2(
    const ushort_t* __restrict__ h, const int* __restrict__ rowptr,
    const int* __restrict__ col, const float* __restrict__ asrc,
    const float* __restrict__ adst, const float* __restrict__ bias,
    float* __restrict__ out) {
  __shared__ float wlds[4][64];
  __shared__ int clds[4][64];
  int wid = threadIdx.x >> 6;
  int n = blockIdx.x * 4 + wid;
  if (n >= N_NODES) return;
  int lane = threadIdx.x & 63;
  int beg = rowptr[n], end = rowptr[n + 1];
  int deg = end - beg;
  float ad = adst[n];
  float we = 0.f;
  int s = 0;
  if (lane < deg) { s = col[beg + lane]; we = __expf(leaky(asrc[s] + ad)); }
  float ssum = we;
  for (int jj = beg + 64 + lane; jj < end; jj += 64)
    ssum += __expf(leaky(asrc[col[jj]] + ad));
#pragma unroll
  for (int off = 32; off; off >>= 1) ssum += __shfl_xor(ssum, off);
  float inv = 1.0f / ssum;
  wlds[wid][lane] = we * inv;
  clds[wid][lane] = s << 7;   // byte offset of 128B row
  float acc = 0.f;
  const char* hb = (const char*)h + lane * 2;
  if (deg <= 64) {
    int t = 0;
    for (; t + 8 <= deg; t += 8) {
      int4 cA = *reinterpret_cast<const int4*>(&clds[wid][t]);
      int4 cB = *reinterpret_cast<const int4*>(&clds[wid][t + 4]);
      float4 wA = *reinterpret_cast<const float4*>(&wlds[wid][t]);
      float4 wB = *reinterpret_cast<const float4*>(&wlds[wid][t + 4]);
      ushort_t u0 = *reinterpret_cast<const ushort_t*>(hb + cA.x);
      ushort_t u1 = *reinterpret_cast<const ushort_t*>(hb + cA.y);
      ushort_t u2 = *reinterpret_cast<const ushort_t*>(hb + cA.z);
      ushort_t u3 = *reinterpret_cast<const ushort_t*>(hb + cA.w);
      ushort_t u4 = *reinterpret_cast<const ushort_t*>(hb + cB.x);
      ushort_t u5 = *reinterpret_cast<const ushort_t*>(hb + cB.y);
      ushort_t u6 = *reinterpret_cast<const ushort_t*>(hb + cB.z);
      ushort_t u7 = *reinterpret_cast<const ushort_t*>(hb + cB.w);
      acc += wA.x * b2f(u0) + wA.y * b2f(u1) + wA.z * b2f(u2) + wA.w * b2f(u3)
           + wB.x * b2f(u4) + wB.y * b2f(u5) + wB.z * b2f(u6) + wB.w * b2f(u7);
    }
    for (; t < deg; ++t)
      acc += wlds[wid][t] * b2f(*reinterpret_cast<const ushort_t*>(hb + clds[wid][t]));
  } else {
    for (int j = beg; j < end; ++j) {
      int sj = col[j];
      float w = __expf(leaky(asrc[sj] + ad)) * inv;
      acc += w * b2f(h[(size_t)sj * 64 + lane]);
    }
  }
  out[(size_t)n * 64 + lane] = acc + bias[lane];
}

// ---------------- launch ----------------

extern "C" void kernel_launch(void* const* d_in, const int* in_sizes, int n_in,
                              void* d_out, int out_size, void* d_ws, size_t ws_size,
                              hipStream_t stream) {
  const float* x    = (const float*)d_in[0];
  const int*   ei   = (const int*)d_in[1];
  const float* W1   = (const float*)d_in[2];
  const float* a1s  = (const float*)d_in[3];
  const float* a1d  = (const float*)d_in[4];
  const float* b1   = (const float*)d_in[5];
  const float* W2   = (const float*)d_in[6];
  const float* a2s  = (const float*)d_in[7];
  const float* a2d  = (const float*)d_in[8];
  const float* b2   = (const float*)d_in[9];
  float* out = (float*)d_out;

  char* ws = (char*)d_ws;
  size_t off = 0;
  auto alloc = [&](size_t bytes) {
    void* p = ws + off;
    off += bytes;
    off = (off + 255) & ~(size_t)255;
    return p;
  };

  ushort_t* x_bf = (ushort_t*)alloc((size_t)N_NODES * 128 * 2);  // bf16 x
  ushort_t* aggX = (ushort_t*)alloc((size_t)N_NODES * 128 * 2);  // bf16 sum(alpha*x)
  ushort_t* a1b  = (ushort_t*)alloc((size_t)N_NODES * 256 * 2);  // bf16 relu(aggX@W1+b1)
  ushort_t* h2   = (ushort_t*)alloc((size_t)N_NODES * 64 * 2);   // bf16
  ushort_t* W1t  = (ushort_t*)alloc((size_t)256 * 128 * 2);
  ushort_t* W2t  = (ushort_t*)alloc((size_t)64 * 256 * 2);
  float* w1as    = (float*)alloc((size_t)128 * 4);
  float* w1ad    = (float*)alloc((size_t)128 * 4);
  float* asrc1   = (float*)alloc((size_t)N_NODES * 4);
  float* adst1   = (float*)alloc((size_t)N_NODES * 4);
  float* asrc2   = (float*)alloc((size_t)N_NODES * 4);
  float* adst2   = (float*)alloc((size_t)N_NODES * 4);
  int*   deg     = (int*)alloc((size_t)N_NODES * 4);
  int*   rowptr  = (int*)alloc((size_t)(N_NODES + 1) * 4);
  int*   fillp   = (int*)alloc((size_t)N_NODES * 4);
  int*   col     = (int*)alloc((size_t)E_TOT * 4);
  ull_t* state   = (ull_t*)alloc((size_t)SCAN_NB * 8);

  const int nodeBlocks4 = (N_NODES + 3) / 4;

  // 1. prep: zeros + W transposes + w1as/w1ad
  prep_kernel<<<1024, 256, 0, stream>>>(deg, state, W1, W1t, W2, W2t,
                                        a1s, a1d, w1as, w1ad);
  // 2. dst-partitioned histogram + x->bf16 + alpha1 row-dots (merged)
  cast_alpha_hist<<<HB + CB, 256, 0, stream>>>(x, x_bf, w1as, w1ad,
                                               asrc1, adst1, ei, deg);
  // 3. single-pass scan
  scan_lookback<<<SCAN_NB, 1024, 0, stream>>>(deg, state, rowptr, fillp);
  // 4. dst-partitioned edge fill (XCD-local col writes)
  fill_kernel<<<FB, 256, 0, stream>>>(ei, fillp, col);
  // 5. layer-1 aggregation over x_bf (linearity: GEMM deferred)
  fused_aggx<<<nodeBlocks4, 256, 0, stream>>>(x_bf, rowptr, col, asrc1, adst1, aggX);
  // 6. a1b = relu(aggX @ W1 + b1)
  mfma_gemm<2, 2, 128, true, 0><<<dim3(GBM, 2), 256, 0, stream>>>(
      aggX, W1t, b1, a1b, N_NODES, 256, nullptr, nullptr, nullptr, nullptr);
  // 7. h2 = a1b @ W2, + alpha2 epilogue (direct store)
  mfma_gemm<4, 1, 256, false, 2><<<dim3(GBM, 1), 256, 0, stream>>>(
      a1b, W2t, nullptr, h2, N_NODES, 64, a2s, a2d, asrc2, adst2);
  // 8. layer-2 softmax+aggregate (+bias) -> out
  fused_agg2<<<nodeBlocks4, 256, 0, stream>>>(h2, rowptr, col, asrc2, adst2, b2, out);
}

// Round 16
// 251.573 us; speedup vs baseline: 1.2343x; 1.0997x over previous
//
#include <hip/hip_runtime.h>
#include <math.h>

#define N_NODES 100000
#define N_EDGES 800000
#define E_TOT (N_EDGES + N_NODES)
#define NEG_SLOPE 0.2f
#define SCAN_NB ((N_NODES + 1023) / 1024)
#define GBM ((N_NODES + 127) / 128)
#define HB 1024   // histogram blocks: 8 dst-partitions x 128
#define CB 2048   // cast/alpha blocks
#define FB 2048   // fill blocks: 8 partitions x 256

typedef unsigned short ushort_t;
typedef unsigned long long ull_t;
typedef __attribute__((ext_vector_type(8))) short short8v;   // 8 bf16
typedef __attribute__((ext_vector_type(4))) float f32x4;

static __device__ __forceinline__ float leaky(float e) {
  return e > 0.f ? e : NEG_SLOPE * e;
}

static __device__ __forceinline__ float b2f(ushort_t u) {
  union { unsigned int i; float f; } x;
  x.i = ((unsigned int)u) << 16;
  return x.f;
}

static __device__ __forceinline__ float blo(unsigned int q) {  // low bf16 of u32
  union { unsigned int i; float f; } x;
  x.i = q << 16;
  return x.f;
}

static __device__ __forceinline__ float bhi(unsigned int q) {  // high bf16 of u32
  union { unsigned int i; float f; } x;
  x.i = q & 0xffff0000u;
  return x.f;
}

static __device__ __forceinline__ ushort_t f2b(float f) {
  union { float f; unsigned int i; } x;
  x.f = f;
  unsigned int r = x.i + 0x7FFFu + ((x.i >> 16) & 1u);  // RNE (finite inputs)
  return (ushort_t)(r >> 16);
}

// ---------------- prep: zeros + weight transposes + w1as/w1ad = W1 @ a1{s,d} ----------------

__global__ void prep_kernel(int* __restrict__ deg, ull_t* __restrict__ state,
                            const float* __restrict__ W1, ushort_t* __restrict__ W1t,
                            const float* __restrict__ W2, ushort_t* __restrict__ W2t,
                            const float* __restrict__ a1s, const float* __restrict__ a1d,
                            float* __restrict__ w1as, float* __restrict__ w1ad) {
  int g = blockIdx.x * 256 + threadIdx.x;
  const int GT = gridDim.x * 256;
  for (int i = g; i < N_NODES; i += GT) deg[i] = 0;
  for (int i = g; i < 256 * 128; i += GT) {       // W1t[n][k] = W1[k][n]
    int n = i >> 7, k = i & 127;
    W1t[i] = f2b(W1[(size_t)k * 256 + n]);
  }
  for (int i = g; i < 64 * 256; i += GT) {        // W2t[n][k] = W2[k][n]
    int n = i >> 8, k = i & 255;
    W2t[i] = f2b(W2[(size_t)k * 64 + n]);
  }
  for (int i = g; i < SCAN_NB; i += GT) state[i] = 0;
  if (g < 128) {                                  // w1as[k] = sum_n W1[k][n]*a1s[n]
    float ss = 0.f, dd = 0.f;
    for (int n = 0; n < 256; ++n) {
      float w = W1[(size_t)g * 256 + n];
      ss += w * a1s[n];
      dd += w * a1d[n];
    }
    w1as[g] = ss;
    w1ad[g] = dd;
  }
}

// ---------------- merged: dst-partitioned histogram + x->bf16 cast + alpha dots ----------------

__global__ __launch_bounds__(256) void cast_alpha_hist(
    const float* __restrict__ x, ushort_t* __restrict__ x_bf,
    const float* __restrict__ w1as, const float* __restrict__ w1ad,
    float* __restrict__ asrc1, float* __restrict__ adst1,
    const int* __restrict__ ei, int* __restrict__ deg) {
  int gb = blockIdx.x;
  if (gb < HB) {
    const int part = gb & 7;
    const int pb = gb >> 3;
    const int PB = HB >> 3;
    const int lo = part * (N_NODES >> 3);
    const int hi = (part == 7) ? N_NODES : lo + (N_NODES >> 3);
    for (int e = pb * 256 + threadIdx.x; e < E_TOT; e += PB * 256) {
      int d = (e < N_EDGES) ? ei[N_EDGES + e] : (e - N_EDGES);
      if (d >= lo && d < hi) atomicAdd(&deg[d], 1);
    }
    return;
  }
  gb -= HB;
  const int lane = threadIdx.x & 63;
  const int half = lane >> 5;
  const int l31 = lane & 31;
  const int wv = gb * 4 + (threadIdx.x >> 6);
  const int R = (N_NODES + CB * 4 - 1) / (CB * 4);
  int base = wv * R;
  int limit = base + R;
  if (limit > N_NODES) limit = N_NODES;
  float4 ws = *reinterpret_cast<const float4*>(&w1as[l31 * 4]);
  float4 wd = *reinterpret_cast<const float4*>(&w1ad[l31 * 4]);
  for (int n0 = base; n0 < limit; n0 += 2) {
    int n = n0 + half;
    bool valid = n < limit;
    float4 v = make_float4(0.f, 0.f, 0.f, 0.f);
    if (valid) v = *reinterpret_cast<const float4*>(&x[(size_t)n * 128 + l31 * 4]);
    if (valid) {
      ushort4 o;
      o.x = f2b(v.x); o.y = f2b(v.y); o.z = f2b(v.z); o.w = f2b(v.w);
      *reinterpret_cast<ushort4*>(&x_bf[(size_t)n * 128 + l31 * 4]) = o;
    }
    float ps = v.x * ws.x + v.y * ws.y + v.z * ws.z + v.w * ws.w;
    float pd = v.x * wd.x + v.y * wd.y + v.z * wd.z + v.w * wd.w;
#pragma unroll
    for (int off = 16; off; off >>= 1) {
      ps += __shfl_xor(ps, off);
      pd += __shfl_xor(pd, off);
    }
    if (l31 == 0 && valid) { asrc1[n] = ps; adst1[n] = pd; }
  }
}

// ---------------- single-pass decoupled-lookback scan ----------------

__global__ __launch_bounds__(1024) void scan_lookback(
    const int* __restrict__ deg, ull_t* __restrict__ state,
    int* __restrict__ rowptr, int* __restrict__ fillpos) {
  __shared__ int sh[1024];
  __shared__ int boff_sh;
  const int tid = threadIdx.x;
  const int bid = blockIdx.x;
  int i = bid * 1024 + tid;
  int v = (i < N_NODES) ? deg[i] : 0;
  sh[tid] = v;
  __syncthreads();
  for (int off = 1; off < 1024; off <<= 1) {
    int t = (tid >= off) ? sh[tid - off] : 0;
    __syncthreads();
    sh[tid] += t;
    __syncthreads();
  }
  if (tid == 0) {
    int total = sh[1023];
    atomicExch(&state[bid], (1ULL << 32) | (unsigned int)total);
    long long excl = 0;
    int p = bid - 1;
    while (p >= 0) {
      ull_t st;
      do { st = atomicAdd(&state[p], 0ULL); } while (st == 0);
      excl += (int)(st & 0xffffffffULL);
      if ((st >> 32) == 2) break;
      --p;
    }
    atomicExch(&state[bid], (2ULL << 32) | (unsigned int)(excl + total));
    boff_sh = (int)excl;
  }
  __syncthreads();
  if (i < N_NODES) {
    int excl = sh[tid] - v + boff_sh;
    rowptr[i] = excl;
    fillpos[i] = excl;
    if (i == N_NODES - 1) rowptr[N_NODES] = excl + v;
  }
}

// ---------------- dst-partitioned edge fill ----------------

__global__ __launch_bounds__(256) void fill_kernel(
    const int* __restrict__ ei, int* __restrict__ fillpos, int* __restrict__ col) {
  const int part = blockIdx.x & 7;
  const int gb = blockIdx.x >> 3;
  const int PB = FB >> 3;
  const int lo = part * (N_NODES >> 3);
  const int hi = (part == 7) ? N_NODES : lo + (N_NODES >> 3);
  for (int e = gb * 256 + threadIdx.x; e < E_TOT; e += PB * 256) {
    int d = (e < N_EDGES) ? ei[N_EDGES + e] : (e - N_EDGES);
    if (d >= lo && d < hi) {
      int s = (e < N_EDGES) ? ei[e] : d;
      int p = atomicAdd(&fillpos[d], 1);
      col[p] = s;
    }
  }
}

// ---------------- layer-1 aggregation: 2 nodes/wave, 512B per VMEM instr ----------------
// Lanes 0-31 own node A, 32-63 node B. Lane covers 4 channels (uint2 = 8B).
// Pass A fills LDS weight/offset tables strided-by-32 per half; shfl reduce
// stays within the 32-lane half (offsets 16..1).

__global__ __launch_bounds__(256) void fused_aggx(
    const ushort_t* __restrict__ xb, const int* __restrict__ rowptr,
    const int* __restrict__ col, const float* __restrict__ asrc,
    const float* __restrict__ adst, ushort_t* __restrict__ out) {
  __shared__ float wlds[8][64];
  __shared__ int clds[8][64];
  const int wid = threadIdx.x >> 6;
  const int lane = threadIdx.x & 63;
  const int half = lane >> 5;
  const int l31 = lane & 31;
  const int slot = wid * 2 + half;
  const int n = blockIdx.x * 8 + slot;
  if (n >= N_NODES) return;
  int beg = rowptr[n], end = rowptr[n + 1];
  int deg = end - beg;
  float ad = adst[n];
  float ssum = 0.f;
  int cap = deg < 64 ? deg : 64;
  for (int t = l31; t < cap; t += 32) {
    int s = col[beg + t];
    float we = __expf(leaky(asrc[s] + ad));
    ssum += we;
    wlds[slot][t] = we;
    clds[slot][t] = s << 8;   // byte offset of 256B row
  }
  for (int jj = beg + 64 + l31; jj < end; jj += 32)   // essentially never
    ssum += __expf(leaky(asrc[col[jj]] + ad));
#pragma unroll
  for (int off = 16; off; off >>= 1) ssum += __shfl_xor(ssum, off);
  float inv = 1.0f / ssum;
  for (int t = l31; t < cap; t += 32) wlds[slot][t] *= inv;
  float a0 = 0.f, a1 = 0.f, a2 = 0.f, a3 = 0.f;
  const char* hb = (const char*)xb + l31 * 8;
  if (deg <= 64) {
    int t = 0;
    for (; t + 8 <= deg; t += 8) {
      int4 cA = *reinterpret_cast<const int4*>(&clds[slot][t]);
      int4 cB = *reinterpret_cast<const int4*>(&clds[slot][t + 4]);
      float4 wA = *reinterpret_cast<const float4*>(&wlds[slot][t]);
      float4 wB = *reinterpret_cast<const float4*>(&wlds[slot][t + 4]);
      uint2 q0 = *reinterpret_cast<const uint2*>(hb + cA.x);
      uint2 q1 = *reinterpret_cast<const uint2*>(hb + cA.y);
      uint2 q2 = *reinterpret_cast<const uint2*>(hb + cA.z);
      uint2 q3 = *reinterpret_cast<const uint2*>(hb + cA.w);
      uint2 q4 = *reinterpret_cast<const uint2*>(hb + cB.x);
      uint2 q5 = *reinterpret_cast<const uint2*>(hb + cB.y);
      uint2 q6 = *reinterpret_cast<const uint2*>(hb + cB.z);
      uint2 q7 = *reinterpret_cast<const uint2*>(hb + cB.w);
      a0 += wA.x * blo(q0.x) + wA.y * blo(q1.x) + wA.z * blo(q2.x) + wA.w * blo(q3.x)
          + wB.x * blo(q4.x) + wB.y * blo(q5.x) + wB.z * blo(q6.x) + wB.w * blo(q7.x);
      a1 += wA.x * bhi(q0.x) + wA.y * bhi(q1.x) + wA.z * bhi(q2.x) + wA.w * bhi(q3.x)
          + wB.x * bhi(q4.x) + wB.y * bhi(q5.x) + wB.z * bhi(q6.x) + wB.w * bhi(q7.x);
      a2 += wA.x * blo(q0.y) + wA.y * blo(q1.y) + wA.z * blo(q2.y) + wA.w * blo(q3.y)
          + wB.x * blo(q4.y) + wB.y * blo(q5.y) + wB.z * blo(q6.y) + wB.w * blo(q7.y);
      a3 += wA.x * bhi(q0.y) + wA.y * bhi(q1.y) + wA.z * bhi(q2.y) + wA.w * bhi(q3.y)
          + wB.x * bhi(q4.y) + wB.y * bhi(q5.y) + wB.z * bhi(q6.y) + wB.w * bhi(q7.y);
    }
    for (; t < deg; ++t) {
      int c = clds[slot][t];
      float w = wlds[slot][t];
      uint2 q = *reinterpret_cast<const uint2*>(hb + c);
      a0 += w * blo(q.x); a1 += w * bhi(q.x);
      a2 += w * blo(q.y); a3 += w * bhi(q.y);
    }
  } else {  // deg > 64: recompute weights (astronomically rare)
    for (int j = beg; j < end; ++j) {
      int sj = col[j];
      float w = __expf(leaky(asrc[sj] + ad)) * inv;
      uint2 q = *reinterpret_cast<const uint2*>(&xb[(size_t)sj * 128 + l31 * 4]);
      a0 += w * blo(q.x); a1 += w * bhi(q.x);
      a2 += w * blo(q.y); a3 += w * bhi(q.y);
    }
  }
  ushort4 o;
  o.x = f2b(a0); o.y = f2b(a1); o.z = f2b(a2); o.w = f2b(a3);
  *reinterpret_cast<ushort4*>(&out[(size_t)n * 128 + l31 * 4]) = o;
}

// ---------------- staged MFMA GEMM (bf16 A) ----------------

template <int WAVES_M, int WAVES_N, int KTOT, bool RELU_BIAS, int ALPHA_MODE>
__global__ __launch_bounds__(256) void mfma_gemm(
    const ushort_t* __restrict__ A, const ushort_t* __restrict__ Bt,
    const float* __restrict__ bias, ushort_t* __restrict__ Out, int M, int NTOT,
    const float* __restrict__ av_s, const float* __restrict__ av_d,
    float* __restrict__ os, float* __restrict__ od) {
  constexpr int BM = 128;
  constexpr int WN = 64;
  constexpr int WM = BM / WAVES_M;
  constexpr int M_REP = WM / 16;
  constexpr int N_REP = WN / 16;
  constexpr int KC = 128;
  __shared__ ushort_t As[BM * KC];

  const int tid = threadIdx.x;
  const int lane = tid & 63;
  const int wid = tid >> 6;
  const int wm = wid % WAVES_M;
  const int wn = wid / WAVES_M;
  const int rowBase = blockIdx.x * BM;
  const int colBase = blockIdx.y * (WAVES_N * WN) + wn * WN;
  const int l15 = lane & 15;
  const int l4 = lane >> 4;

  f32x4 acc[M_REP][N_REP] = {};

  for (int kc = 0; kc < KTOT; kc += KC) {
    if (kc) __syncthreads();
    for (int c = tid; c < BM * KC / 8; c += 256) {
      int r = c >> 4;
      int k8 = (c & 15) << 3;
      int gr = rowBase + r;
      short8v u = {};
      if (gr < M) u = *(const short8v*)&A[(size_t)gr * KTOT + kc + k8];
      int byte = (r * KC + k8) * 2;
      byte ^= (r & 7) << 4;  // G4 swizzle
      *(short8v*)((char*)As + byte) = u;
    }
    short8v bfr[KC / 32][N_REP];
#pragma unroll
    for (int kk = 0; kk < KC / 32; ++kk)
#pragma unroll
      for (int n = 0; n < N_REP; ++n) {
        int bcol = colBase + n * 16 + l15;
        int k0 = kc + kk * 32 + l4 * 8;
        bfr[kk][n] = *(const short8v*)&Bt[(size_t)bcol * KTOT + k0];
      }
    __syncthreads();
#pragma unroll
    for (int kk = 0; kk < KC / 32; ++kk) {
      short8v afr[M_REP];
#pragma unroll
      for (int m = 0; m < M_REP; ++m) {
        int r = wm * WM + m * 16 + l15;
        int k0 = kk * 32 + l4 * 8;
        int byte = ((r * KC + k0) * 2) ^ ((r & 7) << 4);
        afr[m] = *(const short8v*)((const char*)As + byte);
      }
#pragma unroll
      for (int m = 0; m < M_REP; ++m)
#pragma unroll
        for (int n = 0; n < N_REP; ++n)
          acc[m][n] = __builtin_amdgcn_mfma_f32_16x16x32_bf16(
              afr[m], bfr[kk][n], acc[m][n], 0, 0, 0);
    }
  }
  // epilogue: C/D layout col=lane&15, row=(lane>>4)*4+reg
#pragma unroll
  for (int m = 0; m < M_REP; ++m) {
    int r0 = rowBase + wm * WM + m * 16 + l4 * 4;
#pragma unroll
    for (int n = 0; n < N_REP; ++n) {
      int gc = colBase + n * 16 + l15;
      float bv = RELU_BIAS ? bias[gc] : 0.f;
#pragma unroll
      for (int j = 0; j < 4; ++j) {
        int gr = r0 + j;
        float v = acc[m][n][j];
        if (RELU_BIAS) v = fmaxf(v + bv, 0.f);
        if (gr < M) Out[(size_t)gr * NTOT + gc] = f2b(v);
        acc[m][n][j] = v;   // alpha epilogue uses post-activation value
      }
    }
  }
  if (ALPHA_MODE == 2) {
    float as_v[N_REP], ad_v[N_REP];
#pragma unroll
    for (int n = 0; n < N_REP; ++n) {
      as_v[n] = av_s[colBase + n * 16 + l15];
      ad_v[n] = av_d[colBase + n * 16 + l15];
    }
#pragma unroll
    for (int m = 0; m < M_REP; ++m)
#pragma unroll
      for (int j = 0; j < 4; ++j) {
        float ss = 0.f, dd = 0.f;
#pragma unroll
        for (int n = 0; n < N_REP; ++n) {
          ss += acc[m][n][j] * as_v[n];
          dd += acc[m][n][j] * ad_v[n];
        }
#pragma unroll
        for (int o = 1; o < 16; o <<= 1) {
          ss += __shfl_xor(ss, o);
          dd += __shfl_xor(dd, o);
        }
        if (l15 == 0) {
          int gr = rowBase + wm * WM + m * 16 + l4 * 4 + j;
          if (gr < M) { os[gr] = ss; od[gr] = dd; }
        }
      }
  }
}

// ---------------- layer-2 aggregation: 2 nodes/wave (uint = 2 channels/lane) ----------------

__global__ __launch_bounds__(256) void fused_agg2(
    const ushort_t* __restrict__ h, const int* __restrict__ rowptr,
    const int* __restrict__ col, const float* __restrict__ asrc,
    const float* __restrict__ adst, const float* __restrict__ bias,
    float* __restrict__ out) {
  __shared__ float wlds[8][64];
  __shared__ int clds[8][64];
  const int wid = threadIdx.x >> 6;
  const int lane = threadIdx.x & 63;
  const int half = lane >> 5;
  const int l31 = lane & 31;
  const int slot = wid * 2 + half;
  const int n = blockIdx.x * 8 + slot;
  if (n >= N_NODES) return;
  int beg = rowptr[n], end = rowptr[n + 1];
  int deg = end - beg;
  float ad = adst[n];
  float ssum = 0.f;
  int cap = deg < 64 ? deg : 64;
  for (int t = l31; t < cap; t += 32) {
    int s = col[beg + t];
    float we = __expf(leaky(asrc[s] + ad));
    ssum += we;
    wlds[slot][t] = we;
    clds[slot][t] = s << 7;   // byte offset of 128B row
  }
  for (int jj = beg + 64 + l31; jj < end; jj += 32)
    ssum += __expf(leaky(asrc[col[jj]] + ad));
#pragma unroll
  for (int off = 16; off; off >>= 1) ssum += __shfl_xor(ssum, off);
  float inv = 1.0f / ssum;
  for (int t = l31; t < cap; t += 32) wlds[slot][t] *= inv;
  float a0 = 0.f, a1 = 0.f;
  const char* hb = (const char*)h + l31 * 4;
  if (deg <= 64) {
    int t = 0;
    for (; t + 8 <= deg; t += 8) {
      int4 cA = *reinterpret_cast<const int4*>(&clds[slot][t]);
      int4 cB = *reinterpret_cast<const int4*>(&clds[slot][t + 4]);
      float4 wA = *reinterpret_cast<const float4*>(&wlds[slot][t]);
      float4 wB = *reinterpret_cast<const float4*>(&wlds[slot][t + 4]);
      unsigned int q0 = *reinterpret_cast<const unsigned int*>(hb + cA.x);
      unsigned int q1 = *reinterpret_cast<const unsigned int*>(hb + cA.y);
      unsigned int q2 = *reinterpret_cast<const unsigned int*>(hb + cA.z);
      unsigned int q3 = *reinterpret_cast<const unsigned int*>(hb + cA.w);
      unsigned int q4 = *reinterpret_cast<const unsigned int*>(hb + cB.x);
      unsigned int q5 = *reinterpret_cast<const unsigned int*>(hb + cB.y);
      unsigned int q6 = *reinterpret_cast<const unsigned int*>(hb + cB.z);
      unsigned int q7 = *reinterpret_cast<const unsigned int*>(hb + cB.w);
      a0 += wA.x * blo(q0) + wA.y * blo(q1) + wA.z * blo(q2) + wA.w * blo(q3)
          + wB.x * blo(q4) + wB.y * blo(q5) + wB.z * blo(q6) + wB.w * blo(q7);
      a1 += wA.x * bhi(q0) + wA.y * bhi(q1) + wA.z * bhi(q2) + wA.w * bhi(q3)
          + wB.x * bhi(q4) + wB.y * bhi(q5) + wB.z * bhi(q6) + wB.w * bhi(q7);
    }
    for (; t < deg; ++t) {
      int c = clds[slot][t];
      float w = wlds[slot][t];
      unsigned int q = *reinterpret_cast<const unsigned int*>(hb + c);
      a0 += w * blo(q);
      a1 += w * bhi(q);
    }
  } else {
    for (int j = beg; j < end; ++j) {
      int sj = col[j];
      float w = __expf(leaky(asrc[sj] + ad)) * inv;
      unsigned int q = *reinterpret_cast<const unsigned int*>(&h[(size_t)sj * 64 + l31 * 2]);
      a0 += w * blo(q);
      a1 += w * bhi(q);
    }
  }
  float2 o;
  o.x = a0 + bias[l31 * 2];
  o.y = a1 + bias[l31 * 2 + 1];
  *reinterpret_cast<float2*>(&out[(size_t)n * 64 + l31 * 2]) = o;
}

// ---------------- launch ----------------

extern "C" void kernel_launch(void* const* d_in, const int* in_sizes, int n_in,
                              void* d_out, int out_size, void* d_ws, size_t ws_size,
                              hipStream_t stream) {
  const float* x    = (const float*)d_in[0];
  const int*   ei   = (const int*)d_in[1];
  const float* W1   = (const float*)d_in[2];
  const float* a1s  = (const float*)d_in[3];
  const float* a1d  = (const float*)d_in[4];
  const float* b1   = (const float*)d_in[5];
  const float* W2   = (const float*)d_in[6];
  const float* a2s  = (const float*)d_in[7];
  const float* a2d  = (const float*)d_in[8];
  const float* b2   = (const float*)d_in[9];
  float* out = (float*)d_out;

  char* ws = (char*)d_ws;
  size_t off = 0;
  auto alloc = [&](size_t bytes) {
    void* p = ws + off;
    off += bytes;
    off = (off + 255) & ~(size_t)255;
    return p;
  };

  ushort_t* x_bf = (ushort_t*)alloc((size_t)N_NODES * 128 * 2);  // bf16 x
  ushort_t* aggX = (ushort_t*)alloc((size_t)N_NODES * 128 * 2);  // bf16 sum(alpha*x)
  ushort_t* a1b  = (ushort_t*)alloc((size_t)N_NODES * 256 * 2);  // bf16 relu(aggX@W1+b1)
  ushort_t* h2   = (ushort_t*)alloc((size_t)N_NODES * 64 * 2);   // bf16
  ushort_t* W1t  = (ushort_t*)alloc((size_t)256 * 128 * 2);
  ushort_t* W2t  = (ushort_t*)alloc((size_t)64 * 256 * 2);
  float* w1as    = (float*)alloc((size_t)128 * 4);
  float* w1ad    = (float*)alloc((size_t)128 * 4);
  float* asrc1   = (float*)alloc((size_t)N_NODES * 4);
  float* adst1   = (float*)alloc((size_t)N_NODES * 4);
  float* asrc2   = (float*)alloc((size_t)N_NODES * 4);
  float* adst2   = (float*)alloc((size_t)N_NODES * 4);
  int*   deg     = (int*)alloc((size_t)N_NODES * 4);
  int*   rowptr  = (int*)alloc((size_t)(N_NODES + 1) * 4);
  int*   fillp   = (int*)alloc((size_t)N_NODES * 4);
  int*   col     = (int*)alloc((size_t)E_TOT * 4);
  ull_t* state   = (ull_t*)alloc((size_t)SCAN_NB * 8);

  const int nodeBlocks8 = (N_NODES + 7) / 8;

  // 1. prep: zeros + W transposes + w1as/w1ad
  prep_kernel<<<1024, 256, 0, stream>>>(deg, state, W1, W1t, W2, W2t,
                                        a1s, a1d, w1as, w1ad);
  // 2. dst-partitioned histogram + x->bf16 + alpha1 row-dots (merged)
  cast_alpha_hist<<<HB + CB, 256, 0, stream>>>(x, x_bf, w1as, w1ad,
                                               asrc1, adst1, ei, deg);
  // 3. single-pass scan
  scan_lookback<<<SCAN_NB, 1024, 0, stream>>>(deg, state, rowptr, fillp);
  // 4. dst-partitioned edge fill (XCD-local col writes)
  fill_kernel<<<FB, 256, 0, stream>>>(ei, fillp, col);
  // 5. layer-1 aggregation over x_bf (2 nodes/wave, 512B/VMEM)
  fused_aggx<<<nodeBlocks8, 256, 0, stream>>>(x_bf, rowptr, col, asrc1, adst1, aggX);
  // 6. a1b = relu(aggX @ W1 + b1)
  mfma_gemm<2, 2, 128, true, 0><<<dim3(GBM, 2), 256, 0, stream>>>(
      aggX, W1t, b1, a1b, N_NODES, 256, nullptr, nullptr, nullptr, nullptr);
  // 7. h2 = a1b @ W2, + alpha2 epilogue (direct store)
  mfma_gemm<4, 1, 256, false, 2><<<dim3(GBM, 1), 256, 0, stream>>>(
      a1b, W2t, nullptr, h2, N_NODES, 64, a2s, a2d, asrc2, adst2);
  // 8. layer-2 softmax+aggregate (2 nodes/wave, +bias) -> out
  fused_agg2<<<nodeBlocks8, 256, 0, stream>>>(h2, rowptr, col, asrc2, adst2, b2, out);
}

// Round 17
// 235.818 us; speedup vs baseline: 1.3168x; 1.0668x over previous
//
#include <hip/hip_runtime.h>
#include <math.h>

#define N_NODES 100000
#define N_EDGES 800000
#define E_TOT (N_EDGES + N_NODES)
#define NEG_SLOPE 0.2f
#define SCAN_NB ((N_NODES + 1023) / 1024)
#define GBM ((N_NODES + 127) / 128)
#define HB 1024   // histogram blocks: 8 dst-partitions x 128
#define CB 2048   // cast/alpha blocks
#define FB 2048   // fill blocks: 8 partitions x 256

typedef unsigned short ushort_t;
typedef unsigned long long ull_t;
typedef __attribute__((ext_vector_type(8))) short short8v;   // 8 bf16
typedef __attribute__((ext_vector_type(4))) float f32x4;

static __device__ __forceinline__ float leaky(float e) {
  return e > 0.f ? e : NEG_SLOPE * e;
}

static __device__ __forceinline__ float b2f(ushort_t u) {
  union { unsigned int i; float f; } x;
  x.i = ((unsigned int)u) << 16;
  return x.f;
}

static __device__ __forceinline__ float blo(unsigned int q) {
  union { unsigned int i; float f; } x;
  x.i = q << 16;
  return x.f;
}

static __device__ __forceinline__ float bhi(unsigned int q) {
  union { unsigned int i; float f; } x;
  x.i = q & 0xffff0000u;
  return x.f;
}

static __device__ __forceinline__ ushort_t f2b(float f) {
  union { float f; unsigned int i; } x;
  x.f = f;
  unsigned int r = x.i + 0x7FFFu + ((x.i >> 16) & 1u);  // RNE (finite inputs)
  return (ushort_t)(r >> 16);
}

// ---------------- prep: zeros + weight transposes + w1as/w1ad = W1 @ a1{s,d} ----------------

__global__ void prep_kernel(int* __restrict__ deg, ull_t* __restrict__ state,
                            const float* __restrict__ W1, ushort_t* __restrict__ W1t,
                            const float* __restrict__ W2, ushort_t* __restrict__ W2t,
                            const float* __restrict__ a1s, const float* __restrict__ a1d,
                            float* __restrict__ w1as, float* __restrict__ w1ad) {
  int g = blockIdx.x * 256 + threadIdx.x;
  const int GT = gridDim.x * 256;
  for (int i = g; i < N_NODES; i += GT) deg[i] = 0;
  for (int i = g; i < 256 * 128; i += GT) {       // W1t[n][k] = W1[k][n]
    int n = i >> 7, k = i & 127;
    W1t[i] = f2b(W1[(size_t)k * 256 + n]);
  }
  for (int i = g; i < 64 * 256; i += GT) {        // W2t[n][k] = W2[k][n]
    int n = i >> 8, k = i & 255;
    W2t[i] = f2b(W2[(size_t)k * 64 + n]);
  }
  for (int i = g; i < SCAN_NB; i += GT) state[i] = 0;
  if (g < 128) {                                  // w1as[k] = sum_n W1[k][n]*a1s[n]
    float ss = 0.f, dd = 0.f;
    for (int n = 0; n < 256; ++n) {
      float w = W1[(size_t)g * 256 + n];
      ss += w * a1s[n];
      dd += w * a1d[n];
    }
    w1as[g] = ss;
    w1ad[g] = dd;
  }
}

// ---------------- merged: dst-partitioned histogram + x->bf16 cast + alpha dots ----------------

__global__ __launch_bounds__(256) void cast_alpha_hist(
    const float* __restrict__ x, ushort_t* __restrict__ x_bf,
    const float* __restrict__ w1as, const float* __restrict__ w1ad,
    float* __restrict__ asrc1, float* __restrict__ adst1,
    const int* __restrict__ ei, int* __restrict__ deg) {
  int gb = blockIdx.x;
  if (gb < HB) {
    const int part = gb & 7;
    const int pb = gb >> 3;
    const int PB = HB >> 3;
    const int lo = part * (N_NODES >> 3);
    const int hi = (part == 7) ? N_NODES : lo + (N_NODES >> 3);
    for (int e = pb * 256 + threadIdx.x; e < E_TOT; e += PB * 256) {
      int d = (e < N_EDGES) ? ei[N_EDGES + e] : (e - N_EDGES);
      if (d >= lo && d < hi) atomicAdd(&deg[d], 1);
    }
    return;
  }
  gb -= HB;
  const int lane = threadIdx.x & 63;
  const int half = lane >> 5;
  const int l31 = lane & 31;
  const int wv = gb * 4 + (threadIdx.x >> 6);
  const int R = (N_NODES + CB * 4 - 1) / (CB * 4);
  int base = wv * R;
  int limit = base + R;
  if (limit > N_NODES) limit = N_NODES;
  float4 ws = *reinterpret_cast<const float4*>(&w1as[l31 * 4]);
  float4 wd = *reinterpret_cast<const float4*>(&w1ad[l31 * 4]);
  for (int n0 = base; n0 < limit; n0 += 2) {
    int n = n0 + half;
    bool valid = n < limit;
    float4 v = make_float4(0.f, 0.f, 0.f, 0.f);
    if (valid) v = *reinterpret_cast<const float4*>(&x[(size_t)n * 128 + l31 * 4]);
    if (valid) {
      ushort4 o;
      o.x = f2b(v.x); o.y = f2b(v.y); o.z = f2b(v.z); o.w = f2b(v.w);
      *reinterpret_cast<ushort4*>(&x_bf[(size_t)n * 128 + l31 * 4]) = o;
    }
    float ps = v.x * ws.x + v.y * ws.y + v.z * ws.z + v.w * ws.w;
    float pd = v.x * wd.x + v.y * wd.y + v.z * wd.z + v.w * wd.w;
#pragma unroll
    for (int off = 16; off; off >>= 1) {
      ps += __shfl_xor(ps, off);
      pd += __shfl_xor(pd, off);
    }
    if (l31 == 0 && valid) { asrc1[n] = ps; adst1[n] = pd; }
  }
}

// ---------------- single-pass decoupled-lookback scan ----------------

__global__ __launch_bounds__(1024) void scan_lookback(
    const int* __restrict__ deg, ull_t* __restrict__ state,
    int* __restrict__ rowptr, int* __restrict__ fillpos) {
  __shared__ int sh[1024];
  __shared__ int boff_sh;
  const int tid = threadIdx.x;
  const int bid = blockIdx.x;
  int i = bid * 1024 + tid;
  int v = (i < N_NODES) ? deg[i] : 0;
  sh[tid] = v;
  __syncthreads();
  for (int off = 1; off < 1024; off <<= 1) {
    int t = (tid >= off) ? sh[tid - off] : 0;
    __syncthreads();
    sh[tid] += t;
    __syncthreads();
  }
  if (tid == 0) {
    int total = sh[1023];
    atomicExch(&state[bid], (1ULL << 32) | (unsigned int)total);
    long long excl = 0;
    int p = bid - 1;
    while (p >= 0) {
      ull_t st;
      do { st = atomicAdd(&state[p], 0ULL); } while (st == 0);
      excl += (int)(st & 0xffffffffULL);
      if ((st >> 32) == 2) break;
      --p;
    }
    atomicExch(&state[bid], (2ULL << 32) | (unsigned int)(excl + total));
    boff_sh = (int)excl;
  }
  __syncthreads();
  if (i < N_NODES) {
    int excl = sh[tid] - v + boff_sh;
    rowptr[i] = excl;
    fillpos[i] = excl;
    if (i == N_NODES - 1) rowptr[N_NODES] = excl + v;
  }
}

// ---------------- dst-partitioned edge fill ----------------

__global__ __launch_bounds__(256) void fill_kernel(
    const int* __restrict__ ei, int* __restrict__ fillpos, int* __restrict__ col) {
  const int part = blockIdx.x & 7;
  const int gb = blockIdx.x >> 3;
  const int PB = FB >> 3;
  const int lo = part * (N_NODES >> 3);
  const int hi = (part == 7) ? N_NODES : lo + (N_NODES >> 3);
  for (int e = gb * 256 + threadIdx.x; e < E_TOT; e += PB * 256) {
    int d = (e < N_EDGES) ? ei[N_EDGES + e] : (e - N_EDGES);
    if (d >= lo && d < hi) {
      int s = (e < N_EDGES) ? ei[e] : d;
      int p = atomicAdd(&fillpos[d], 1);
      col[p] = s;
    }
  }
}

// ---------------- layer-1 aggregation: 2 nodes/wave, 512B per VMEM instr ----------------

__global__ __launch_bounds__(256) void fused_aggx(
    const ushort_t* __restrict__ xb, const int* __restrict__ rowptr,
    const int* __restrict__ col, const float* __restrict__ asrc,
    const float* __restrict__ adst, ushort_t* __restrict__ out) {
  __shared__ float wlds[8][64];
  __shared__ int clds[8][64];
  const int wid = threadIdx.x >> 6;
  const int lane = threadIdx.x & 63;
  const int half = lane >> 5;
  const int l31 = lane & 31;
  const int slot = wid * 2 + half;
  const int n = blockIdx.x * 8 + slot;
  if (n >= N_NODES) return;
  int beg = rowptr[n], end = rowptr[n + 1];
  int deg = end - beg;
  float ad = adst[n];
  float ssum = 0.f;
  int cap = deg < 64 ? deg : 64;
  for (int t = l31; t < cap; t += 32) {
    int s = col[beg + t];
    float we = __expf(leaky(asrc[s] + ad));
    ssum += we;
    wlds[slot][t] = we;
    clds[slot][t] = s << 8;   // byte offset of 256B row
  }
  for (int jj = beg + 64 + l31; jj < end; jj += 32)   // essentially never
    ssum += __expf(leaky(asrc[col[jj]] + ad));
#pragma unroll
  for (int off = 16; off; off >>= 1) ssum += __shfl_xor(ssum, off);
  float inv = 1.0f / ssum;
  for (int t = l31; t < cap; t += 32) wlds[slot][t] *= inv;
  float a0 = 0.f, a1 = 0.f, a2 = 0.f, a3 = 0.f;
  const char* hb = (const char*)xb + l31 * 8;
  if (deg <= 64) {
    int t = 0;
    for (; t + 8 <= deg; t += 8) {
      int4 cA = *reinterpret_cast<const int4*>(&clds[slot][t]);
      int4 cB = *reinterpret_cast<const int4*>(&clds[slot][t + 4]);
      float4 wA = *reinterpret_cast<const float4*>(&wlds[slot][t]);
      float4 wB = *reinterpret_cast<const float4*>(&wlds[slot][t + 4]);
      uint2 q0 = *reinterpret_cast<const uint2*>(hb + cA.x);
      uint2 q1 = *reinterpret_cast<const uint2*>(hb + cA.y);
      uint2 q2 = *reinterpret_cast<const uint2*>(hb + cA.z);
      uint2 q3 = *reinterpret_cast<const uint2*>(hb + cA.w);
      uint2 q4 = *reinterpret_cast<const uint2*>(hb + cB.x);
      uint2 q5 = *reinterpret_cast<const uint2*>(hb + cB.y);
      uint2 q6 = *reinterpret_cast<const uint2*>(hb + cB.z);
      uint2 q7 = *reinterpret_cast<const uint2*>(hb + cB.w);
      a0 += wA.x * blo(q0.x) + wA.y * blo(q1.x) + wA.z * blo(q2.x) + wA.w * blo(q3.x)
          + wB.x * blo(q4.x) + wB.y * blo(q5.x) + wB.z * blo(q6.x) + wB.w * blo(q7.x);
      a1 += wA.x * bhi(q0.x) + wA.y * bhi(q1.x) + wA.z * bhi(q2.x) + wA.w * bhi(q3.x)
          + wB.x * bhi(q4.x) + wB.y * bhi(q5.x) + wB.z * bhi(q6.x) + wB.w * bhi(q7.x);
      a2 += wA.x * blo(q0.y) + wA.y * blo(q1.y) + wA.z * blo(q2.y) + wA.w * blo(q3.y)
          + wB.x * blo(q4.y) + wB.y * blo(q5.y) + wB.z * blo(q6.y) + wB.w * blo(q7.y);
      a3 += wA.x * bhi(q0.y) + wA.y * bhi(q1.y) + wA.z * bhi(q2.y) + wA.w * bhi(q3.y)
          + wB.x * bhi(q4.y) + wB.y * bhi(q5.y) + wB.z * bhi(q6.y) + wB.w * bhi(q7.y);
    }
    for (; t < deg; ++t) {
      int c = clds[slot][t];
      float w = wlds[slot][t];
      uint2 q = *reinterpret_cast<const uint2*>(hb + c);
      a0 += w * blo(q.x); a1 += w * bhi(q.x);
      a2 += w * blo(q.y); a3 += w * bhi(q.y);
    }
  } else {
    for (int j = beg; j < end; ++j) {
      int sj = col[j];
      float w = __expf(leaky(asrc[sj] + ad)) * inv;
      uint2 q = *reinterpret_cast<const uint2*>(&xb[(size_t)sj * 128 + l31 * 4]);
      a0 += w * blo(q.x); a1 += w * bhi(q.x);
      a2 += w * blo(q.y); a3 += w * bhi(q.y);
    }
  }
  ushort4 o;
  o.x = f2b(a0); o.y = f2b(a1); o.z = f2b(a2); o.w = f2b(a3);
  *reinterpret_cast<ushort4*>(&out[(size_t)n * 128 + l31 * 4]) = o;
}

// ---------------- fused GEMM1+GEMM2: h2 = relu(aggX@W1+b1)@W2, T never leaves LDS ----------------
// Per 128-row block: stage aggX (swizzled As, 32KB). For each 128-col chunk of
// the intermediate: GEMM1 MFMAs -> T=relu(.+b1) into swizzled Ts (32KB) ->
// barrier -> GEMM2 MFMAs accumulate h2 += T @ W2t_chunk. Epilogue: h2 store +
// alpha2 dots (direct, no atomics). a1b never touches global memory.

__global__ __launch_bounds__(256) void gemm12_kernel(
    const ushort_t* __restrict__ aggX, const ushort_t* __restrict__ W1t,
    const float* __restrict__ b1, const ushort_t* __restrict__ W2t,
    const float* __restrict__ a2s, const float* __restrict__ a2d,
    ushort_t* __restrict__ h2, float* __restrict__ asrc2,
    float* __restrict__ adst2, int M) {
  __shared__ ushort_t As[128 * 128];   // 32KB
  __shared__ ushort_t Ts[128 * 128];   // 32KB
  const int tid = threadIdx.x;
  const int lane = tid & 63;
  const int wid = tid >> 6;
  const int l15 = lane & 15;
  const int l4 = lane >> 4;
  const int rowBase = blockIdx.x * 128;
  const int wm = wid & 1;    // GEMM1: 2x2 wave grid (WM=64, WN=64)
  const int wn = wid >> 1;

  // stage As = aggX[rowBase..+128][0..128], swizzled
  for (int c = tid; c < 128 * 128 / 8; c += 256) {
    int r = c >> 4;
    int k8 = (c & 15) << 3;
    int gr = rowBase + r;
    short8v u = {};
    if (gr < M) u = *(const short8v*)&aggX[(size_t)gr * 128 + k8];
    int byte = ((r * 128 + k8) * 2) ^ ((r & 7) << 4);
    *(short8v*)((char*)As + byte) = u;
  }
  __syncthreads();

  f32x4 acc2[2][4] = {};
#pragma unroll
  for (int chunk = 0; chunk < 2; ++chunk) {
    // GEMM1: acc1 = As @ W1t[chunk cols]
    f32x4 acc1[4][4] = {};
#pragma unroll
    for (int kk = 0; kk < 4; ++kk) {
      short8v afr[4];
#pragma unroll
      for (int m = 0; m < 4; ++m) {
        int r = wm * 64 + m * 16 + l15;
        int byte = ((r * 128 + kk * 32 + l4 * 8) * 2) ^ ((r & 7) << 4);
        afr[m] = *(const short8v*)((const char*)As + byte);
      }
      short8v bfr[4];
#pragma unroll
      for (int n = 0; n < 4; ++n) {
        int bcol = chunk * 128 + wn * 64 + n * 16 + l15;
        bfr[n] = *(const short8v*)&W1t[(size_t)bcol * 128 + kk * 32 + l4 * 8];
      }
#pragma unroll
      for (int m = 0; m < 4; ++m)
#pragma unroll
        for (int n = 0; n < 4; ++n)
          acc1[m][n] = __builtin_amdgcn_mfma_f32_16x16x32_bf16(
              afr[m], bfr[n], acc1[m][n], 0, 0, 0);
    }
    if (chunk) __syncthreads();   // prev chunk's GEMM2 reads of Ts must finish
    // T = relu(acc1 + b1) -> Ts (swizzled); C layout col=l15, row=l4*4+j
#pragma unroll
    for (int m = 0; m < 4; ++m)
#pragma unroll
      for (int n = 0; n < 4; ++n) {
        int colc = wn * 64 + n * 16 + l15;
        float bv = b1[chunk * 128 + colc];
#pragma unroll
        for (int j = 0; j < 4; ++j) {
          int r = wm * 64 + m * 16 + l4 * 4 + j;
          float v = fmaxf(acc1[m][n][j] + bv, 0.f);
          int byte = ((r * 128 + colc) * 2) ^ ((r & 7) << 4);
          *(ushort_t*)((char*)Ts + byte) = f2b(v);
        }
      }
    __syncthreads();
    // GEMM2: acc2 += Ts @ W2t[:, chunk*128..+128]; waves split M (WM2=32)
#pragma unroll
    for (int kk = 0; kk < 4; ++kk) {
      short8v afr2[2];
#pragma unroll
      for (int m = 0; m < 2; ++m) {
        int r = wid * 32 + m * 16 + l15;
        int byte = ((r * 128 + kk * 32 + l4 * 8) * 2) ^ ((r & 7) << 4);
        afr2[m] = *(const short8v*)((const char*)Ts + byte);
      }
      short8v bfr2[4];
#pragma unroll
      for (int n = 0; n < 4; ++n) {
        int bcol = n * 16 + l15;
        bfr2[n] = *(const short8v*)&W2t[(size_t)bcol * 256 + chunk * 128 + kk * 32 + l4 * 8];
      }
#pragma unroll
      for (int m = 0; m < 2; ++m)
#pragma unroll
        for (int n = 0; n < 4; ++n)
          acc2[m][n] = __builtin_amdgcn_mfma_f32_16x16x32_bf16(
              afr2[m], bfr2[n], acc2[m][n], 0, 0, 0);
    }
  }
  // epilogue: h2 store + alpha2 dots (direct store, block covers all 64 cols)
  float as_v[4], ad_v[4];
#pragma unroll
  for (int n = 0; n < 4; ++n) {
    as_v[n] = a2s[n * 16 + l15];
    ad_v[n] = a2d[n * 16 + l15];
  }
#pragma unroll
  for (int m = 0; m < 2; ++m) {
    int r0 = rowBase + wid * 32 + m * 16 + l4 * 4;
#pragma unroll
    for (int j = 0; j < 4; ++j) {
      int gr = r0 + j;
      float ss = 0.f, dd = 0.f;
#pragma unroll
      for (int n = 0; n < 4; ++n) {
        float v = acc2[m][n][j];
        if (gr < M) h2[(size_t)gr * 64 + n * 16 + l15] = f2b(v);
        ss += v * as_v[n];
        dd += v * ad_v[n];
      }
#pragma unroll
      for (int o = 1; o < 16; o <<= 1) {
        ss += __shfl_xor(ss, o);
        dd += __shfl_xor(dd, o);
      }
      if (l15 == 0 && gr < M) { asrc2[gr] = ss; adst2[gr] = dd; }
    }
  }
}

// ---------------- layer-2 aggregation: 2 nodes/wave (uint = 2 channels/lane) ----------------

__global__ __launch_bounds__(256) void fused_agg2(
    const ushort_t* __restrict__ h, const int* __restrict__ rowptr,
    const int* __restrict__ col, const float* __restrict__ asrc,
    const float* __restrict__ adst, const float* __restrict__ bias,
    float* __restrict__ out) {
  __shared__ float wlds[8][64];
  __shared__ int clds[8][64];
  const int wid = threadIdx.x >> 6;
  const int lane = threadIdx.x & 63;
  const int half = lane >> 5;
  const int l31 = lane & 31;
  const int slot = wid * 2 + half;
  const int n = blockIdx.x * 8 + slot;
  if (n >= N_NODES) return;
  int beg = rowptr[n], end = rowptr[n + 1];
  int deg = end - beg;
  float ad = adst[n];
  float ssum = 0.f;
  int cap = deg < 64 ? deg : 64;
  for (int t = l31; t < cap; t += 32) {
    int s = col[beg + t];
    float we = __expf(leaky(asrc[s] + ad));
    ssum += we;
    wlds[slot][t] = we;
    clds[slot][t] = s << 7;   // byte offset of 128B row
  }
  for (int jj = beg + 64 + l31; jj < end; jj += 32)
    ssum += __expf(leaky(asrc[col[jj]] + ad));
#pragma unroll
  for (int off = 16; off; off >>= 1) ssum += __shfl_xor(ssum, off);
  float inv = 1.0f / ssum;
  for (int t = l31; t < cap; t += 32) wlds[slot][t] *= inv;
  float a0 = 0.f, a1 = 0.f;
  const char* hb = (const char*)h + l31 * 4;
  if (deg <= 64) {
    int t = 0;
    for (; t + 8 <= deg; t += 8) {
      int4 cA = *reinterpret_cast<const int4*>(&clds[slot][t]);
      int4 cB = *reinterpret_cast<const int4*>(&clds[slot][t + 4]);
      float4 wA = *reinterpret_cast<const float4*>(&wlds[slot][t]);
      float4 wB = *reinterpret_cast<const float4*>(&wlds[slot][t + 4]);
      unsigned int q0 = *reinterpret_cast<const unsigned int*>(hb + cA.x);
      unsigned int q1 = *reinterpret_cast<const unsigned int*>(hb + cA.y);
      unsigned int q2 = *reinterpret_cast<const unsigned int*>(hb + cA.z);
      unsigned int q3 = *reinterpret_cast<const unsigned int*>(hb + cA.w);
      unsigned int q4 = *reinterpret_cast<const unsigned int*>(hb + cB.x);
      unsigned int q5 = *reinterpret_cast<const unsigned int*>(hb + cB.y);
      unsigned int q6 = *reinterpret_cast<const unsigned int*>(hb + cB.z);
      unsigned int q7 = *reinterpret_cast<const unsigned int*>(hb + cB.w);
      a0 += wA.x * blo(q0) + wA.y * blo(q1) + wA.z * blo(q2) + wA.w * blo(q3)
          + wB.x * blo(q4) + wB.y * blo(q5) + wB.z * blo(q6) + wB.w * blo(q7);
      a1 += wA.x * bhi(q0) + wA.y * bhi(q1) + wA.z * bhi(q2) + wA.w * bhi(q3)
          + wB.x * bhi(q4) + wB.y * bhi(q5) + wB.z * bhi(q6) + wB.w * bhi(q7);
    }
    for (; t < deg; ++t) {
      int c = clds[slot][t];
      float w = wlds[slot][t];
      unsigned int q = *reinterpret_cast<const unsigned int*>(hb + c);
      a0 += w * blo(q);
      a1 += w * bhi(q);
    }
  } else {
    for (int j = beg; j < end; ++j) {
      int sj = col[j];
      float w = __expf(leaky(asrc[sj] + ad)) * inv;
      unsigned int q = *reinterpret_cast<const unsigned int*>(&h[(size_t)sj * 64 + l31 * 2]);
      a0 += w * blo(q);
      a1 += w * bhi(q);
    }
  }
  float2 o;
  o.x = a0 + bias[l31 * 2];
  o.y = a1 + bias[l31 * 2 + 1];
  *reinterpret_cast<float2*>(&out[(size_t)n * 64 + l31 * 2]) = o;
}

// ---------------- launch ----------------

extern "C" void kernel_launch(void* const* d_in, const int* in_sizes, int n_in,
                              void* d_out, int out_size, void* d_ws, size_t ws_size,
                              hipStream_t stream) {
  const float* x    = (const float*)d_in[0];
  const int*   ei   = (const int*)d_in[1];
  const float* W1   = (const float*)d_in[2];
  const float* a1s  = (const float*)d_in[3];
  const float* a1d  = (const float*)d_in[4];
  const float* b1   = (const float*)d_in[5];
  const float* W2   = (const float*)d_in[6];
  const float* a2s  = (const float*)d_in[7];
  const float* a2d  = (const float*)d_in[8];
  const float* b2   = (const float*)d_in[9];
  float* out = (float*)d_out;

  char* ws = (char*)d_ws;
  size_t off = 0;
  auto alloc = [&](size_t bytes) {
    void* p = ws + off;
    off += bytes;
    off = (off + 255) & ~(size_t)255;
    return p;
  };

  ushort_t* x_bf = (ushort_t*)alloc((size_t)N_NODES * 128 * 2);  // bf16 x
  ushort_t* aggX = (ushort_t*)alloc((size_t)N_NODES * 128 * 2);  // bf16 sum(alpha*x)
  ushort_t* h2   = (ushort_t*)alloc((size_t)N_NODES * 64 * 2);   // bf16
  ushort_t* W1t  = (ushort_t*)alloc((size_t)256 * 128 * 2);
  ushort_t* W2t  = (ushort_t*)alloc((size_t)64 * 256 * 2);
  float* w1as    = (float*)alloc((size_t)128 * 4);
  float* w1ad    = (float*)alloc((size_t)128 * 4);
  float* asrc1   = (float*)alloc((size_t)N_NODES * 4);
  float* adst1   = (float*)alloc((size_t)N_NODES * 4);
  float* asrc2   = (float*)alloc((size_t)N_NODES * 4);
  float* adst2   = (float*)alloc((size_t)N_NODES * 4);
  int*   deg     = (int*)alloc((size_t)N_NODES * 4);
  int*   rowptr  = (int*)alloc((size_t)(N_NODES + 1) * 4);
  int*   fillp   = (int*)alloc((size_t)N_NODES * 4);
  int*   col     = (int*)alloc((size_t)E_TOT * 4);
  ull_t* state   = (ull_t*)alloc((size_t)SCAN_NB * 8);

  const int nodeBlocks8 = (N_NODES + 7) / 8;

  // 1. prep: zeros + W transposes + w1as/w1ad
  prep_kernel<<<1024, 256, 0, stream>>>(deg, state, W1, W1t, W2, W2t,
                                        a1s, a1d, w1as, w1ad);
  // 2. dst-partitioned histogram + x->bf16 + alpha1 row-dots (merged)
  cast_alpha_hist<<<HB + CB, 256, 0, stream>>>(x, x_bf, w1as, w1ad,
                                               asrc1, adst1, ei, deg);
  // 3. single-pass scan
  scan_lookback<<<SCAN_NB, 1024, 0, stream>>>(deg, state, rowptr, fillp);
  // 4. dst-partitioned edge fill (XCD-local col writes)
  fill_kernel<<<FB, 256, 0, stream>>>(ei, fillp, col);
  // 5. layer-1 aggregation over x_bf (2 nodes/wave, 512B/VMEM)
  fused_aggx<<<nodeBlocks8, 256, 0, stream>>>(x_bf, rowptr, col, asrc1, adst1, aggX);
  // 6. fused GEMM1+GEMM2 (+relu+b1 in LDS, alpha2 epilogue)
  gemm12_kernel<<<GBM, 256, 0, stream>>>(aggX, W1t, b1, W2t, a2s, a2d,
                                         h2, asrc2, adst2, N_NODES);
  // 7. layer-2 softmax+aggregate (2 nodes/wave, +bias) -> out
  fused_agg2<<<nodeBlocks8, 256, 0, stream>>>(h2, rowptr, col, asrc2, adst2, b2, out);
}

// Round 18
// 220.235 us; speedup vs baseline: 1.4100x; 1.0708x over previous
//
#include <hip/hip_runtime.h>
#include <math.h>

#define N_NODES 100000
#define N_EDGES 800000
#define E_TOT (N_EDGES + N_NODES)
#define NEG_SLOPE 0.2f
#define SCAN_NB ((N_NODES + 1023) / 1024)
#define GB64 ((N_NODES + 63) / 64)
#define HB 1024   // histogram blocks: 8 dst-partitions x 128
#define CB 2048   // cast/alpha blocks
#define FB 2048   // fill blocks: 8 partitions x 256

typedef unsigned short ushort_t;
typedef unsigned long long ull_t;
typedef __attribute__((ext_vector_type(8))) short short8v;   // 8 bf16
typedef __attribute__((ext_vector_type(4))) float f32x4;

static __device__ __forceinline__ float leaky(float e) {
  return e > 0.f ? e : NEG_SLOPE * e;
}

static __device__ __forceinline__ float b2f(ushort_t u) {
  union { unsigned int i; float f; } x;
  x.i = ((unsigned int)u) << 16;
  return x.f;
}

static __device__ __forceinline__ float blo(unsigned int q) {
  union { unsigned int i; float f; } x;
  x.i = q << 16;
  return x.f;
}

static __device__ __forceinline__ float bhi(unsigned int q) {
  union { unsigned int i; float f; } x;
  x.i = q & 0xffff0000u;
  return x.f;
}

static __device__ __forceinline__ ushort_t f2b(float f) {
  union { float f; unsigned int i; } x;
  x.f = f;
  unsigned int r = x.i + 0x7FFFu + ((x.i >> 16) & 1u);  // RNE (finite inputs)
  return (ushort_t)(r >> 16);
}

// ---------------- prep: zeros + weight transposes + w1as/w1ad = W1 @ a1{s,d} ----------------

__global__ void prep_kernel(int* __restrict__ deg, ull_t* __restrict__ state,
                            const float* __restrict__ W1, ushort_t* __restrict__ W1t,
                            const float* __restrict__ W2, ushort_t* __restrict__ W2t,
                            const float* __restrict__ a1s, const float* __restrict__ a1d,
                            float* __restrict__ w1as, float* __restrict__ w1ad) {
  int g = blockIdx.x * 256 + threadIdx.x;
  const int GT = gridDim.x * 256;
  for (int i = g; i < N_NODES; i += GT) deg[i] = 0;
  for (int i = g; i < 256 * 128; i += GT) {       // W1t[n][k] = W1[k][n]
    int n = i >> 7, k = i & 127;
    W1t[i] = f2b(W1[(size_t)k * 256 + n]);
  }
  for (int i = g; i < 64 * 256; i += GT) {        // W2t[n][k] = W2[k][n]
    int n = i >> 8, k = i & 255;
    W2t[i] = f2b(W2[(size_t)k * 64 + n]);
  }
  for (int i = g; i < SCAN_NB; i += GT) state[i] = 0;
  if (g < 128) {                                  // w1as[k] = sum_n W1[k][n]*a1s[n]
    float ss = 0.f, dd = 0.f;
    for (int n = 0; n < 256; ++n) {
      float w = W1[(size_t)g * 256 + n];
      ss += w * a1s[n];
      dd += w * a1d[n];
    }
    w1as[g] = ss;
    w1ad[g] = dd;
  }
}

// ---------------- merged: dst-partitioned histogram + x->bf16 cast + alpha dots ----------------

__global__ __launch_bounds__(256) void cast_alpha_hist(
    const float* __restrict__ x, ushort_t* __restrict__ x_bf,
    const float* __restrict__ w1as, const float* __restrict__ w1ad,
    float* __restrict__ asrc1, float* __restrict__ adst1,
    const int* __restrict__ ei, int* __restrict__ deg) {
  int gb = blockIdx.x;
  if (gb < HB) {
    const int part = gb & 7;
    const int pb = gb >> 3;
    const int PB = HB >> 3;
    const int lo = part * (N_NODES >> 3);
    const int hi = (part == 7) ? N_NODES : lo + (N_NODES >> 3);
    for (int e = pb * 256 + threadIdx.x; e < E_TOT; e += PB * 256) {
      int d = (e < N_EDGES) ? ei[N_EDGES + e] : (e - N_EDGES);
      if (d >= lo && d < hi) atomicAdd(&deg[d], 1);
    }
    return;
  }
  gb -= HB;
  const int lane = threadIdx.x & 63;
  const int half = lane >> 5;
  const int l31 = lane & 31;
  const int wv = gb * 4 + (threadIdx.x >> 6);
  const int R = (N_NODES + CB * 4 - 1) / (CB * 4);
  int base = wv * R;
  int limit = base + R;
  if (limit > N_NODES) limit = N_NODES;
  float4 ws = *reinterpret_cast<const float4*>(&w1as[l31 * 4]);
  float4 wd = *reinterpret_cast<const float4*>(&w1ad[l31 * 4]);
  for (int n0 = base; n0 < limit; n0 += 2) {
    int n = n0 + half;
    bool valid = n < limit;
    float4 v = make_float4(0.f, 0.f, 0.f, 0.f);
    if (valid) v = *reinterpret_cast<const float4*>(&x[(size_t)n * 128 + l31 * 4]);
    if (valid) {
      ushort4 o;
      o.x = f2b(v.x); o.y = f2b(v.y); o.z = f2b(v.z); o.w = f2b(v.w);
      *reinterpret_cast<ushort4*>(&x_bf[(size_t)n * 128 + l31 * 4]) = o;
    }
    float ps = v.x * ws.x + v.y * ws.y + v.z * ws.z + v.w * ws.w;
    float pd = v.x * wd.x + v.y * wd.y + v.z * wd.z + v.w * wd.w;
#pragma unroll
    for (int off = 16; off; off >>= 1) {
      ps += __shfl_xor(ps, off);
      pd += __shfl_xor(pd, off);
    }
    if (l31 == 0 && valid) { asrc1[n] = ps; adst1[n] = pd; }
  }
}

// ---------------- single-pass decoupled-lookback scan ----------------

__global__ __launch_bounds__(1024) void scan_lookback(
    const int* __restrict__ deg, ull_t* __restrict__ state,
    int* __restrict__ rowptr, int* __restrict__ fillpos) {
  __shared__ int sh[1024];
  __shared__ int boff_sh;
  const int tid = threadIdx.x;
  const int bid = blockIdx.x;
  int i = bid * 1024 + tid;
  int v = (i < N_NODES) ? deg[i] : 0;
  sh[tid] = v;
  __syncthreads();
  for (int off = 1; off < 1024; off <<= 1) {
    int t = (tid >= off) ? sh[tid - off] : 0;
    __syncthreads();
    sh[tid] += t;
    __syncthreads();
  }
  if (tid == 0) {
    int total = sh[1023];
    atomicExch(&state[bid], (1ULL << 32) | (unsigned int)total);
    long long excl = 0;
    int p = bid - 1;
    while (p >= 0) {
      ull_t st;
      do { st = atomicAdd(&state[p], 0ULL); } while (st == 0);
      excl += (int)(st & 0xffffffffULL);
      if ((st >> 32) == 2) break;
      --p;
    }
    atomicExch(&state[bid], (2ULL << 32) | (unsigned int)(excl + total));
    boff_sh = (int)excl;
  }
  __syncthreads();
  if (i < N_NODES) {
    int excl = sh[tid] - v + boff_sh;
    rowptr[i] = excl;
    fillpos[i] = excl;
    if (i == N_NODES - 1) rowptr[N_NODES] = excl + v;
  }
}

// ---------------- dst-partitioned edge fill ----------------

__global__ __launch_bounds__(256) void fill_kernel(
    const int* __restrict__ ei, int* __restrict__ fillpos, int* __restrict__ col) {
  const int part = blockIdx.x & 7;
  const int gb = blockIdx.x >> 3;
  const int PB = FB >> 3;
  const int lo = part * (N_NODES >> 3);
  const int hi = (part == 7) ? N_NODES : lo + (N_NODES >> 3);
  for (int e = gb * 256 + threadIdx.x; e < E_TOT; e += PB * 256) {
    int d = (e < N_EDGES) ? ei[N_EDGES + e] : (e - N_EDGES);
    if (d >= lo && d < hi) {
      int s = (e < N_EDGES) ? ei[e] : d;
      int p = atomicAdd(&fillpos[d], 1);
      col[p] = s;
    }
  }
}

// ---------------- layer-1 aggregation: 2 nodes/wave, 512B per VMEM instr ----------------

__global__ __launch_bounds__(256) void fused_aggx(
    const ushort_t* __restrict__ xb, const int* __restrict__ rowptr,
    const int* __restrict__ col, const float* __restrict__ asrc,
    const float* __restrict__ adst, ushort_t* __restrict__ out) {
  __shared__ float wlds[8][64];
  __shared__ int clds[8][64];
  const int wid = threadIdx.x >> 6;
  const int lane = threadIdx.x & 63;
  const int half = lane >> 5;
  const int l31 = lane & 31;
  const int slot = wid * 2 + half;
  const int n = blockIdx.x * 8 + slot;
  if (n >= N_NODES) return;
  int beg = rowptr[n], end = rowptr[n + 1];
  int deg = end - beg;
  float ad = adst[n];
  float ssum = 0.f;
  int cap = deg < 64 ? deg : 64;
  for (int t = l31; t < cap; t += 32) {
    int s = col[beg + t];
    float we = __expf(leaky(asrc[s] + ad));
    ssum += we;
    wlds[slot][t] = we;
    clds[slot][t] = s << 8;   // byte offset of 256B row
  }
  for (int jj = beg + 64 + l31; jj < end; jj += 32)   // essentially never
    ssum += __expf(leaky(asrc[col[jj]] + ad));
#pragma unroll
  for (int off = 16; off; off >>= 1) ssum += __shfl_xor(ssum, off);
  float inv = 1.0f / ssum;
  for (int t = l31; t < cap; t += 32) wlds[slot][t] *= inv;
  float a0 = 0.f, a1 = 0.f, a2 = 0.f, a3 = 0.f;
  const char* hb = (const char*)xb + l31 * 8;
  if (deg <= 64) {
    int t = 0;
    for (; t + 8 <= deg; t += 8) {
      int4 cA = *reinterpret_cast<const int4*>(&clds[slot][t]);
      int4 cB = *reinterpret_cast<const int4*>(&clds[slot][t + 4]);
      float4 wA = *reinterpret_cast<const float4*>(&wlds[slot][t]);
      float4 wB = *reinterpret_cast<const float4*>(&wlds[slot][t + 4]);
      uint2 q0 = *reinterpret_cast<const uint2*>(hb + cA.x);
      uint2 q1 = *reinterpret_cast<const uint2*>(hb + cA.y);
      uint2 q2 = *reinterpret_cast<const uint2*>(hb + cA.z);
      uint2 q3 = *reinterpret_cast<const uint2*>(hb + cA.w);
      uint2 q4 = *reinterpret_cast<const uint2*>(hb + cB.x);
      uint2 q5 = *reinterpret_cast<const uint2*>(hb + cB.y);
      uint2 q6 = *reinterpret_cast<const uint2*>(hb + cB.z);
      uint2 q7 = *reinterpret_cast<const uint2*>(hb + cB.w);
      a0 += wA.x * blo(q0.x) + wA.y * blo(q1.x) + wA.z * blo(q2.x) + wA.w * blo(q3.x)
          + wB.x * blo(q4.x) + wB.y * blo(q5.x) + wB.z * blo(q6.x) + wB.w * blo(q7.x);
      a1 += wA.x * bhi(q0.x) + wA.y * bhi(q1.x) + wA.z * bhi(q2.x) + wA.w * bhi(q3.x)
          + wB.x * bhi(q4.x) + wB.y * bhi(q5.x) + wB.z * bhi(q6.x) + wB.w * bhi(q7.x);
      a2 += wA.x * blo(q0.y) + wA.y * blo(q1.y) + wA.z * blo(q2.y) + wA.w * blo(q3.y)
          + wB.x * blo(q4.y) + wB.y * blo(q5.y) + wB.z * blo(q6.y) + wB.w * blo(q7.y);
      a3 += wA.x * bhi(q0.y) + wA.y * bhi(q1.y) + wA.z * bhi(q2.y) + wA.w * bhi(q3.y)
          + wB.x * bhi(q4.y) + wB.y * bhi(q5.y) + wB.z * bhi(q6.y) + wB.w * bhi(q7.y);
    }
    for (; t < deg; ++t) {
      int c = clds[slot][t];
      float w = wlds[slot][t];
      uint2 q = *reinterpret_cast<const uint2*>(hb + c);
      a0 += w * blo(q.x); a1 += w * bhi(q.x);
      a2 += w * blo(q.y); a3 += w * bhi(q.y);
    }
  } else {
    for (int j = beg; j < end; ++j) {
      int sj = col[j];
      float w = __expf(leaky(asrc[sj] + ad)) * inv;
      uint2 q = *reinterpret_cast<const uint2*>(&xb[(size_t)sj * 128 + l31 * 4]);
      a0 += w * blo(q.x); a1 += w * bhi(q.x);
      a2 += w * blo(q.y); a3 += w * bhi(q.y);
    }
  }
  ushort4 o;
  o.x = f2b(a0); o.y = f2b(a1); o.z = f2b(a2); o.w = f2b(a3);
  *reinterpret_cast<ushort4*>(&out[(size_t)n * 128 + l31 * 4]) = o;
}

// ---------------- fused GEMM1+GEMM2, 64-row blocks, 32KB LDS (As reused as Ts) ----------------
// stage As(64x128,16KB) -> bar -> GEMM1 (acc1 in regs) -> bar -> Ts(64x256,32KB)
// overwrites As -> bar -> GEMM2 -> epilogue (h2 + alpha2 direct stores).
// 5 blocks/CU (vs 2 at 64KB) — occupancy was the round-17 binding constraint.

__global__ __launch_bounds__(256) void gemm12_kernel(
    const ushort_t* __restrict__ aggX, const ushort_t* __restrict__ W1t,
    const float* __restrict__ b1, const ushort_t* __restrict__ W2t,
    const float* __restrict__ a2s, const float* __restrict__ a2d,
    ushort_t* __restrict__ h2, float* __restrict__ asrc2,
    float* __restrict__ adst2, int M) {
  __shared__ ushort_t smem[64 * 256];   // 32KB; As = first 16KB, Ts = all of it
  const int tid = threadIdx.x;
  const int lane = tid & 63;
  const int wid = tid >> 6;
  const int l15 = lane & 15;
  const int l4 = lane >> 4;
  const int rowBase = blockIdx.x * 64;

  // stage As = aggX[rowBase..+64][0..128], swizzled
  for (int c = tid; c < 64 * 128 / 8; c += 256) {
    int r = c >> 4;
    int k8 = (c & 15) << 3;
    int gr = rowBase + r;
    short8v u = {};
    if (gr < M) u = *(const short8v*)&aggX[(size_t)gr * 128 + k8];
    int byte = ((r * 128 + k8) * 2) ^ ((r & 7) << 4);
    *(short8v*)((char*)smem + byte) = u;
  }
  __syncthreads();

  // GEMM1: wave owns all 64 rows x its 64 cols (acc1 = 16 x f32x4)
  f32x4 acc1[4][4] = {};
#pragma unroll
  for (int kk = 0; kk < 4; ++kk) {
    short8v afr[4];
#pragma unroll
    for (int m = 0; m < 4; ++m) {
      int r = m * 16 + l15;
      int byte = ((r * 128 + kk * 32 + l4 * 8) * 2) ^ ((r & 7) << 4);
      afr[m] = *(const short8v*)((const char*)smem + byte);
    }
    short8v bfr[4];
#pragma unroll
    for (int n = 0; n < 4; ++n) {
      int bcol = wid * 64 + n * 16 + l15;
      bfr[n] = *(const short8v*)&W1t[(size_t)bcol * 128 + kk * 32 + l4 * 8];
    }
#pragma unroll
    for (int m = 0; m < 4; ++m)
#pragma unroll
      for (int n = 0; n < 4; ++n)
        acc1[m][n] = __builtin_amdgcn_mfma_f32_16x16x32_bf16(
            afr[m], bfr[n], acc1[m][n], 0, 0, 0);
  }
  __syncthreads();   // all As reads complete before Ts overwrites

  // Ts = relu(acc1 + b1), swizzled [64][256]; C layout col=l15, row=l4*4+j
#pragma unroll
  for (int m = 0; m < 4; ++m)
#pragma unroll
    for (int n = 0; n < 4; ++n) {
      int colc = wid * 64 + n * 16 + l15;
      float bv = b1[colc];
#pragma unroll
      for (int j = 0; j < 4; ++j) {
        int r = m * 16 + l4 * 4 + j;
        float v = fmaxf(acc1[m][n][j] + bv, 0.f);
        int byte = ((r * 256 + colc) * 2) ^ ((r & 7) << 4);
        *(ushort_t*)((char*)smem + byte) = f2b(v);
      }
    }
  __syncthreads();

  // GEMM2: wave owns 16 rows x all 64 cols; K=256
  f32x4 acc2[4] = {};
#pragma unroll
  for (int kk = 0; kk < 8; ++kk) {
    int r = wid * 16 + l15;
    int byte = ((r * 256 + kk * 32 + l4 * 8) * 2) ^ ((r & 7) << 4);
    short8v afr2 = *(const short8v*)((const char*)smem + byte);
    short8v bfr2[4];
#pragma unroll
    for (int n = 0; n < 4; ++n) {
      int bcol = n * 16 + l15;
      bfr2[n] = *(const short8v*)&W2t[(size_t)bcol * 256 + kk * 32 + l4 * 8];
    }
#pragma unroll
    for (int n = 0; n < 4; ++n)
      acc2[n] = __builtin_amdgcn_mfma_f32_16x16x32_bf16(afr2, bfr2[n], acc2[n], 0, 0, 0);
  }
  // epilogue: h2 store + alpha2 dots (direct, no atomics)
  float as_v[4], ad_v[4];
#pragma unroll
  for (int n = 0; n < 4; ++n) {
    as_v[n] = a2s[n * 16 + l15];
    ad_v[n] = a2d[n * 16 + l15];
  }
#pragma unroll
  for (int j = 0; j < 4; ++j) {
    int gr = rowBase + wid * 16 + l4 * 4 + j;
    float ss = 0.f, dd = 0.f;
#pragma unroll
    for (int n = 0; n < 4; ++n) {
      float v = acc2[n][j];
      if (gr < M) h2[(size_t)gr * 64 + n * 16 + l15] = f2b(v);
      ss += v * as_v[n];
      dd += v * ad_v[n];
    }
#pragma unroll
    for (int o = 1; o < 16; o <<= 1) {
      ss += __shfl_xor(ss, o);
      dd += __shfl_xor(dd, o);
    }
    if (l15 == 0 && gr < M) { asrc2[gr] = ss; adst2[gr] = dd; }
  }
}

// ---------------- layer-2 aggregation: 2 nodes/wave (uint = 2 channels/lane) ----------------

__global__ __launch_bounds__(256) void fused_agg2(
    const ushort_t* __restrict__ h, const int* __restrict__ rowptr,
    const int* __restrict__ col, const float* __restrict__ asrc,
    const float* __restrict__ adst, const float* __restrict__ bias,
    float* __restrict__ out) {
  __shared__ float wlds[8][64];
  __shared__ int clds[8][64];
  const int wid = threadIdx.x >> 6;
  const int lane = threadIdx.x & 63;
  const int half = lane >> 5;
  const int l31 = lane & 31;
  const int slot = wid * 2 + half;
  const int n = blockIdx.x * 8 + slot;
  if (n >= N_NODES) return;
  int beg = rowptr[n], end = rowptr[n + 1];
  int deg = end - beg;
  float ad = adst[n];
  float ssum = 0.f;
  int cap = deg < 64 ? deg : 64;
  for (int t = l31; t < cap; t += 32) {
    int s = col[beg + t];
    float we = __expf(leaky(asrc[s] + ad));
    ssum += we;
    wlds[slot][t] = we;
    clds[slot][t] = s << 7;   // byte offset of 128B row
  }
  for (int jj = beg + 64 + l31; jj < end; jj += 32)
    ssum += __expf(leaky(asrc[col[jj]] + ad));
#pragma unroll
  for (int off = 16; off; off >>= 1) ssum += __shfl_xor(ssum, off);
  float inv = 1.0f / ssum;
  for (int t = l31; t < cap; t += 32) wlds[slot][t] *= inv;
  float a0 = 0.f, a1 = 0.f;
  const char* hb = (const char*)h + l31 * 4;
  if (deg <= 64) {
    int t = 0;
    for (; t + 8 <= deg; t += 8) {
      int4 cA = *reinterpret_cast<const int4*>(&clds[slot][t]);
      int4 cB = *reinterpret_cast<const int4*>(&clds[slot][t + 4]);
      float4 wA = *reinterpret_cast<const float4*>(&wlds[slot][t]);
      float4 wB = *reinterpret_cast<const float4*>(&wlds[slot][t + 4]);
      unsigned int q0 = *reinterpret_cast<const unsigned int*>(hb + cA.x);
      unsigned int q1 = *reinterpret_cast<const unsigned int*>(hb + cA.y);
      unsigned int q2 = *reinterpret_cast<const unsigned int*>(hb + cA.z);
      unsigned int q3 = *reinterpret_cast<const unsigned int*>(hb + cA.w);
      unsigned int q4 = *reinterpret_cast<const unsigned int*>(hb + cB.x);
      unsigned int q5 = *reinterpret_cast<const unsigned int*>(hb + cB.y);
      unsigned int q6 = *reinterpret_cast<const unsigned int*>(hb + cB.z);
      unsigned int q7 = *reinterpret_cast<const unsigned int*>(hb + cB.w);
      a0 += wA.x * blo(q0) + wA.y * blo(q1) + wA.z * blo(q2) + wA.w * blo(q3)
          + wB.x * blo(q4) + wB.y * blo(q5) + wB.z * blo(q6) + wB.w * blo(q7);
      a1 += wA.x * bhi(q0) + wA.y * bhi(q1) + wA.z * bhi(q2) + wA.w * bhi(q3)
          + wB.x * bhi(q4) + wB.y * bhi(q5) + wB.z * bhi(q6) + wB.w * bhi(q7);
    }
    for (; t < deg; ++t) {
      int c = clds[slot][t];
      float w = wlds[slot][t];
      unsigned int q = *reinterpret_cast<const unsigned int*>(hb + c);
      a0 += w * blo(q);
      a1 += w * bhi(q);
    }
  } else {
    for (int j = beg; j < end; ++j) {
      int sj = col[j];
      float w = __expf(leaky(asrc[sj] + ad)) * inv;
      unsigned int q = *reinterpret_cast<const unsigned int*>(&h[(size_t)sj * 64 + l31 * 2]);
      a0 += w * blo(q);
      a1 += w * bhi(q);
    }
  }
  float2 o;
  o.x = a0 + bias[l31 * 2];
  o.y = a1 + bias[l31 * 2 + 1];
  *reinterpret_cast<float2*>(&out[(size_t)n * 64 + l31 * 2]) = o;
}

// ---------------- launch ----------------

extern "C" void kernel_launch(void* const* d_in, const int* in_sizes, int n_in,
                              void* d_out, int out_size, void* d_ws, size_t ws_size,
                              hipStream_t stream) {
  const float* x    = (const float*)d_in[0];
  const int*   ei   = (const int*)d_in[1];
  const float* W1   = (const float*)d_in[2];
  const float* a1s  = (const float*)d_in[3];
  const float* a1d  = (const float*)d_in[4];
  const float* b1   = (const float*)d_in[5];
  const float* W2   = (const float*)d_in[6];
  const float* a2s  = (const float*)d_in[7];
  const float* a2d  = (const float*)d_in[8];
  const float* b2   = (const float*)d_in[9];
  float* out = (float*)d_out;

  char* ws = (char*)d_ws;
  size_t off = 0;
  auto alloc = [&](size_t bytes) {
    void* p = ws + off;
    off += bytes;
    off = (off + 255) & ~(size_t)255;
    return p;
  };

  ushort_t* x_bf = (ushort_t*)alloc((size_t)N_NODES * 128 * 2);  // bf16 x
  ushort_t* aggX = (ushort_t*)alloc((size_t)N_NODES * 128 * 2);  // bf16 sum(alpha*x)
  ushort_t* h2   = (ushort_t*)alloc((size_t)N_NODES * 64 * 2);   // bf16
  ushort_t* W1t  = (ushort_t*)alloc((size_t)256 * 128 * 2);
  ushort_t* W2t  = (ushort_t*)alloc((size_t)64 * 256 * 2);
  float* w1as    = (float*)alloc((size_t)128 * 4);
  float* w1ad    = (float*)alloc((size_t)128 * 4);
  float* asrc1   = (float*)alloc((size_t)N_NODES * 4);
  float* adst1   = (float*)alloc((size_t)N_NODES * 4);
  float* asrc2   = (float*)alloc((size_t)N_NODES * 4);
  float* adst2   = (float*)alloc((size_t)N_NODES * 4);
  int*   deg     = (int*)alloc((size_t)N_NODES * 4);
  int*   rowptr  = (int*)alloc((size_t)(N_NODES + 1) * 4);
  int*   fillp   = (int*)alloc((size_t)N_NODES * 4);
  int*   col     = (int*)alloc((size_t)E_TOT * 4);
  ull_t* state   = (ull_t*)alloc((size_t)SCAN_NB * 8);

  const int nodeBlocks8 = (N_NODES + 7) / 8;

  // 1. prep: zeros + W transposes + w1as/w1ad
  prep_kernel<<<1024, 256, 0, stream>>>(deg, state, W1, W1t, W2, W2t,
                                        a1s, a1d, w1as, w1ad);
  // 2. dst-partitioned histogram + x->bf16 + alpha1 row-dots (merged)
  cast_alpha_hist<<<HB + CB, 256, 0, stream>>>(x, x_bf, w1as, w1ad,
                                               asrc1, adst1, ei, deg);
  // 3. single-pass scan
  scan_lookback<<<SCAN_NB, 1024, 0, stream>>>(deg, state, rowptr, fillp);
  // 4. dst-partitioned edge fill (XCD-local col writes)
  fill_kernel<<<FB, 256, 0, stream>>>(ei, fillp, col);
  // 5. layer-1 aggregation over x_bf (2 nodes/wave, 512B/VMEM)
  fused_aggx<<<nodeBlocks8, 256, 0, stream>>>(x_bf, rowptr, col, asrc1, adst1, aggX);
  // 6. fused GEMM1+GEMM2 (64-row blocks, 32KB LDS, alpha2 epilogue)
  gemm12_kernel<<<GB64, 256, 0, stream>>>(aggX, W1t, b1, W2t, a2s, a2d,
                                          h2, asrc2, adst2, N_NODES);
  // 7. layer-2 softmax+aggregate (2 nodes/wave, +bias) -> out
  fused_agg2<<<nodeBlocks8, 256, 0, stream>>>(h2, rowptr, col, asrc2, adst2, b2, out);
}

// Round 19
// 219.920 us; speedup vs baseline: 1.4120x; 1.0014x over previous
//
#include <hip/hip_runtime.h>
#include <math.h>

#define N_NODES 100000
#define N_EDGES 800000
#define E_TOT (N_EDGES + N_NODES)
#define NEG_SLOPE 0.2f
#define SCAN_NB ((N_NODES + 1023) / 1024)
#define GB64 ((N_NODES + 63) / 64)
#define HB 1024   // histogram blocks: 8 dst-partitions x 128
#define CB 2048   // cast/alpha blocks
#define FB 2048   // fill blocks: 8 partitions x 256

typedef unsigned short ushort_t;
typedef unsigned long long ull_t;
typedef __attribute__((ext_vector_type(8))) short short8v;   // 8 bf16
typedef __attribute__((ext_vector_type(4))) float f32x4;

static __device__ __forceinline__ float leaky(float e) {
  return e > 0.f ? e : NEG_SLOPE * e;
}

static __device__ __forceinline__ float b2f(ushort_t u) {
  union { unsigned int i; float f; } x;
  x.i = ((unsigned int)u) << 16;
  return x.f;
}

static __device__ __forceinline__ float blo(unsigned int q) {
  union { unsigned int i; float f; } x;
  x.i = q << 16;
  return x.f;
}

static __device__ __forceinline__ float bhi(unsigned int q) {
  union { unsigned int i; float f; } x;
  x.i = q & 0xffff0000u;
  return x.f;
}

static __device__ __forceinline__ ushort_t f2b(float f) {
  union { float f; unsigned int i; } x;
  x.f = f;
  unsigned int r = x.i + 0x7FFFu + ((x.i >> 16) & 1u);  // RNE (finite inputs)
  return (ushort_t)(r >> 16);
}

// ---------------- prep: zeros + weight transposes + w1as/w1ad = W1 @ a1{s,d} ----------------

__global__ void prep_kernel(int* __restrict__ deg, ull_t* __restrict__ state,
                            const float* __restrict__ W1, ushort_t* __restrict__ W1t,
                            const float* __restrict__ W2, ushort_t* __restrict__ W2t,
                            const float* __restrict__ a1s, const float* __restrict__ a1d,
                            float* __restrict__ w1as, float* __restrict__ w1ad) {
  int g = blockIdx.x * 256 + threadIdx.x;
  const int GT = gridDim.x * 256;
  for (int i = g; i < N_NODES; i += GT) deg[i] = 0;
  for (int i = g; i < 256 * 128; i += GT) {       // W1t[n][k] = W1[k][n]
    int n = i >> 7, k = i & 127;
    W1t[i] = f2b(W1[(size_t)k * 256 + n]);
  }
  for (int i = g; i < 64 * 256; i += GT) {        // W2t[n][k] = W2[k][n]
    int n = i >> 8, k = i & 255;
    W2t[i] = f2b(W2[(size_t)k * 64 + n]);
  }
  for (int i = g; i < SCAN_NB; i += GT) state[i] = 0;
  if (g < 128) {                                  // w1as[k] = sum_n W1[k][n]*a1s[n]
    float ss = 0.f, dd = 0.f;
    for (int n = 0; n < 256; ++n) {
      float w = W1[(size_t)g * 256 + n];
      ss += w * a1s[n];
      dd += w * a1d[n];
    }
    w1as[g] = ss;
    w1ad[g] = dd;
  }
}

// ---------------- merged: dst-partitioned histogram + x->bf16 cast + alpha dots ----------------

__global__ __launch_bounds__(256) void cast_alpha_hist(
    const float* __restrict__ x, ushort_t* __restrict__ x_bf,
    const float* __restrict__ w1as, const float* __restrict__ w1ad,
    float* __restrict__ asrc1, float* __restrict__ adst1,
    const int* __restrict__ ei, int* __restrict__ deg) {
  int gb = blockIdx.x;
  if (gb < HB) {
    const int part = gb & 7;
    const int pb = gb >> 3;
    const int PB = HB >> 3;
    const int lo = part * (N_NODES >> 3);
    const int hi = (part == 7) ? N_NODES : lo + (N_NODES >> 3);
    for (int e = pb * 256 + threadIdx.x; e < E_TOT; e += PB * 256) {
      int d = (e < N_EDGES) ? ei[N_EDGES + e] : (e - N_EDGES);
      if (d >= lo && d < hi) atomicAdd(&deg[d], 1);
    }
    return;
  }
  gb -= HB;
  const int lane = threadIdx.x & 63;
  const int half = lane >> 5;
  const int l31 = lane & 31;
  const int wv = gb * 4 + (threadIdx.x >> 6);
  const int R = (N_NODES + CB * 4 - 1) / (CB * 4);
  int base = wv * R;
  int limit = base + R;
  if (limit > N_NODES) limit = N_NODES;
  float4 ws = *reinterpret_cast<const float4*>(&w1as[l31 * 4]);
  float4 wd = *reinterpret_cast<const float4*>(&w1ad[l31 * 4]);
  for (int n0 = base; n0 < limit; n0 += 2) {
    int n = n0 + half;
    bool valid = n < limit;
    float4 v = make_float4(0.f, 0.f, 0.f, 0.f);
    if (valid) v = *reinterpret_cast<const float4*>(&x[(size_t)n * 128 + l31 * 4]);
    if (valid) {
      ushort4 o;
      o.x = f2b(v.x); o.y = f2b(v.y); o.z = f2b(v.z); o.w = f2b(v.w);
      *reinterpret_cast<ushort4*>(&x_bf[(size_t)n * 128 + l31 * 4]) = o;
    }
    float ps = v.x * ws.x + v.y * ws.y + v.z * ws.z + v.w * ws.w;
    float pd = v.x * wd.x + v.y * wd.y + v.z * wd.z + v.w * wd.w;
#pragma unroll
    for (int off = 16; off; off >>= 1) {
      ps += __shfl_xor(ps, off);
      pd += __shfl_xor(pd, off);
    }
    if (l31 == 0 && valid) { asrc1[n] = ps; adst1[n] = pd; }
  }
}

// ---------------- single-pass decoupled-lookback scan ----------------

__global__ __launch_bounds__(1024) void scan_lookback(
    const int* __restrict__ deg, ull_t* __restrict__ state,
    int* __restrict__ rowptr, int* __restrict__ fillpos) {
  __shared__ int sh[1024];
  __shared__ int boff_sh;
  const int tid = threadIdx.x;
  const int bid = blockIdx.x;
  int i = bid * 1024 + tid;
  int v = (i < N_NODES) ? deg[i] : 0;
  sh[tid] = v;
  __syncthreads();
  for (int off = 1; off < 1024; off <<= 1) {
    int t = (tid >= off) ? sh[tid - off] : 0;
    __syncthreads();
    sh[tid] += t;
    __syncthreads();
  }
  if (tid == 0) {
    int total = sh[1023];
    atomicExch(&state[bid], (1ULL << 32) | (unsigned int)total);
    long long excl = 0;
    int p = bid - 1;
    while (p >= 0) {
      ull_t st;
      do { st = atomicAdd(&state[p], 0ULL); } while (st == 0);
      excl += (int)(st & 0xffffffffULL);
      if ((st >> 32) == 2) break;
      --p;
    }
    atomicExch(&state[bid], (2ULL << 32) | (unsigned int)(excl + total));
    boff_sh = (int)excl;
  }
  __syncthreads();
  if (i < N_NODES) {
    int excl = sh[tid] - v + boff_sh;
    rowptr[i] = excl;
    fillpos[i] = excl;
    if (i == N_NODES - 1) rowptr[N_NODES] = excl + v;
  }
}

// ---------------- dst-partitioned edge fill ----------------

__global__ __launch_bounds__(256) void fill_kernel(
    const int* __restrict__ ei, int* __restrict__ fillpos, int* __restrict__ col) {
  const int part = blockIdx.x & 7;
  const int gb = blockIdx.x >> 3;
  const int PB = FB >> 3;
  const int lo = part * (N_NODES >> 3);
  const int hi = (part == 7) ? N_NODES : lo + (N_NODES >> 3);
  for (int e = gb * 256 + threadIdx.x; e < E_TOT; e += PB * 256) {
    int d = (e < N_EDGES) ? ei[N_EDGES + e] : (e - N_EDGES);
    if (d >= lo && d < hi) {
      int s = (e < N_EDGES) ? ei[e] : d;
      int p = atomicAdd(&fillpos[d], 1);
      col[p] = s;
    }
  }
}

// ---------------- layer-1 aggregation: 2 nodes/wave, 512B per VMEM instr ----------------

__global__ __launch_bounds__(256) void fused_aggx(
    const ushort_t* __restrict__ xb, const int* __restrict__ rowptr,
    const int* __restrict__ col, const float* __restrict__ asrc,
    const float* __restrict__ adst, ushort_t* __restrict__ out) {
  __shared__ float wlds[8][64];
  __shared__ int clds[8][64];
  const int wid = threadIdx.x >> 6;
  const int lane = threadIdx.x & 63;
  const int half = lane >> 5;
  const int l31 = lane & 31;
  const int slot = wid * 2 + half;
  const int n = blockIdx.x * 8 + slot;
  if (n >= N_NODES) return;
  int beg = rowptr[n], end = rowptr[n + 1];
  int deg = end - beg;
  float ad = adst[n];
  float ssum = 0.f;
  int cap = deg < 64 ? deg : 64;
  for (int t = l31; t < cap; t += 32) {
    int s = col[beg + t];
    float we = __expf(leaky(asrc[s] + ad));
    ssum += we;
    wlds[slot][t] = we;
    clds[slot][t] = s << 8;   // byte offset of 256B row
  }
  for (int jj = beg + 64 + l31; jj < end; jj += 32)   // essentially never
    ssum += __expf(leaky(asrc[col[jj]] + ad));
#pragma unroll
  for (int off = 16; off; off >>= 1) ssum += __shfl_xor(ssum, off);
  float inv = 1.0f / ssum;
  for (int t = l31; t < cap; t += 32) wlds[slot][t] *= inv;
  float a0 = 0.f, a1 = 0.f, a2 = 0.f, a3 = 0.f;
  const char* hb = (const char*)xb + l31 * 8;
  if (deg <= 64) {
    int t = 0;
    for (; t + 8 <= deg; t += 8) {
      int4 cA = *reinterpret_cast<const int4*>(&clds[slot][t]);
      int4 cB = *reinterpret_cast<const int4*>(&clds[slot][t + 4]);
      float4 wA = *reinterpret_cast<const float4*>(&wlds[slot][t]);
      float4 wB = *reinterpret_cast<const float4*>(&wlds[slot][t + 4]);
      uint2 q0 = *reinterpret_cast<const uint2*>(hb + cA.x);
      uint2 q1 = *reinterpret_cast<const uint2*>(hb + cA.y);
      uint2 q2 = *reinterpret_cast<const uint2*>(hb + cA.z);
      uint2 q3 = *reinterpret_cast<const uint2*>(hb + cA.w);
      uint2 q4 = *reinterpret_cast<const uint2*>(hb + cB.x);
      uint2 q5 = *reinterpret_cast<const uint2*>(hb + cB.y);
      uint2 q6 = *reinterpret_cast<const uint2*>(hb + cB.z);
      uint2 q7 = *reinterpret_cast<const uint2*>(hb + cB.w);
      a0 += wA.x * blo(q0.x) + wA.y * blo(q1.x) + wA.z * blo(q2.x) + wA.w * blo(q3.x)
          + wB.x * blo(q4.x) + wB.y * blo(q5.x) + wB.z * blo(q6.x) + wB.w * blo(q7.x);
      a1 += wA.x * bhi(q0.x) + wA.y * bhi(q1.x) + wA.z * bhi(q2.x) + wA.w * bhi(q3.x)
          + wB.x * bhi(q4.x) + wB.y * bhi(q5.x) + wB.z * bhi(q6.x) + wB.w * bhi(q7.x);
      a2 += wA.x * blo(q0.y) + wA.y * blo(q1.y) + wA.z * blo(q2.y) + wA.w * blo(q3.y)
          + wB.x * blo(q4.y) + wB.y * blo(q5.y) + wB.z * blo(q6.y) + wB.w * blo(q7.y);
      a3 += wA.x * bhi(q0.y) + wA.y * bhi(q1.y) + wA.z * bhi(q2.y) + wA.w * bhi(q3.y)
          + wB.x * bhi(q4.y) + wB.y * bhi(q5.y) + wB.z * bhi(q6.y) + wB.w * bhi(q7.y);
    }
    for (; t < deg; ++t) {
      int c = clds[slot][t];
      float w = wlds[slot][t];
      uint2 q = *reinterpret_cast<const uint2*>(hb + c);
      a0 += w * blo(q.x); a1 += w * bhi(q.x);
      a2 += w * blo(q.y); a3 += w * bhi(q.y);
    }
  } else {
    for (int j = beg; j < end; ++j) {
      int sj = col[j];
      float w = __expf(leaky(asrc[sj] + ad)) * inv;
      uint2 q = *reinterpret_cast<const uint2*>(&xb[(size_t)sj * 128 + l31 * 4]);
      a0 += w * blo(q.x); a1 += w * bhi(q.x);
      a2 += w * blo(q.y); a3 += w * bhi(q.y);
    }
  }
  ushort4 o;
  o.x = f2b(a0); o.y = f2b(a1); o.z = f2b(a2); o.w = f2b(a3);
  *reinterpret_cast<ushort4*>(&out[(size_t)n * 128 + l31 * 4]) = o;
}

// ---------------- fused GEMM1+GEMM2, 64-row blocks, 32KB LDS, SWAPPED GEMM1 ----------------
// GEMM1 computes T^T = W1t_mat @ aggX^T via mfma(A=W1t_frag, B=aggX_frag):
// identical input reads, but D-layout gives lane col=l15=node row (fixed),
// row=l4*4+j=channel (contiguous) -> Ts written as ushort4 (16 vec writes vs
// 64 scalar). Ts[node r][c] swizzled; GEMM2 + epilogue unchanged.

__global__ __launch_bounds__(256) void gemm12_kernel(
    const ushort_t* __restrict__ aggX, const ushort_t* __restrict__ W1t,
    const float* __restrict__ b1, const ushort_t* __restrict__ W2t,
    const float* __restrict__ a2s, const float* __restrict__ a2d,
    ushort_t* __restrict__ h2, float* __restrict__ asrc2,
    float* __restrict__ adst2, int M) {
  __shared__ ushort_t smem[64 * 256];   // 32KB; As = first 16KB, Ts = all of it
  const int tid = threadIdx.x;
  const int lane = tid & 63;
  const int wid = tid >> 6;
  const int l15 = lane & 15;
  const int l4 = lane >> 4;
  const int rowBase = blockIdx.x * 64;

  // stage As = aggX[rowBase..+64][0..128], swizzled
  for (int c = tid; c < 64 * 128 / 8; c += 256) {
    int r = c >> 4;
    int k8 = (c & 15) << 3;
    int gr = rowBase + r;
    short8v u = {};
    if (gr < M) u = *(const short8v*)&aggX[(size_t)gr * 128 + k8];
    int byte = ((r * 128 + k8) * 2) ^ ((r & 7) << 4);
    *(short8v*)((char*)smem + byte) = u;
  }
  __syncthreads();

  // GEMM1 (swapped): acc1[m][n] = T^T tile; wave owns c-range wid*64..+64, all 64 nodes
  f32x4 acc1[4][4] = {};
#pragma unroll
  for (int kk = 0; kk < 4; ++kk) {
    short8v wfr[4];   // A-operand: W1t row = channel c
#pragma unroll
    for (int m = 0; m < 4; ++m) {
      int crow = wid * 64 + m * 16 + l15;
      wfr[m] = *(const short8v*)&W1t[(size_t)crow * 128 + kk * 32 + l4 * 8];
    }
    short8v afr[4];   // B-operand: aggX node col r
#pragma unroll
    for (int n = 0; n < 4; ++n) {
      int r = n * 16 + l15;
      int byte = ((r * 128 + kk * 32 + l4 * 8) * 2) ^ ((r & 7) << 4);
      afr[n] = *(const short8v*)((const char*)smem + byte);
    }
#pragma unroll
    for (int m = 0; m < 4; ++m)
#pragma unroll
      for (int n = 0; n < 4; ++n)
        acc1[m][n] = __builtin_amdgcn_mfma_f32_16x16x32_bf16(
            wfr[m], afr[n], acc1[m][n], 0, 0, 0);
  }
  __syncthreads();   // all As reads complete before Ts overwrites

  // Ts[r][c] = relu(T + b1): vectorized ushort4 writes (c contiguous in j)
#pragma unroll
  for (int m = 0; m < 4; ++m) {
    int c0 = wid * 64 + m * 16 + l4 * 4;
    float4 bv = *reinterpret_cast<const float4*>(&b1[c0]);
#pragma unroll
    for (int n = 0; n < 4; ++n) {
      int r = n * 16 + l15;
      ushort4 o;
      o.x = f2b(fmaxf(acc1[m][n][0] + bv.x, 0.f));
      o.y = f2b(fmaxf(acc1[m][n][1] + bv.y, 0.f));
      o.z = f2b(fmaxf(acc1[m][n][2] + bv.z, 0.f));
      o.w = f2b(fmaxf(acc1[m][n][3] + bv.w, 0.f));
      int byte = ((r * 256 + c0) * 2) ^ ((r & 7) << 4);
      *(ushort4*)((char*)smem + byte) = o;
    }
  }
  __syncthreads();

  // GEMM2: wave owns 16 rows x all 64 cols; K=256
  f32x4 acc2[4] = {};
#pragma unroll
  for (int kk = 0; kk < 8; ++kk) {
    int r = wid * 16 + l15;
    int byte = ((r * 256 + kk * 32 + l4 * 8) * 2) ^ ((r & 7) << 4);
    short8v afr2 = *(const short8v*)((const char*)smem + byte);
    short8v bfr2[4];
#pragma unroll
    for (int n = 0; n < 4; ++n) {
      int bcol = n * 16 + l15;
      bfr2[n] = *(const short8v*)&W2t[(size_t)bcol * 256 + kk * 32 + l4 * 8];
    }
#pragma unroll
    for (int n = 0; n < 4; ++n)
      acc2[n] = __builtin_amdgcn_mfma_f32_16x16x32_bf16(afr2, bfr2[n], acc2[n], 0, 0, 0);
  }
  // epilogue: h2 store + alpha2 dots (direct, no atomics)
  float as_v[4], ad_v[4];
#pragma unroll
  for (int n = 0; n < 4; ++n) {
    as_v[n] = a2s[n * 16 + l15];
    ad_v[n] = a2d[n * 16 + l15];
  }
#pragma unroll
  for (int j = 0; j < 4; ++j) {
    int gr = rowBase + wid * 16 + l4 * 4 + j;
    float ss = 0.f, dd = 0.f;
#pragma unroll
    for (int n = 0; n < 4; ++n) {
      float v = acc2[n][j];
      if (gr < M) h2[(size_t)gr * 64 + n * 16 + l15] = f2b(v);
      ss += v * as_v[n];
      dd += v * ad_v[n];
    }
#pragma unroll
    for (int o = 1; o < 16; o <<= 1) {
      ss += __shfl_xor(ss, o);
      dd += __shfl_xor(dd, o);
    }
    if (l15 == 0 && gr < M) { asrc2[gr] = ss; adst2[gr] = dd; }
  }
}

// ---------------- layer-2 aggregation: 2 nodes/wave (uint = 2 channels/lane) ----------------

__global__ __launch_bounds__(256) void fused_agg2(
    const ushort_t* __restrict__ h, const int* __restrict__ rowptr,
    const int* __restrict__ col, const float* __restrict__ asrc,
    const float* __restrict__ adst, const float* __restrict__ bias,
    float* __restrict__ out) {
  __shared__ float wlds[8][64];
  __shared__ int clds[8][64];
  const int wid = threadIdx.x >> 6;
  const int lane = threadIdx.x & 63;
  const int half = lane >> 5;
  const int l31 = lane & 31;
  const int slot = wid * 2 + half;
  const int n = blockIdx.x * 8 + slot;
  if (n >= N_NODES) return;
  int beg = rowptr[n], end = rowptr[n + 1];
  int deg = end - beg;
  float ad = adst[n];
  float ssum = 0.f;
  int cap = deg < 64 ? deg : 64;
  for (int t = l31; t < cap; t += 32) {
    int s = col[beg + t];
    float we = __expf(leaky(asrc[s] + ad));
    ssum += we;
    wlds[slot][t] = we;
    clds[slot][t] = s << 7;   // byte offset of 128B row
  }
  for (int jj = beg + 64 + l31; jj < end; jj += 32)
    ssum += __expf(leaky(asrc[col[jj]] + ad));
#pragma unroll
  for (int off = 16; off; off >>= 1) ssum += __shfl_xor(ssum, off);
  float inv = 1.0f / ssum;
  for (int t = l31; t < cap; t += 32) wlds[slot][t] *= inv;
  float a0 = 0.f, a1 = 0.f;
  const char* hb = (const char*)h + l31 * 4;
  if (deg <= 64) {
    int t = 0;
    for (; t + 8 <= deg; t += 8) {
      int4 cA = *reinterpret_cast<const int4*>(&clds[slot][t]);
      int4 cB = *reinterpret_cast<const int4*>(&clds[slot][t + 4]);
      float4 wA = *reinterpret_cast<const float4*>(&wlds[slot][t]);
      float4 wB = *reinterpret_cast<const float4*>(&wlds[slot][t + 4]);
      unsigned int q0 = *reinterpret_cast<const unsigned int*>(hb + cA.x);
      unsigned int q1 = *reinterpret_cast<const unsigned int*>(hb + cA.y);
      unsigned int q2 = *reinterpret_cast<const unsigned int*>(hb + cA.z);
      unsigned int q3 = *reinterpret_cast<const unsigned int*>(hb + cA.w);
      unsigned int q4 = *reinterpret_cast<const unsigned int*>(hb + cB.x);
      unsigned int q5 = *reinterpret_cast<const unsigned int*>(hb + cB.y);
      unsigned int q6 = *reinterpret_cast<const unsigned int*>(hb + cB.z);
      unsigned int q7 = *reinterpret_cast<const unsigned int*>(hb + cB.w);
      a0 += wA.x * blo(q0) + wA.y * blo(q1) + wA.z * blo(q2) + wA.w * blo(q3)
          + wB.x * blo(q4) + wB.y * blo(q5) + wB.z * blo(q6) + wB.w * blo(q7);
      a1 += wA.x * bhi(q0) + wA.y * bhi(q1) + wA.z * bhi(q2) + wA.w * bhi(q3)
          + wB.x * bhi(q4) + wB.y * bhi(q5) + wB.z * bhi(q6) + wB.w * bhi(q7);
    }
    for (; t < deg; ++t) {
      int c = clds[slot][t];
      float w = wlds[slot][t];
      unsigned int q = *reinterpret_cast<const unsigned int*>(hb + c);
      a0 += w * blo(q);
      a1 += w * bhi(q);
    }
  } else {
    for (int j = beg; j < end; ++j) {
      int sj = col[j];
      float w = __expf(leaky(asrc[sj] + ad)) * inv;
      unsigned int q = *reinterpret_cast<const unsigned int*>(&h[(size_t)sj * 64 + l31 * 2]);
      a0 += w * blo(q);
      a1 += w * bhi(q);
    }
  }
  float2 o;
  o.x = a0 + bias[l31 * 2];
  o.y = a1 + bias[l31 * 2 + 1];
  *reinterpret_cast<float2*>(&out[(size_t)n * 64 + l31 * 2]) = o;
}

// ---------------- launch ----------------

extern "C" void kernel_launch(void* const* d_in, const int* in_sizes, int n_in,
                              void* d_out, int out_size, void* d_ws, size_t ws_size,
                              hipStream_t stream) {
  const float* x    = (const float*)d_in[0];
  const int*   ei   = (const int*)d_in[1];
  const float* W1   = (const float*)d_in[2];
  const float* a1s  = (const float*)d_in[3];
  const float* a1d  = (const float*)d_in[4];
  const float* b1   = (const float*)d_in[5];
  const float* W2   = (const float*)d_in[6];
  const float* a2s  = (const float*)d_in[7];
  const float* a2d  = (const float*)d_in[8];
  const float* b2   = (const float*)d_in[9];
  float* out = (float*)d_out;

  char* ws = (char*)d_ws;
  size_t off = 0;
  auto alloc = [&](size_t bytes) {
    void* p = ws + off;
    off += bytes;
    off = (off + 255) & ~(size_t)255;
    return p;
  };

  ushort_t* x_bf = (ushort_t*)alloc((size_t)N_NODES * 128 * 2);  // bf16 x
  ushort_t* aggX = (ushort_t*)alloc((size_t)N_NODES * 128 * 2);  // bf16 sum(alpha*x)
  ushort_t* h2   = (ushort_t*)alloc((size_t)N_NODES * 64 * 2);   // bf16
  ushort_t* W1t  = (ushort_t*)alloc((size_t)256 * 128 * 2);
  ushort_t* W2t  = (ushort_t*)alloc((size_t)64 * 256 * 2);
  float* w1as    = (float*)alloc((size_t)128 * 4);
  float* w1ad    = (float*)alloc((size_t)128 * 4);
  float* asrc1   = (float*)alloc((size_t)N_NODES * 4);
  float* adst1   = (float*)alloc((size_t)N_NODES * 4);
  float* asrc2   = (float*)alloc((size_t)N_NODES * 4);
  float* adst2   = (float*)alloc((size_t)N_NODES * 4);
  int*   deg     = (int*)alloc((size_t)N_NODES * 4);
  int*   rowptr  = (int*)alloc((size_t)(N_NODES + 1) * 4);
  int*   fillp   = (int*)alloc((size_t)N_NODES * 4);
  int*   col     = (int*)alloc((size_t)E_TOT * 4);
  ull_t* state   = (ull_t*)alloc((size_t)SCAN_NB * 8);

  const int nodeBlocks8 = (N_NODES + 7) / 8;

  // 1. prep: zeros + W transposes + w1as/w1ad
  prep_kernel<<<1024, 256, 0, stream>>>(deg, state, W1, W1t, W2, W2t,
                                        a1s, a1d, w1as, w1ad);
  // 2. dst-partitioned histogram + x->bf16 + alpha1 row-dots (merged)
  cast_alpha_hist<<<HB + CB, 256, 0, stream>>>(x, x_bf, w1as, w1ad,
                                               asrc1, adst1, ei, deg);
  // 3. single-pass scan
  scan_lookback<<<SCAN_NB, 1024, 0, stream>>>(deg, state, rowptr, fillp);
  // 4. dst-partitioned edge fill (XCD-local col writes)
  fill_kernel<<<FB, 256, 0, stream>>>(ei, fillp, col);
  // 5. layer-1 aggregation over x_bf (2 nodes/wave, 512B/VMEM)
  fused_aggx<<<nodeBlocks8, 256, 0, stream>>>(x_bf, rowptr, col, asrc1, adst1, aggX);
  // 6. fused GEMM1+GEMM2 (swapped GEMM1, vectorized Ts, alpha2 epilogue)
  gemm12_kernel<<<GB64, 256, 0, stream>>>(aggX, W1t, b1, W2t, a2s, a2d,
                                          h2, asrc2, adst2, N_NODES);
  // 7. layer-2 softmax+aggregate (2 nodes/wave, +bias) -> out
  fused_agg2<<<nodeBlocks8, 256, 0, stream>>>(h2, rowptr, col, asrc2, adst2, b2, out);
}